// Round 3
// baseline (1196.653 us; speedup 1.0000x reference)
//
#include <hip/hip_runtime.h>
#include <math.h>

#define NROWS 4096
#define MCOLS 16384
#define CDIM  256

static __device__ __forceinline__ float softplusf(float x) {
    return fmaxf(x, 0.0f) + log1pf(expf(-fabsf(x)));
}

// ---------------------------------------------------------------------------
// Passthrough copy: d_out[0 .. 1M) = inp_cont
// ---------------------------------------------------------------------------
__global__ __launch_bounds__(256)
void copy_kernel(const float4* __restrict__ src, float4* __restrict__ dst, int n4) {
    int i = blockIdx.x * blockDim.x + threadIdx.x;
    if (i < n4) dst[i] = src[i];
}

// ---------------------------------------------------------------------------
// Column norms. i < MCOLS -> peers (fp64 accumulate), else inp pixel column.
// ---------------------------------------------------------------------------
__global__ __launch_bounds__(256)
void norms_kernel(const float* __restrict__ xiT, const float* __restrict__ xpT,
                  float* __restrict__ normI, float* __restrict__ normP) {
    int i = blockIdx.x * blockDim.x + threadIdx.x;
    if (i >= MCOLS + NROWS) return;
    const float* p;
    int base;
    if (i < MCOLS) { p = xpT; base = (i >> 12) * (CDIM * 4096) + (i & 4095); }
    else           { p = xiT; base = i - MCOLS; }
    double s = 0.0;
    for (int c = 0; c < CDIM; ++c) {
        float v = p[base + c * 4096];
        s = fma((double)v, (double)v, s);
    }
    if (i < MCOLS) normP[i] = (float)s;
    else           normI[i - MCOLS] = (float)s;
}

// ---------------------------------------------------------------------------
// Distance GEMM + per-row top-8 (in dist domain, post-sqrt, to match ref ties)
// grid = 128 row-tiles * 2 col-splits; block = 512 threads.
// Block: 32 rows x 8192 cols, subtiles of 512 cols, K=256 fully in LDS.
// ---------------------------------------------------------------------------
__global__ __launch_bounds__(512)
void dist_topk_kernel(const float* __restrict__ xiT, const float* __restrict__ xpT,
                      const float* __restrict__ normI, const float* __restrict__ normP,
                      float* __restrict__ candV, int* __restrict__ candI) {
    __shared__ __align__(16) float A[CDIM][32];   // 32 KB
    __shared__ __align__(16) float T[32][513];    // ~65.7 KB

    const int t = threadIdx.x;
    const int rowTile = blockIdx.x >> 1;
    const int split   = blockIdx.x & 1;
    const int r0    = rowTile * 32;
    const int mbase = split * 8192;

    // stage A tile: xiT[c][r0 + r]
    for (int i = t; i < CDIM * 32; i += 512) {
        int c = i >> 5, r = i & 31;
        A[c][r] = xiT[c * 4096 + r0 + r];
    }

    const int cl   = t & 127;   // column lane (4 cols: cl + 128*j)
    const int rg   = t >> 7;    // row group 0..3
    const int row0 = rg * 8;

    float nI[8];
#pragma unroll
    for (int r = 0; r < 8; ++r) nI[r] = normI[r0 + row0 + r];

    // selection mapping: 32 rows x 16 slices
    const int selRow   = t & 31;
    const int selSlice = t >> 5;

    float bv[8]; int bi[8];
#pragma unroll
    for (int j = 0; j < 8; ++j) { bv[j] = 3.4e38f; bi[j] = -1; }
    float worst = 3.4e38f; int worstp = 0;

    __syncthreads();

    for (int sub = 0; sub < 16; ++sub) {
        const int m0 = mbase + sub * 512;
        const float* pc = xpT + (m0 >> 12) * (CDIM * 4096) + (m0 & 4095) + cl;

        float acc[8][4];
#pragma unroll
        for (int r = 0; r < 8; ++r)
#pragma unroll
            for (int j = 0; j < 4; ++j) acc[r][j] = 0.0f;

#pragma unroll 2
        for (int c = 0; c < CDIM; ++c) {
            const float b0 = pc[c * 4096];
            const float b1 = pc[c * 4096 + 128];
            const float b2 = pc[c * 4096 + 256];
            const float b3 = pc[c * 4096 + 384];
            const float4 a0  = *reinterpret_cast<const float4*>(&A[c][row0]);
            const float4 a1v = *reinterpret_cast<const float4*>(&A[c][row0 + 4]);
            const float av[8] = {a0.x, a0.y, a0.z, a0.w, a1v.x, a1v.y, a1v.z, a1v.w};
#pragma unroll
            for (int r = 0; r < 8; ++r) {
                acc[r][0] = fmaf(av[r], b0, acc[r][0]);
                acc[r][1] = fmaf(av[r], b1, acc[r][1]);
                acc[r][2] = fmaf(av[r], b2, acc[r][2]);
                acc[r][3] = fmaf(av[r], b3, acc[r][3]);
            }
        }

        __syncthreads();   // previous selection pass done reading T
#pragma unroll
        for (int j = 0; j < 4; ++j) {
            const float npv = normP[m0 + cl + 128 * j];
#pragma unroll
            for (int r = 0; r < 8; ++r) {
                float d2 = nI[r] + npv - 2.0f * acc[r][j];
                T[row0 + r][cl + 128 * j] = sqrtf(fmaxf(d2, 0.0f));
            }
        }
        __syncthreads();

        // selection: each thread scans 32 cols of its row
#pragma unroll 4
        for (int i2 = 0; i2 < 32; ++i2) {
            const int col = selSlice * 32 + i2;
            const float v = T[selRow][col];
            if (v < worst) {
                bv[worstp] = v; bi[worstp] = m0 + col;
                worst = bv[0]; worstp = 0;
#pragma unroll
                for (int j = 1; j < 8; ++j)
                    if (bv[j] > worst) { worst = bv[j]; worstp = j; }
            }
        }
    }

    __syncthreads();
    // merge 16 slice-privates per row. Transposed layout: conflict-free.
    float* mV = &T[0][0];
    int*   mI = reinterpret_cast<int*>(mV + 4096);
#pragma unroll
    for (int j = 0; j < 8; ++j) {
        mV[(selSlice * 8 + j) * 32 + selRow] = bv[j];
        mI[(selSlice * 8 + j) * 32 + selRow] = bi[j];
    }
    __syncthreads();

    if (t < 32) {
        float sv[8]; int si[8];
#pragma unroll
        for (int j = 0; j < 8; ++j) { sv[j] = 3.4e38f; si[j] = -1; }
        float w2 = 3.4e38f; int wp = 0;
        for (int k = 0; k < 128; ++k) {
            const float v = mV[k * 32 + t];
            if (v < w2) {
                sv[wp] = v; si[wp] = mI[k * 32 + t];
                w2 = sv[0]; wp = 0;
#pragma unroll
                for (int j = 1; j < 8; ++j)
                    if (sv[j] > w2) { w2 = sv[j]; wp = j; }
            }
        }
        // insertion sort ascending
        for (int a = 1; a < 8; ++a) {
            float v = sv[a]; int ii = si[a]; int b = a - 1;
            while (b >= 0 && sv[b] > v) { sv[b + 1] = sv[b]; si[b + 1] = si[b]; --b; }
            sv[b + 1] = v; si[b + 1] = ii;
        }
        const int row = r0 + t;
#pragma unroll
        for (int j = 0; j < 8; ++j) {
            candV[row * 16 + split * 8 + j] = sv[j];
            candI[row * 16 + split * 8 + j] = si[j];
        }
    }
}

// ---------------------------------------------------------------------------
// MLP GEMM: OutT[k][row] = (bn-relu?)(X)[row][:] . W[k][:] + bias[k]
// PIXIN: X is pixel-layout [B][CIN][4096]; else X is [CIN][rows].
// block 256 threads, 128 rows per block (2 rows/thread), W transposed in LDS.
// ---------------------------------------------------------------------------
template <int CIN, int COUT, bool PIXIN, bool BNIN>
__global__ __launch_bounds__(256)
void mlp_gemm_kernel(const float* __restrict__ X, int rows,
                     const float* __restrict__ W, const float* __restrict__ bias,
                     const float* __restrict__ stats, const float* __restrict__ g,
                     const float* __restrict__ be, float invDenom,
                     float* __restrict__ outT) {
    constexpr int PW  = COUT + 4;
    constexpr int OPT = COUT / 4;            // outputs per thread
    constexpr int LOGC = (CIN == 256) ? 8 : 7;
    __shared__ __align__(16) float Wl[CIN][PW];
    __shared__ float scL[CIN], shL[CIN];

    const int t = threadIdx.x;
    for (int i = t; i < CIN * COUT; i += 256) {
        int k = i >> LOGC, c = i & (CIN - 1);
        Wl[c][k] = W[i];
    }
    if (BNIN) {
        for (int c = t; c < CIN; c += 256) {
            float mean = stats[c] * invDenom;
            float var  = stats[CIN + c] * invDenom - mean * mean;
            float sc   = rsqrtf(var + 1e-5f) * g[c];
            scL[c] = sc;
            shL[c] = be[c] - mean * sc;
        }
    }
    __syncthreads();

    const int r   = blockIdx.x * 128 + (t & 63);
    const int r2  = r + 64;
    const int chb = (t >> 6) * OPT;

    float acc0[OPT], acc1[OPT];
#pragma unroll
    for (int q = 0; q < OPT; ++q) { acc0[q] = 0.0f; acc1[q] = 0.0f; }

#pragma unroll 2
    for (int c = 0; c < CIN; ++c) {
        float x0, x1;
        if (PIXIN) {
            x0 = X[(r  >> 12) * (CDIM * 4096) + c * 4096 + (r  & 4095)];
            x1 = X[(r2 >> 12) * (CDIM * 4096) + c * 4096 + (r2 & 4095)];
        } else {
            x0 = X[c * rows + r];
            x1 = X[c * rows + r2];
        }
        if (BNIN) {
            x0 = fmaxf(fmaf(x0, scL[c], shL[c]), 0.0f);
            x1 = fmaxf(fmaf(x1, scL[c], shL[c]), 0.0f);
        }
#pragma unroll
        for (int q = 0; q < OPT / 4; ++q) {
            const float4 wv = *reinterpret_cast<const float4*>(&Wl[c][chb + 4 * q]);
            acc0[4 * q + 0] = fmaf(x0, wv.x, acc0[4 * q + 0]);
            acc0[4 * q + 1] = fmaf(x0, wv.y, acc0[4 * q + 1]);
            acc0[4 * q + 2] = fmaf(x0, wv.z, acc0[4 * q + 2]);
            acc0[4 * q + 3] = fmaf(x0, wv.w, acc0[4 * q + 3]);
            acc1[4 * q + 0] = fmaf(x1, wv.x, acc1[4 * q + 0]);
            acc1[4 * q + 1] = fmaf(x1, wv.y, acc1[4 * q + 1]);
            acc1[4 * q + 2] = fmaf(x1, wv.z, acc1[4 * q + 2]);
            acc1[4 * q + 3] = fmaf(x1, wv.w, acc1[4 * q + 3]);
        }
    }
#pragma unroll
    for (int q = 0; q < OPT; ++q) {
        const int k = chb + q;
        const float b = bias[k];
        outT[k * rows + r]  = acc0[q] + b;
        outT[k * rows + r2] = acc1[q] + b;
    }
}

// ---------------------------------------------------------------------------
// Column stats (sum, sumsq) over rows of HT [C][rows]. Deterministic tree.
// ---------------------------------------------------------------------------
__global__ __launch_bounds__(256)
void colstats_kernel(const float* __restrict__ H, int rows,
                     float* __restrict__ stats, int C) {
    __shared__ float rs[256], rq[256];
    const int c = blockIdx.x;
    const int t = threadIdx.x;
    float s = 0.0f, q = 0.0f;
    for (int r = t; r < rows; r += 256) {
        float v = H[c * rows + r];
        s += v;
        q = fmaf(v, v, q);
    }
    rs[t] = s; rq[t] = q;
    __syncthreads();
    for (int st = 128; st > 0; st >>= 1) {
        if (t < st) { rs[t] += rs[t + st]; rq[t] += rq[t + st]; }
        __syncthreads();
    }
    if (t == 0) { stats[c] = rs[0]; stats[C + c] = rq[0]; }
}

// ---------------------------------------------------------------------------
// a[row] = sum_c relu(bn(H2T[c][row])) * cw[c] + cb
// ---------------------------------------------------------------------------
__global__ __launch_bounds__(256)
void a_kernel(const float* __restrict__ H2T, int rows,
              const float* __restrict__ stats, const float* __restrict__ g,
              const float* __restrict__ be, const float* __restrict__ cw,
              const float* __restrict__ cb, float* __restrict__ aout,
              float invDenom) {
    __shared__ float scL[64], shL[64], cwL[64];
    const int t = threadIdx.x;
    if (t < 64) {
        float mean = stats[t] * invDenom;
        float var  = stats[64 + t] * invDenom - mean * mean;
        float sc   = rsqrtf(var + 1e-5f) * g[t];
        scL[t] = sc;
        shL[t] = be[t] - mean * sc;
        cwL[t] = cw[t];
    }
    __syncthreads();
    const int row = blockIdx.x * 256 + t;
    if (row < rows) {
        float a = 0.0f;
        for (int c = 0; c < 64; ++c) {
            float v = H2T[c * rows + row];
            a += fmaxf(fmaf(v, scL[c], shL[c]), 0.0f) * cwL[c];
        }
        aout[row] = a + cb[0];
    }
}

// ---------------------------------------------------------------------------
// Final: merge candidates, softplus->softmax over kNN, gather peers_style.
// grid = 64 blocks (64 rows each), block 256.
// ---------------------------------------------------------------------------
__global__ __launch_bounds__(256)
void out_kernel(const float* __restrict__ candV, const int* __restrict__ candI,
                const float* __restrict__ a1, const float* __restrict__ a2,
                const float* __restrict__ PS, float* __restrict__ dout) {
    __shared__ float wL[64][8];
    __shared__ int   aL[64][8];
    const int t  = threadIdx.x;
    const int nb = blockIdx.x * 64;

    if (t < 64) {
        const int row = nb + t;
        float sv[8]; int si[8];
#pragma unroll
        for (int j = 0; j < 8; ++j) { sv[j] = 3.4e38f; si[j] = 0; }
        float w2 = 3.4e38f; int wp = 0;
        for (int k = 0; k < 16; ++k) {
            const float v = candV[row * 16 + k];
            if (v < w2) {
                sv[wp] = v; si[wp] = candI[row * 16 + k];
                w2 = sv[0]; wp = 0;
#pragma unroll
                for (int j = 1; j < 8; ++j)
                    if (sv[j] > w2) { w2 = sv[j]; wp = j; }
            }
        }
        for (int a = 1; a < 8; ++a) {
            float v = sv[a]; int ii = si[a]; int b = a - 1;
            while (b >= 0 && sv[b] > v) { sv[b + 1] = sv[b]; si[b + 1] = si[b]; --b; }
            sv[b + 1] = v; si[b + 1] = ii;
        }
        const float kth = sv[4];
        int cnt = 5;
        while (cnt < 8 && sv[cnt] <= kth) ++cnt;

        const float arow = a1[row];
        float s[8], e[8];
        float mx = -1e30f;
#pragma unroll
        for (int j = 0; j < 8; ++j) s[j] = 0.0f;
        for (int j = 0; j < cnt; ++j) {
            s[j] = softplusf(arow + a2[si[j]]);
            mx = fmaxf(mx, s[j]);
        }
        float Z = 0.0f;
        for (int j = 0; j < 8; ++j) {
            e[j] = (j < cnt) ? expf(s[j] - mx) : 0.0f;
            Z += e[j];
        }
        for (int j = 0; j < 8; ++j) {
            const int ix = (j < cnt) ? si[j] : si[0];
            wL[t][j] = e[j] / Z;
            aL[t][j] = (ix >> 12) * (CDIM * 4096) + (ix & 4095);
        }
    }
    __syncthreads();

    const int rl  = t & 63;
    const int grp = t >> 6;
    float w[8]; int ab[8];
#pragma unroll
    for (int j = 0; j < 8; ++j) { w[j] = wL[rl][j]; ab[j] = aL[rl][j]; }
    const int n = nb + rl;
    for (int c = grp * 64; c < grp * 64 + 64; ++c) {
        float acc = 0.0f;
#pragma unroll
        for (int j = 0; j < 8; ++j) acc += w[j] * PS[ab[j] + c * 4096];
        dout[(CDIM + c) * 4096 + n] = acc;
    }
}

// ---------------------------------------------------------------------------
extern "C" void kernel_launch(void* const* d_in, const int* in_sizes, int n_in,
                              void* d_out, int out_size, void* d_ws, size_t ws_size,
                              hipStream_t stream) {
    const float* inp_cont    = (const float*)d_in[0];
    // d_in[1] = inp_style (unused by reference except for shape)
    const float* peers_cont  = (const float*)d_in[2];
    const float* peers_style = (const float*)d_in[3];
    const float* W1  = (const float*)d_in[4];
    const float* b1  = (const float*)d_in[5];
    const float* g1  = (const float*)d_in[6];
    const float* be1 = (const float*)d_in[7];
    const float* W2  = (const float*)d_in[8];
    const float* b2  = (const float*)d_in[9];
    const float* g2  = (const float*)d_in[10];
    const float* be2 = (const float*)d_in[11];
    const float* cw1 = (const float*)d_in[12];
    const float* cb1 = (const float*)d_in[13];
    const float* cw2 = (const float*)d_in[14];
    const float* cb2 = (const float*)d_in[15];
    float* out = (float*)d_out;
    float* ws  = (float*)d_ws;

    // workspace layout (floats)
    float* H1Tp  = ws;                       // 128*16384
    float* H1Ti  = H1Tp + 128 * 16384;       // 128*4096
    float* H2Tp  = H1Ti + 128 * 4096;        // 64*16384
    float* H2Ti  = H2Tp + 64 * 16384;        // 64*4096
    float* normP = H2Ti + 64 * 4096;         // 16384
    float* normI = normP + 16384;            // 4096
    float* a2    = normI + 4096;             // 16384
    float* a1    = a2 + 16384;               // 4096
    float* s1p   = a1 + 4096;                // 256
    float* s1i   = s1p + 256;                // 256
    float* s2p   = s1i + 256;                // 128
    float* s2i   = s2p + 128;                // 128
    float* candV = s2i + 128;                // 4096*16
    int*   candI = (int*)(candV + 4096 * 16);// 4096*16
    // total ~16.4 MB
    if (ws_size < (size_t)(4104960 * 4)) return;

    // passthrough channels 0..255
    copy_kernel<<<1024, 256, 0, stream>>>((const float4*)inp_cont, (float4*)out, 262144);

    // distance branch
    norms_kernel<<<80, 256, 0, stream>>>(inp_cont, peers_cont, normI, normP);
    dist_topk_kernel<<<256, 512, 0, stream>>>(inp_cont, peers_cont, normI, normP, candV, candI);

    // MLP branch
    mlp_gemm_kernel<256, 128, true, false><<<128, 256, 0, stream>>>(
        peers_cont, 16384, W1, b1, nullptr, nullptr, nullptr, 0.0f, H1Tp);
    mlp_gemm_kernel<256, 128, true, false><<<32, 256, 0, stream>>>(
        inp_cont, 4096, W1, b1, nullptr, nullptr, nullptr, 0.0f, H1Ti);
    colstats_kernel<<<128, 256, 0, stream>>>(H1Tp, 16384, s1p, 128);
    colstats_kernel<<<128, 256, 0, stream>>>(H1Ti, 4096, s1i, 128);
    mlp_gemm_kernel<128, 64, false, true><<<128, 256, 0, stream>>>(
        H1Tp, 16384, W2, b2, s1p, g1, be1, 1.0f / 16384.0f, H2Tp);
    mlp_gemm_kernel<128, 64, false, true><<<32, 256, 0, stream>>>(
        H1Ti, 4096, W2, b2, s1i, g1, be1, 1.0f / 4096.0f, H2Ti);
    colstats_kernel<<<64, 256, 0, stream>>>(H2Tp, 16384, s2p, 64);
    colstats_kernel<<<64, 256, 0, stream>>>(H2Ti, 4096, s2i, 64);
    a_kernel<<<64, 256, 0, stream>>>(H2Tp, 16384, s2p, g2, be2, cw2, cb2, a2, 1.0f / 16384.0f);
    a_kernel<<<16, 256, 0, stream>>>(H2Ti, 4096, s2i, g2, be2, cw1, cb1, a1, 1.0f / 4096.0f);

    // final gather
    out_kernel<<<64, 256, 0, stream>>>(candV, candI, a1, a2, peers_style, out);
}

// Round 4
// 617.672 us; speedup vs baseline: 1.9374x; 1.9374x over previous
//
#include <hip/hip_runtime.h>
#include <math.h>

#define NROWS 4096
#define MCOLS 16384
#define CDIM  256

typedef _Float16 half8 __attribute__((ext_vector_type(8)));
typedef float f32x4 __attribute__((ext_vector_type(4)));

static __device__ __forceinline__ float softplusf(float x) {
    return fmaxf(x, 0.0f) + log1pf(expf(-fabsf(x)));
}

#define TOPK_UPDATE(BV, BI, WORST, WP, V, IDX)                                 \
    if ((V) < (WORST)) {                                                       \
        BV[WP] = (V); BI[WP] = (IDX);                                          \
        WORST = BV[0]; WP = 0;                                                 \
        _Pragma("unroll")                                                      \
        for (int _q = 1; _q < 8; ++_q)                                         \
            if (BV[_q] > WORST) { WORST = BV[_q]; WP = _q; }                   \
    }

// ---------------------------------------------------------------------------
// Passthrough copy: d_out[0 .. 1M) = inp_cont
// ---------------------------------------------------------------------------
__global__ __launch_bounds__(256)
void copy_kernel(const float4* __restrict__ src, float4* __restrict__ dst, int n4) {
    int i = blockIdx.x * blockDim.x + threadIdx.x;
    if (i < n4) dst[i] = src[i];
}

// ---------------------------------------------------------------------------
// Column norms from ORIGINAL fp32 data (fp64 accumulate).
// ---------------------------------------------------------------------------
__global__ __launch_bounds__(256)
void norms_kernel(const float* __restrict__ xiT, const float* __restrict__ xpT,
                  float* __restrict__ normI, float* __restrict__ normP) {
    int i = blockIdx.x * blockDim.x + threadIdx.x;
    if (i >= MCOLS + NROWS) return;
    const float* p;
    int base;
    if (i < MCOLS) { p = xpT; base = (i >> 12) * (CDIM * 4096) + (i & 4095); }
    else           { p = xiT; base = i - MCOLS; }
    double s = 0.0;
    for (int c = 0; c < CDIM; ++c) {
        float v = p[base + c * 4096];
        s = fma((double)v, (double)v, s);
    }
    if (i < MCOLS) normP[i] = (float)s;
    else           normI[i - MCOLS] = (float)s;
}

// ---------------------------------------------------------------------------
// fp32 [K=256][cols] (batched pixel layout) -> fragment-ready fp16 hi/lo.
// Output layout: chunk index (ct*8 + kt)*64 + lane, 8 halves (16B) per chunk:
//   element = x[col = ct*16 + (lane&15)][k = kt*32 + (lane>>4)*8 + j]
// Tile: 64 cols x 64 k per block, 256 threads, LDS transpose.
// ---------------------------------------------------------------------------
__global__ __launch_bounds__(256)
void convert_kernel(const float* __restrict__ src, uint4* __restrict__ dhi,
                    uint4* __restrict__ dlo, int ncols) {
    __shared__ float S[64][65];
    const int t = threadIdx.x;
    const int tilesPerRow = ncols >> 6;
    const int colbase = (blockIdx.x % tilesPerRow) << 6;
    const int ktbase  = (blockIdx.x / tilesPerRow) << 6;
    const int b = colbase >> 12;            // batch index (xi: 0)
    const int pixbase = colbase & 4095;
    const float* sp = src + (size_t)b * (CDIM * 4096) + (size_t)ktbase * 4096 + pixbase;

    for (int i = t; i < 4096; i += 256) {
        int kk = i >> 6, cc = i & 63;
        S[kk][cc] = sp[kk * 4096 + cc];
    }
    __syncthreads();

    const int l = t & 63;
#pragma unroll
    for (int s = 0; s < 2; ++s) {
        const int pid  = (t >> 6) + 4 * s;  // 0..7
        const int ct_l = pid & 3;
        const int kt_l = pid >> 2;
        const int c_l  = ct_l * 16 + (l & 15);
        const int k_l  = kt_l * 32 + ((l >> 4) << 3);
        half8 h, lo;
#pragma unroll
        for (int j = 0; j < 8; ++j) {
            float v = S[k_l + j][c_l];
            _Float16 hv = (_Float16)v;
            h[j]  = hv;
            lo[j] = (_Float16)(v - (float)hv);
        }
        const int ct_g = (colbase >> 4) + ct_l;
        const int kt_g = (ktbase >> 5) + kt_l;
        const size_t off = (size_t)(ct_g * 8 + kt_g) * 64 + l;
        dhi[off] = *reinterpret_cast<uint4*>(&h);
        dlo[off] = *reinterpret_cast<uint4*>(&lo);
    }
}

// ---------------------------------------------------------------------------
// MFMA distance + per-row top-8 (in clamped d2 domain; monotone == dist).
// Grid: 32 rowtiles * 8 colsplits = 256 blocks; 256 threads = 4 waves.
// Block: 128 rows x 2048 cols. Wave w: rowgroups w and w+4 (16 rows each),
// all 2048 cols. Swapped operands: A = xp cols (M), B = xi rows (N) so the
// D column (lane&15) is one xi-row -> lane-local selection.
// xp frags streamed global->LDS (double buffer); xi frags pinned in VGPRs.
// ---------------------------------------------------------------------------
__global__ __launch_bounds__(256, 1)
void dist_topk_mfma(const uint4* __restrict__ xpBhi, const uint4* __restrict__ xpBlo,
                    const uint4* __restrict__ xiBhi, const uint4* __restrict__ xiBlo,
                    const float* __restrict__ normI, const float* __restrict__ normP,
                    float* __restrict__ candV, int* __restrict__ candI) {
    __shared__ __align__(16) char Abuf[2][16384];   // [buf][part*8192 + kt*1024 + lane*16]
    __shared__ float nPl[2048];
    __shared__ float mVal[2048];
    __shared__ int   mIdx[2048];

    const int t = threadIdx.x;
    const int w = t >> 6;       // wave 0..3
    const int l = t & 63;       // lane
    const int rt = blockIdx.x >> 3;
    const int cs = blockIdx.x & 7;
    const int colbase = cs * 2048;

    for (int i = t; i < 2048; i += 256) nPl[i] = normP[colbase + i];

    // xi fragments (pinned): rowgroups rgA = w, rgB = w+4
    half8 bhA[8], blA[8], bhB[8], blB[8];
    const int ctA = rt * 8 + w;
    const int ctB = ctA + 4;
#pragma unroll
    for (int kt = 0; kt < 8; ++kt) {
        bhA[kt] = *reinterpret_cast<const half8*>(&xiBhi[(size_t)(ctA * 8 + kt) * 64 + l]);
        blA[kt] = *reinterpret_cast<const half8*>(&xiBlo[(size_t)(ctA * 8 + kt) * 64 + l]);
        bhB[kt] = *reinterpret_cast<const half8*>(&xiBhi[(size_t)(ctB * 8 + kt) * 64 + l]);
        blB[kt] = *reinterpret_cast<const half8*>(&xiBlo[(size_t)(ctB * 8 + kt) * 64 + l]);
    }
    const float nIA = normI[rt * 128 + w * 16 + (l & 15)];
    const float nIB = normI[rt * 128 + (w + 4) * 16 + (l & 15)];

    float bvA[8], bvB[8]; int biA[8], biB[8];
#pragma unroll
    for (int j = 0; j < 8; ++j) { bvA[j] = 3.4e38f; bvB[j] = 3.4e38f; biA[j] = -1; biB[j] = -1; }
    float worstA = 3.4e38f, worstB = 3.4e38f;
    int wpA = 0, wpB = 0;

    // stage xp col-tile ct into Abuf[buf]: wave0 -> hi (part 0), wave1 -> lo (part 1)
    auto stage = [&](int ct, int buf) {
        if (w < 2) {
            const char* gb  = (const char*)(w == 0 ? xpBhi : xpBlo);
            const char* src = gb + (size_t)(cs * 128 + ct) * 8192 + l * 16;
            char* db = &Abuf[buf][w * 8192];
#pragma unroll
            for (int kt = 0; kt < 8; ++kt)
                __builtin_amdgcn_global_load_lds(
                    (const __attribute__((address_space(1))) void*)(src + kt * 1024),
                    (__attribute__((address_space(3))) void*)(db + kt * 1024),
                    16, 0, 0);
        }
    };

    stage(0, 0);
    asm volatile("s_waitcnt vmcnt(0)" ::: "memory");
    __syncthreads();

    for (int ct = 0; ct < 128; ++ct) {
        if (ct < 127) stage(ct + 1, (ct + 1) & 1);

        const char* Ab = Abuf[ct & 1];
        const float4 np4 = *reinterpret_cast<const float4*>(&nPl[ct * 16 + ((l >> 4) << 2)]);

        f32x4 hhA = {0.f,0.f,0.f,0.f}, hlA = {0.f,0.f,0.f,0.f}, lhA = {0.f,0.f,0.f,0.f};
        f32x4 hhB = {0.f,0.f,0.f,0.f}, hlB = {0.f,0.f,0.f,0.f}, lhB = {0.f,0.f,0.f,0.f};
#pragma unroll
        for (int kt = 0; kt < 8; ++kt) {
            const half8 ah = *reinterpret_cast<const half8*>(Ab + kt * 1024 + l * 16);
            const half8 al = *reinterpret_cast<const half8*>(Ab + 8192 + kt * 1024 + l * 16);
            hhA = __builtin_amdgcn_mfma_f32_16x16x32_f16(ah, bhA[kt], hhA, 0, 0, 0);
            hlA = __builtin_amdgcn_mfma_f32_16x16x32_f16(ah, blA[kt], hlA, 0, 0, 0);
            lhA = __builtin_amdgcn_mfma_f32_16x16x32_f16(al, bhA[kt], lhA, 0, 0, 0);
            hhB = __builtin_amdgcn_mfma_f32_16x16x32_f16(ah, bhB[kt], hhB, 0, 0, 0);
            hlB = __builtin_amdgcn_mfma_f32_16x16x32_f16(ah, blB[kt], hlB, 0, 0, 0);
            lhB = __builtin_amdgcn_mfma_f32_16x16x32_f16(al, bhB[kt], lhB, 0, 0, 0);
        }

        const int cb = colbase + ct * 16 + ((l >> 4) << 2);
        const float npv[4] = {np4.x, np4.y, np4.z, np4.w};
#pragma unroll
        for (int j = 0; j < 4; ++j) {
            const float sA = hhA[j] + hlA[j] + lhA[j];
            const float dA = fmaxf(nIA + npv[j] - 2.0f * sA, 0.0f);
            TOPK_UPDATE(bvA, biA, worstA, wpA, dA, cb + j);
            const float sB = hhB[j] + hlB[j] + lhB[j];
            const float dB = fmaxf(nIB + npv[j] - 2.0f * sB, 0.0f);
            TOPK_UPDATE(bvB, biB, worstB, wpB, dB, cb + j);
        }

        asm volatile("s_waitcnt vmcnt(0)" ::: "memory");
        __syncthreads();
    }

    // merge: pass A (rows rt*128 + 0..63), pass B (rows rt*128 + 64..127)
#define DUMP_AND_MERGE(BV, BI, ROWOFF)                                          \
    {                                                                           \
        __syncthreads();                                                        \
        _Pragma("unroll")                                                       \
        for (int j = 0; j < 8; ++j) { mVal[t * 8 + j] = BV[j]; mIdx[t * 8 + j] = BI[j]; } \
        __syncthreads();                                                        \
        if (t < 64) {                                                           \
            float sv[8]; int si[8];                                             \
            _Pragma("unroll")                                                   \
            for (int j = 0; j < 8; ++j) { sv[j] = 3.4e38f; si[j] = -1; }        \
            float wv = 3.4e38f; int wp = 0;                                     \
            for (int g = 0; g < 4; ++g) {                                       \
                const int fl = ((t >> 4) << 6) + (t & 15) + 16 * g;             \
                _Pragma("unroll")                                               \
                for (int j = 0; j < 8; ++j) {                                   \
                    const float v = mVal[fl * 8 + j];                           \
                    TOPK_UPDATE(sv, si, wv, wp, v, mIdx[fl * 8 + j]);           \
                }                                                               \
            }                                                                   \
            for (int a = 1; a < 8; ++a) {                                       \
                float v = sv[a]; int ii = si[a]; int b2 = a - 1;                \
                while (b2 >= 0 && sv[b2] > v) { sv[b2+1] = sv[b2]; si[b2+1] = si[b2]; --b2; } \
                sv[b2+1] = v; si[b2+1] = ii;                                    \
            }                                                                   \
            const int row = rt * 128 + (ROWOFF) + t;                            \
            _Pragma("unroll")                                                   \
            for (int j = 0; j < 8; ++j) {                                       \
                candV[row * 64 + cs * 8 + j] = sv[j];                           \
                candI[row * 64 + cs * 8 + j] = si[j];                           \
            }                                                                   \
        }                                                                       \
    }

    DUMP_AND_MERGE(bvA, biA, 0)
    DUMP_AND_MERGE(bvB, biB, 64)
#undef DUMP_AND_MERGE
}

// ---------------------------------------------------------------------------
// MLP GEMM (unchanged from baseline)
// ---------------------------------------------------------------------------
template <int CIN, int COUT, bool PIXIN, bool BNIN>
__global__ __launch_bounds__(256)
void mlp_gemm_kernel(const float* __restrict__ X, int rows,
                     const float* __restrict__ W, const float* __restrict__ bias,
                     const float* __restrict__ stats, const float* __restrict__ g,
                     const float* __restrict__ be, float invDenom,
                     float* __restrict__ outT) {
    constexpr int PW  = COUT + 4;
    constexpr int OPT = COUT / 4;
    constexpr int LOGC = (CIN == 256) ? 8 : 7;
    __shared__ __align__(16) float Wl[CIN][PW];
    __shared__ float scL[CIN], shL[CIN];

    const int t = threadIdx.x;
    for (int i = t; i < CIN * COUT; i += 256) {
        int k = i >> LOGC, c = i & (CIN - 1);
        Wl[c][k] = W[i];
    }
    if (BNIN) {
        for (int c = t; c < CIN; c += 256) {
            float mean = stats[c] * invDenom;
            float var  = stats[CIN + c] * invDenom - mean * mean;
            float sc   = rsqrtf(var + 1e-5f) * g[c];
            scL[c] = sc;
            shL[c] = be[c] - mean * sc;
        }
    }
    __syncthreads();

    const int r   = blockIdx.x * 128 + (t & 63);
    const int r2  = r + 64;
    const int chb = (t >> 6) * OPT;

    float acc0[OPT], acc1[OPT];
#pragma unroll
    for (int q = 0; q < OPT; ++q) { acc0[q] = 0.0f; acc1[q] = 0.0f; }

#pragma unroll 2
    for (int c = 0; c < CIN; ++c) {
        float x0, x1;
        if (PIXIN) {
            x0 = X[(r  >> 12) * (CDIM * 4096) + c * 4096 + (r  & 4095)];
            x1 = X[(r2 >> 12) * (CDIM * 4096) + c * 4096 + (r2 & 4095)];
        } else {
            x0 = X[c * rows + r];
            x1 = X[c * rows + r2];
        }
        if (BNIN) {
            x0 = fmaxf(fmaf(x0, scL[c], shL[c]), 0.0f);
            x1 = fmaxf(fmaf(x1, scL[c], shL[c]), 0.0f);
        }
#pragma unroll
        for (int q = 0; q < OPT / 4; ++q) {
            const float4 wv = *reinterpret_cast<const float4*>(&Wl[c][chb + 4 * q]);
            acc0[4 * q + 0] = fmaf(x0, wv.x, acc0[4 * q + 0]);
            acc0[4 * q + 1] = fmaf(x0, wv.y, acc0[4 * q + 1]);
            acc0[4 * q + 2] = fmaf(x0, wv.z, acc0[4 * q + 2]);
            acc0[4 * q + 3] = fmaf(x0, wv.w, acc0[4 * q + 3]);
            acc1[4 * q + 0] = fmaf(x1, wv.x, acc1[4 * q + 0]);
            acc1[4 * q + 1] = fmaf(x1, wv.y, acc1[4 * q + 1]);
            acc1[4 * q + 2] = fmaf(x1, wv.z, acc1[4 * q + 2]);
            acc1[4 * q + 3] = fmaf(x1, wv.w, acc1[4 * q + 3]);
        }
    }
#pragma unroll
    for (int q = 0; q < OPT; ++q) {
        const int k = chb + q;
        const float b = bias[k];
        outT[k * rows + r]  = acc0[q] + b;
        outT[k * rows + r2] = acc1[q] + b;
    }
}

__global__ __launch_bounds__(256)
void colstats_kernel(const float* __restrict__ H, int rows,
                     float* __restrict__ stats, int C) {
    __shared__ float rs[256], rq[256];
    const int c = blockIdx.x;
    const int t = threadIdx.x;
    float s = 0.0f, q = 0.0f;
    for (int r = t; r < rows; r += 256) {
        float v = H[c * rows + r];
        s += v;
        q = fmaf(v, v, q);
    }
    rs[t] = s; rq[t] = q;
    __syncthreads();
    for (int st = 128; st > 0; st >>= 1) {
        if (t < st) { rs[t] += rs[t + st]; rq[t] += rq[t + st]; }
        __syncthreads();
    }
    if (t == 0) { stats[c] = rs[0]; stats[C + c] = rq[0]; }
}

__global__ __launch_bounds__(256)
void a_kernel(const float* __restrict__ H2T, int rows,
              const float* __restrict__ stats, const float* __restrict__ g,
              const float* __restrict__ be, const float* __restrict__ cw,
              const float* __restrict__ cb, float* __restrict__ aout,
              float invDenom) {
    __shared__ float scL[64], shL[64], cwL[64];
    const int t = threadIdx.x;
    if (t < 64) {
        float mean = stats[t] * invDenom;
        float var  = stats[64 + t] * invDenom - mean * mean;
        float sc   = rsqrtf(var + 1e-5f) * g[t];
        scL[t] = sc;
        shL[t] = be[t] - mean * sc;
        cwL[t] = cw[t];
    }
    __syncthreads();
    const int row = blockIdx.x * 256 + t;
    if (row < rows) {
        float a = 0.0f;
        for (int c = 0; c < 64; ++c) {
            float v = H2T[c * rows + row];
            a += fmaxf(fmaf(v, scL[c], shL[c]), 0.0f) * cwL[c];
        }
        aout[row] = a + cb[0];
    }
}

// ---------------------------------------------------------------------------
// Final: merge 64 candidates/row, softplus->softmax over kNN, gather style.
// ---------------------------------------------------------------------------
__global__ __launch_bounds__(256)
void out_kernel(const float* __restrict__ candV, const int* __restrict__ candI,
                const float* __restrict__ a1, const float* __restrict__ a2,
                const float* __restrict__ PS, float* __restrict__ dout) {
    __shared__ float wL[64][8];
    __shared__ int   aL[64][8];
    const int t  = threadIdx.x;
    const int nb = blockIdx.x * 64;

    if (t < 64) {
        const int row = nb + t;
        float sv[8]; int si[8];
#pragma unroll
        for (int j = 0; j < 8; ++j) { sv[j] = 3.4e38f; si[j] = 0; }
        float w2 = 3.4e38f; int wp = 0;
        for (int k = 0; k < 64; ++k) {
            const float v = candV[row * 64 + k];
            TOPK_UPDATE(sv, si, w2, wp, v, candI[row * 64 + k]);
        }
        for (int a = 1; a < 8; ++a) {
            float v = sv[a]; int ii = si[a]; int b = a - 1;
            while (b >= 0 && sv[b] > v) { sv[b + 1] = sv[b]; si[b + 1] = si[b]; --b; }
            sv[b + 1] = v; si[b + 1] = ii;
        }
        const float kth = sv[4];
        int cnt = 5;
        while (cnt < 8 && sv[cnt] <= kth) ++cnt;

        const float arow = a1[row];
        float s[8], e[8];
        float mx = -1e30f;
#pragma unroll
        for (int j = 0; j < 8; ++j) s[j] = 0.0f;
        for (int j = 0; j < cnt; ++j) {
            s[j] = softplusf(arow + a2[si[j]]);
            mx = fmaxf(mx, s[j]);
        }
        float Z = 0.0f;
        for (int j = 0; j < 8; ++j) {
            e[j] = (j < cnt) ? expf(s[j] - mx) : 0.0f;
            Z += e[j];
        }
        for (int j = 0; j < 8; ++j) {
            const int ix = (j < cnt) ? si[j] : si[0];
            wL[t][j] = e[j] / Z;
            aL[t][j] = (ix >> 12) * (CDIM * 4096) + (ix & 4095);
        }
    }
    __syncthreads();

    const int rl  = t & 63;
    const int grp = t >> 6;
    float w[8]; int ab[8];
#pragma unroll
    for (int j = 0; j < 8; ++j) { w[j] = wL[rl][j]; ab[j] = aL[rl][j]; }
    const int n = nb + rl;
    for (int c = grp * 64; c < grp * 64 + 64; ++c) {
        float acc = 0.0f;
#pragma unroll
        for (int j = 0; j < 8; ++j) acc += w[j] * PS[ab[j] + c * 4096];
        dout[(CDIM + c) * 4096 + n] = acc;
    }
}

// ---------------------------------------------------------------------------
extern "C" void kernel_launch(void* const* d_in, const int* in_sizes, int n_in,
                              void* d_out, int out_size, void* d_ws, size_t ws_size,
                              hipStream_t stream) {
    const float* inp_cont    = (const float*)d_in[0];
    const float* peers_cont  = (const float*)d_in[2];
    const float* peers_style = (const float*)d_in[3];
    const float* W1  = (const float*)d_in[4];
    const float* b1  = (const float*)d_in[5];
    const float* g1  = (const float*)d_in[6];
    const float* be1 = (const float*)d_in[7];
    const float* W2  = (const float*)d_in[8];
    const float* b2  = (const float*)d_in[9];
    const float* g2  = (const float*)d_in[10];
    const float* be2 = (const float*)d_in[11];
    const float* cw1 = (const float*)d_in[12];
    const float* cb1 = (const float*)d_in[13];
    const float* cw2 = (const float*)d_in[14];
    const float* cb2 = (const float*)d_in[15];
    float* out = (float*)d_out;
    char*  wsb = (char*)d_ws;

    if (ws_size < (size_t)23400000) return;

    // workspace layout (bytes)
    uint4* xpBhi = (uint4*)(wsb + 0);                    //  8,388,608
    uint4* xpBlo = (uint4*)(wsb + 8388608);              //  8,388,608
    uint4* xiBhi = (uint4*)(wsb + 16777216);             //  2,097,152
    uint4* xiBlo = (uint4*)(wsb + 18874368);             //  2,097,152
    float* normP = (float*)(wsb + 20971520);             //     65,536
    float* normI = (float*)(wsb + 21037056);             //     16,384
    float* candV = (float*)(wsb + 21053440);             //  1,048,576
    int*   candI = (int*)  (wsb + 22102016);             //  1,048,576
    float* a2    = (float*)(wsb + 23150592);             //     65,536
    float* a1    = (float*)(wsb + 23216128);             //     16,384
    float* s1p   = (float*)(wsb + 23232512);             //      1,024
    float* s1i   = (float*)(wsb + 23233536);             //      1,024
    float* s2p   = (float*)(wsb + 23234560);             //        512
    float* s2i   = (float*)(wsb + 23235072);             //        512
    // Aliased AFTER dist kernel completes (xpB/xiB dead by then):
    float* H1Tp  = (float*)(wsb + 0);                    // 128*16384*4 = 8 MB
    float* H2Tp  = (float*)(wsb + 8388608);              //  64*16384*4 = 4 MB
    float* H1Ti  = (float*)(wsb + 16777216);             // 128*4096*4  = 2 MB
    float* H2Ti  = (float*)(wsb + 18874368);             //  64*4096*4  = 1 MB

    // passthrough channels 0..255
    copy_kernel<<<1024, 256, 0, stream>>>((const float4*)inp_cont, (float4*)out, 262144);

    // norms from original fp32
    norms_kernel<<<80, 256, 0, stream>>>(inp_cont, peers_cont, normI, normP);

    // fp16 hi/lo fragment-ready conversion
    convert_kernel<<<256, 256, 0, stream>>>(inp_cont, xiBhi, xiBlo, 4096);
    convert_kernel<<<1024, 256, 0, stream>>>(peers_cont, xpBhi, xpBlo, 16384);

    // MFMA distance + top-k
    dist_topk_mfma<<<256, 256, 0, stream>>>(xpBhi, xpBlo, xiBhi, xiBlo,
                                            normI, normP, candV, candI);

    // MLP branch (reuses xpB/xiB space)
    mlp_gemm_kernel<256, 128, true, false><<<128, 256, 0, stream>>>(
        peers_cont, 16384, W1, b1, nullptr, nullptr, nullptr, 0.0f, H1Tp);
    mlp_gemm_kernel<256, 128, true, false><<<32, 256, 0, stream>>>(
        inp_cont, 4096, W1, b1, nullptr, nullptr, nullptr, 0.0f, H1Ti);
    colstats_kernel<<<128, 256, 0, stream>>>(H1Tp, 16384, s1p, 128);
    colstats_kernel<<<128, 256, 0, stream>>>(H1Ti, 4096, s1i, 128);
    mlp_gemm_kernel<128, 64, false, true><<<128, 256, 0, stream>>>(
        H1Tp, 16384, W2, b2, s1p, g1, be1, 1.0f / 16384.0f, H2Tp);
    mlp_gemm_kernel<128, 64, false, true><<<32, 256, 0, stream>>>(
        H1Ti, 4096, W2, b2, s1i, g1, be1, 1.0f / 4096.0f, H2Ti);
    colstats_kernel<<<64, 256, 0, stream>>>(H2Tp, 16384, s2p, 64);
    colstats_kernel<<<64, 256, 0, stream>>>(H2Ti, 4096, s2i, 64);
    a_kernel<<<64, 256, 0, stream>>>(H2Tp, 16384, s2p, g2, be2, cw2, cb2, a2, 1.0f / 16384.0f);
    a_kernel<<<16, 256, 0, stream>>>(H2Ti, 4096, s2i, g2, be2, cw1, cb1, a1, 1.0f / 4096.0f);

    // final gather
    out_kernel<<<64, 256, 0, stream>>>(candV, candI, a1, a2, peers_style, out);
}

// Round 6
// 582.763 us; speedup vs baseline: 2.0534x; 1.0599x over previous
//
#include <hip/hip_runtime.h>
#include <math.h>

#define NROWS 4096
#define MCOLS 16384
#define CDIM  256

typedef _Float16 half8 __attribute__((ext_vector_type(8)));
typedef float f32x4 __attribute__((ext_vector_type(4)));

static __device__ __forceinline__ float softplusf(float x) {
    return fmaxf(x, 0.0f) + log1pf(expf(-fabsf(x)));
}

#define TOPK_UPDATE(BV, BI, WORST, WP, V, IDX)                                 \
    if ((V) < (WORST)) {                                                       \
        BV[WP] = (V); BI[WP] = (IDX);                                          \
        WORST = BV[0]; WP = 0;                                                 \
        _Pragma("unroll")                                                      \
        for (int _q = 1; _q < 8; ++_q)                                         \
            if (BV[_q] > WORST) { WORST = BV[_q]; WP = _q; }                   \
    }

// ---------------------------------------------------------------------------
// Passthrough copy
// ---------------------------------------------------------------------------
__global__ __launch_bounds__(256)
void copy_kernel(const float4* __restrict__ src, float4* __restrict__ dst, int n4) {
    int i = blockIdx.x * blockDim.x + threadIdx.x;
    if (i < n4) dst[i] = src[i];
}

// ---------------------------------------------------------------------------
// Column norms from ORIGINAL fp32 data (fp64 accumulate).
// ---------------------------------------------------------------------------
__global__ __launch_bounds__(256)
void norms_kernel(const float* __restrict__ xiT, const float* __restrict__ xpT,
                  float* __restrict__ normI, float* __restrict__ normP) {
    int i = blockIdx.x * blockDim.x + threadIdx.x;
    if (i >= MCOLS + NROWS) return;
    const float* p;
    int base;
    if (i < MCOLS) { p = xpT; base = (i >> 12) * (CDIM * 4096) + (i & 4095); }
    else           { p = xiT; base = i - MCOLS; }
    double s = 0.0;
    for (int c = 0; c < CDIM; ++c) {
        float v = p[base + c * 4096];
        s = fma((double)v, (double)v, s);
    }
    if (i < MCOLS) normP[i] = (float)s;
    else           normI[i - MCOLS] = (float)s;
}

// ---------------------------------------------------------------------------
// fp32 [K=256][cols] (batched pixel layout) -> fragment-ready fp16 hi/lo.
// chunk (ct*8 + kt)*64 + lane holds 8 halves:
//   element = x[col = ct*16 + (lane&15)][k = kt*32 + (lane>>4)*8 + j]
// ---------------------------------------------------------------------------
__global__ __launch_bounds__(256)
void convert_kernel(const float* __restrict__ src, uint4* __restrict__ dhi,
                    uint4* __restrict__ dlo, int ncols) {
    __shared__ float S[64][65];
    const int t = threadIdx.x;
    const int tilesPerRow = ncols >> 6;
    const int colbase = (blockIdx.x % tilesPerRow) << 6;
    const int ktbase  = (blockIdx.x / tilesPerRow) << 6;
    const int b = colbase >> 12;
    const int pixbase = colbase & 4095;
    const float* sp = src + (size_t)b * (CDIM * 4096) + (size_t)ktbase * 4096 + pixbase;

    for (int i = t; i < 4096; i += 256) {
        int kk = i >> 6, cc = i & 63;
        S[kk][cc] = sp[kk * 4096 + cc];
    }
    __syncthreads();

    const int l = t & 63;
#pragma unroll
    for (int s = 0; s < 2; ++s) {
        const int pid  = (t >> 6) + 4 * s;
        const int ct_l = pid & 3;
        const int kt_l = pid >> 2;
        const int c_l  = ct_l * 16 + (l & 15);
        const int k_l  = kt_l * 32 + ((l >> 4) << 3);
        half8 h, lo;
#pragma unroll
        for (int j = 0; j < 8; ++j) {
            float v = S[k_l + j][c_l];
            _Float16 hv = (_Float16)v;
            h[j]  = hv;
            lo[j] = (_Float16)(v - (float)hv);
        }
        const int ct_g = (colbase >> 4) + ct_l;
        const int kt_g = (ktbase >> 5) + kt_l;
        const size_t off = (size_t)(ct_g * 8 + kt_g) * 64 + l;
        dhi[off] = *reinterpret_cast<uint4*>(&h);
        dlo[off] = *reinterpret_cast<uint4*>(&lo);
    }
}

// ---------------------------------------------------------------------------
// MFMA distance + per-row top-8 (clamped d2 domain; monotone == dist).
// Grid: 64 rowtiles (64 rows) * nsplit colsplits; 128 threads = 2 waves.
// Wave w owns rowgroups w and w+2 (16 rows each).
// Swapped operands: A = xp cols, B = xi rows -> D column (lane&15) = xi row.
// xp hi/lo streamed global->LDS double-buffered (wave0 hi, wave1 lo).
// ---------------------------------------------------------------------------
__global__ __launch_bounds__(128, 2)
void dist_topk_mfma(const uint4* __restrict__ xpBhi, const uint4* __restrict__ xpBlo,
                    const uint4* __restrict__ xiBhi, const uint4* __restrict__ xiBlo,
                    const float* __restrict__ normI, const float* __restrict__ normP,
                    float* __restrict__ candV, int* __restrict__ candI,
                    int nsplit) {
    __shared__ __align__(16) char Abuf[2][16384];   // [buf][part*8192 + kt*1024 + lane*16]

    const int t = threadIdx.x;
    const int w = t >> 6;       // wave 0..1
    const int l = t & 63;       // lane
    const int rt = blockIdx.x / nsplit;   // 0..63
    const int cs = blockIdx.x % nsplit;
    const int niter = (MCOLS / 16) / nsplit;     // 128 (ns=8) or 64 (ns=16)
    const int colbase = cs * (MCOLS / nsplit);
    const int ncand = nsplit * 8;

    // xi fragments (register-resident): rowgroups rgA = w, rgB = w+2
    uint4 bhA[8], blA[8], bhB[8], blB[8];
    const int ctA = rt * 4 + w;
    const int ctB = ctA + 2;
#pragma unroll
    for (int kt = 0; kt < 8; ++kt) {
        bhA[kt] = xiBhi[(size_t)(ctA * 8 + kt) * 64 + l];
        blA[kt] = xiBlo[(size_t)(ctA * 8 + kt) * 64 + l];
        bhB[kt] = xiBhi[(size_t)(ctB * 8 + kt) * 64 + l];
        blB[kt] = xiBlo[(size_t)(ctB * 8 + kt) * 64 + l];
    }

    const float nIA = normI[rt * 64 + w * 16 + (l & 15)];
    const float nIB = normI[rt * 64 + (w + 2) * 16 + (l & 15)];

    float bvA[8], bvB[8]; int biA[8], biB[8];
#pragma unroll
    for (int j = 0; j < 8; ++j) { bvA[j] = 3.4e38f; bvB[j] = 3.4e38f; biA[j] = -1; biB[j] = -1; }
    float worstA = 3.4e38f, worstB = 3.4e38f;
    int wpA = 0, wpB = 0;

    // wave0 stages hi -> part 0, wave1 stages lo -> part 1 (same col-tile)
    const char* gb = (w & 1) ? (const char*)xpBlo : (const char*)xpBhi;
    auto stage = [&](int it, int buf) {
        const char* src = gb + (size_t)(cs * niter + it) * 8192 + l * 16;
        char* db = &Abuf[buf][w * 8192];
#pragma unroll
        for (int kt = 0; kt < 8; ++kt)
            __builtin_amdgcn_global_load_lds(
                (const __attribute__((address_space(1))) void*)(src + kt * 1024),
                (__attribute__((address_space(3))) void*)(db + kt * 1024),
                16, 0, 0);
    };

    stage(0, 0);
    asm volatile("s_waitcnt vmcnt(0)" ::: "memory");
    __syncthreads();

    for (int it = 0; it < niter; ++it) {
        if (it < niter - 1) stage(it + 1, (it + 1) & 1);

        const char* Ab = Abuf[it & 1];
        const int cb = colbase + it * 16 + ((l >> 4) << 2);
        const float4 np4 = *reinterpret_cast<const float4*>(&normP[cb]);

        f32x4 hhA = {0.f,0.f,0.f,0.f}, hlA = {0.f,0.f,0.f,0.f}, lhA = {0.f,0.f,0.f,0.f};
        f32x4 hhB = {0.f,0.f,0.f,0.f}, hlB = {0.f,0.f,0.f,0.f}, lhB = {0.f,0.f,0.f,0.f};
#pragma unroll
        for (int kt = 0; kt < 8; ++kt) {
            const half8 ah = *reinterpret_cast<const half8*>(Ab + kt * 1024 + l * 16);
            const half8 al = *reinterpret_cast<const half8*>(Ab + 8192 + kt * 1024 + l * 16);
            const half8 vhA = *reinterpret_cast<const half8*>(&bhA[kt]);
            const half8 vlA = *reinterpret_cast<const half8*>(&blA[kt]);
            const half8 vhB = *reinterpret_cast<const half8*>(&bhB[kt]);
            const half8 vlB = *reinterpret_cast<const half8*>(&blB[kt]);
            hhA = __builtin_amdgcn_mfma_f32_16x16x32_f16(ah, vhA, hhA, 0, 0, 0);
            hlA = __builtin_amdgcn_mfma_f32_16x16x32_f16(ah, vlA, hlA, 0, 0, 0);
            lhA = __builtin_amdgcn_mfma_f32_16x16x32_f16(al, vhA, lhA, 0, 0, 0);
            hhB = __builtin_amdgcn_mfma_f32_16x16x32_f16(ah, vhB, hhB, 0, 0, 0);
            hlB = __builtin_amdgcn_mfma_f32_16x16x32_f16(ah, vlB, hlB, 0, 0, 0);
            lhB = __builtin_amdgcn_mfma_f32_16x16x32_f16(al, vhB, lhB, 0, 0, 0);
        }

        const float npv[4] = {np4.x, np4.y, np4.z, np4.w};
#pragma unroll
        for (int j = 0; j < 4; ++j) {
            const float sA = hhA[j] + hlA[j] + lhA[j];
            const float dA = fmaxf(nIA + npv[j] - 2.0f * sA, 0.0f);
            TOPK_UPDATE(bvA, biA, worstA, wpA, dA, cb + j);
            const float sB = hhB[j] + hlB[j] + lhB[j];
            const float dB = fmaxf(nIB + npv[j] - 2.0f * sB, 0.0f);
            TOPK_UPDATE(bvB, biB, worstB, wpB, dB, cb + j);
        }

        asm volatile("s_waitcnt vmcnt(0)" ::: "memory");
        __syncthreads();
    }

    // merge scratch aliased onto Abuf (staging dead now)
    float* mVal = (float*)&Abuf[0][0];
    int*   mIdx = (int*)&Abuf[0][8192];

#define DUMP_AND_MERGE(BV, BI, ROWOFF)                                          \
    {                                                                           \
        __syncthreads();                                                        \
        _Pragma("unroll")                                                       \
        for (int j = 0; j < 8; ++j) { mVal[t * 8 + j] = BV[j]; mIdx[t * 8 + j] = BI[j]; } \
        __syncthreads();                                                        \
        if (t < 32) {                                                           \
            float sv[8]; int si[8];                                             \
            _Pragma("unroll")                                                   \
            for (int j = 0; j < 8; ++j) { sv[j] = 3.4e38f; si[j] = -1; }        \
            float wv = 3.4e38f; int wp = 0;                                     \
            for (int g = 0; g < 4; ++g) {                                       \
                const int fl = ((t >> 4) << 6) + (t & 15) + 16 * g;             \
                _Pragma("unroll")                                               \
                for (int j = 0; j < 8; ++j) {                                   \
                    const float v = mVal[fl * 8 + j];                           \
                    TOPK_UPDATE(sv, si, wv, wp, v, mIdx[fl * 8 + j]);           \
                }                                                               \
            }                                                                   \
            for (int a = 1; a < 8; ++a) {                                       \
                float v = sv[a]; int ii = si[a]; int b2 = a - 1;                \
                while (b2 >= 0 && sv[b2] > v) { sv[b2+1] = sv[b2]; si[b2+1] = si[b2]; --b2; } \
                sv[b2+1] = v; si[b2+1] = ii;                                    \
            }                                                                   \
            const int row = rt * 64 + (ROWOFF) + t;                             \
            _Pragma("unroll")                                                   \
            for (int j = 0; j < 8; ++j) {                                       \
                candV[row * ncand + cs * 8 + j] = sv[j];                        \
                candI[row * ncand + cs * 8 + j] = si[j];                        \
            }                                                                   \
        }                                                                       \
    }

    DUMP_AND_MERGE(bvA, biA, 0)
    DUMP_AND_MERGE(bvB, biB, 32)
#undef DUMP_AND_MERGE
}

// ---------------------------------------------------------------------------
// MLP GEMM (unchanged)
// ---------------------------------------------------------------------------
template <int CIN, int COUT, bool PIXIN, bool BNIN>
__global__ __launch_bounds__(256)
void mlp_gemm_kernel(const float* __restrict__ X, int rows,
                     const float* __restrict__ W, const float* __restrict__ bias,
                     const float* __restrict__ stats, const float* __restrict__ g,
                     const float* __restrict__ be, float invDenom,
                     float* __restrict__ outT) {
    constexpr int PW  = COUT + 4;
    constexpr int OPT = COUT / 4;
    constexpr int LOGC = (CIN == 256) ? 8 : 7;
    __shared__ __align__(16) float Wl[CIN][PW];
    __shared__ float scL[CIN], shL[CIN];

    const int t = threadIdx.x;
    for (int i = t; i < CIN * COUT; i += 256) {
        int k = i >> LOGC, c = i & (CIN - 1);
        Wl[c][k] = W[i];
    }
    if (BNIN) {
        for (int c = t; c < CIN; c += 256) {
            float mean = stats[c] * invDenom;
            float var  = stats[CIN + c] * invDenom - mean * mean;
            float sc   = rsqrtf(var + 1e-5f) * g[c];
            scL[c] = sc;
            shL[c] = be[c] - mean * sc;
        }
    }
    __syncthreads();

    const int r   = blockIdx.x * 128 + (t & 63);
    const int r2  = r + 64;
    const int chb = (t >> 6) * OPT;

    float acc0[OPT], acc1[OPT];
#pragma unroll
    for (int q = 0; q < OPT; ++q) { acc0[q] = 0.0f; acc1[q] = 0.0f; }

#pragma unroll 2
    for (int c = 0; c < CIN; ++c) {
        float x0, x1;
        if (PIXIN) {
            x0 = X[(r  >> 12) * (CDIM * 4096) + c * 4096 + (r  & 4095)];
            x1 = X[(r2 >> 12) * (CDIM * 4096) + c * 4096 + (r2 & 4095)];
        } else {
            x0 = X[c * rows + r];
            x1 = X[c * rows + r2];
        }
        if (BNIN) {
            x0 = fmaxf(fmaf(x0, scL[c], shL[c]), 0.0f);
            x1 = fmaxf(fmaf(x1, scL[c], shL[c]), 0.0f);
        }
#pragma unroll
        for (int q = 0; q < OPT / 4; ++q) {
            const float4 wv = *reinterpret_cast<const float4*>(&Wl[c][chb + 4 * q]);
            acc0[4 * q + 0] = fmaf(x0, wv.x, acc0[4 * q + 0]);
            acc0[4 * q + 1] = fmaf(x0, wv.y, acc0[4 * q + 1]);
            acc0[4 * q + 2] = fmaf(x0, wv.z, acc0[4 * q + 2]);
            acc0[4 * q + 3] = fmaf(x0, wv.w, acc0[4 * q + 3]);
            acc1[4 * q + 0] = fmaf(x1, wv.x, acc1[4 * q + 0]);
            acc1[4 * q + 1] = fmaf(x1, wv.y, acc1[4 * q + 1]);
            acc1[4 * q + 2] = fmaf(x1, wv.z, acc1[4 * q + 2]);
            acc1[4 * q + 3] = fmaf(x1, wv.w, acc1[4 * q + 3]);
        }
    }
#pragma unroll
    for (int q = 0; q < OPT; ++q) {
        const int k = chb + q;
        const float b = bias[k];
        outT[k * rows + r]  = acc0[q] + b;
        outT[k * rows + r2] = acc1[q] + b;
    }
}

__global__ __launch_bounds__(256)
void colstats_kernel(const float* __restrict__ H, int rows,
                     float* __restrict__ stats, int C) {
    __shared__ float rs[256], rq[256];
    const int c = blockIdx.x;
    const int t = threadIdx.x;
    float s = 0.0f, q = 0.0f;
    for (int r = t; r < rows; r += 256) {
        float v = H[c * rows + r];
        s += v;
        q = fmaf(v, v, q);
    }
    rs[t] = s; rq[t] = q;
    __syncthreads();
    for (int st = 128; st > 0; st >>= 1) {
        if (t < st) { rs[t] += rs[t + st]; rq[t] += rq[t + st]; }
        __syncthreads();
    }
    if (t == 0) { stats[c] = rs[0]; stats[C + c] = rq[0]; }
}

__global__ __launch_bounds__(256)
void a_kernel(const float* __restrict__ H2T, int rows,
              const float* __restrict__ stats, const float* __restrict__ g,
              const float* __restrict__ be, const float* __restrict__ cw,
              const float* __restrict__ cb, float* __restrict__ aout,
              float invDenom) {
    __shared__ float scL[64], shL[64], cwL[64];
    const int t = threadIdx.x;
    if (t < 64) {
        float mean = stats[t] * invDenom;
        float var  = stats[64 + t] * invDenom - mean * mean;
        float sc   = rsqrtf(var + 1e-5f) * g[t];
        scL[t] = sc;
        shL[t] = be[t] - mean * sc;
        cwL[t] = cw[t];
    }
    __syncthreads();
    const int row = blockIdx.x * 256 + t;
    if (row < rows) {
        float a = 0.0f;
        for (int c = 0; c < 64; ++c) {
            float v = H2T[c * rows + row];
            a += fmaxf(fmaf(v, scL[c], shL[c]), 0.0f) * cwL[c];
        }
        aout[row] = a + cb[0];
    }
}

// ---------------------------------------------------------------------------
// Final: merge ncand candidates/row, softplus->softmax over kNN, gather style.
// ---------------------------------------------------------------------------
__global__ __launch_bounds__(256)
void out_kernel(const float* __restrict__ candV, const int* __restrict__ candI,
                const float* __restrict__ a1, const float* __restrict__ a2,
                const float* __restrict__ PS, float* __restrict__ dout, int ncand) {
    __shared__ float wL[64][8];
    __shared__ int   aL[64][8];
    const int t  = threadIdx.x;
    const int nb = blockIdx.x * 64;

    if (t < 64) {
        const int row = nb + t;
        float sv[8]; int si[8];
#pragma unroll
        for (int j = 0; j < 8; ++j) { sv[j] = 3.4e38f; si[j] = 0; }
        float w2 = 3.4e38f; int wp = 0;
        for (int k = 0; k < ncand; ++k) {
            const float v = candV[row * ncand + k];
            TOPK_UPDATE(sv, si, w2, wp, v, candI[row * ncand + k]);
        }
        for (int a = 1; a < 8; ++a) {
            float v = sv[a]; int ii = si[a]; int b = a - 1;
            while (b >= 0 && sv[b] > v) { sv[b + 1] = sv[b]; si[b + 1] = si[b]; --b; }
            sv[b + 1] = v; si[b + 1] = ii;
        }
        const float kth = sv[4];
        int cnt = 5;
        while (cnt < 8 && sv[cnt] <= kth) ++cnt;

        const float arow = a1[row];
        float s[8], e[8];
        float mx = -1e30f;
#pragma unroll
        for (int j = 0; j < 8; ++j) s[j] = 0.0f;
        for (int j = 0; j < cnt; ++j) {
            s[j] = softplusf(arow + a2[si[j]]);
            mx = fmaxf(mx, s[j]);
        }
        float Z = 0.0f;
        for (int j = 0; j < 8; ++j) {
            e[j] = (j < cnt) ? expf(s[j] - mx) : 0.0f;
            Z += e[j];
        }
        for (int j = 0; j < 8; ++j) {
            const int ix = (j < cnt) ? si[j] : si[0];
            wL[t][j] = e[j] / Z;
            aL[t][j] = (ix >> 12) * (CDIM * 4096) + (ix & 4095);
        }
    }
    __syncthreads();

    const int rl  = t & 63;
    const int grp = t >> 6;
    float w[8]; int ab[8];
#pragma unroll
    for (int j = 0; j < 8; ++j) { w[j] = wL[rl][j]; ab[j] = aL[rl][j]; }
    const int n = nb + rl;
    for (int c = grp * 64; c < grp * 64 + 64; ++c) {
        float acc = 0.0f;
#pragma unroll
        for (int j = 0; j < 8; ++j) acc += w[j] * PS[ab[j] + c * 4096];
        dout[(CDIM + c) * 4096 + n] = acc;
    }
}

// ---------------------------------------------------------------------------
extern "C" void kernel_launch(void* const* d_in, const int* in_sizes, int n_in,
                              void* d_out, int out_size, void* d_ws, size_t ws_size,
                              hipStream_t stream) {
    const float* inp_cont    = (const float*)d_in[0];
    const float* peers_cont  = (const float*)d_in[2];
    const float* peers_style = (const float*)d_in[3];
    const float* W1  = (const float*)d_in[4];
    const float* b1  = (const float*)d_in[5];
    const float* g1  = (const float*)d_in[6];
    const float* be1 = (const float*)d_in[7];
    const float* W2  = (const float*)d_in[8];
    const float* b2  = (const float*)d_in[9];
    const float* g2  = (const float*)d_in[10];
    const float* be2 = (const float*)d_in[11];
    const float* cw1 = (const float*)d_in[12];
    const float* cb1 = (const float*)d_in[13];
    const float* cw2 = (const float*)d_in[14];
    const float* cb2 = (const float*)d_in[15];
    float* out = (float*)d_out;
    char*  wsb = (char*)d_ws;

    // adaptive split count: 16 if workspace allows (2 waves/SIMD), else 8
    int nsplit;
    if      (ws_size >= (size_t)25400000) nsplit = 16;
    else if (ws_size >= (size_t)23300000) nsplit = 8;
    else return;
    const int ncand = nsplit * 8;
    const size_t candBytes = (size_t)NROWS * ncand * 4;

    // workspace layout (bytes)
    uint4* xpBhi = (uint4*)(wsb + 0);                    //  8 MB
    uint4* xpBlo = (uint4*)(wsb + 8388608);              //  8 MB
    uint4* xiBhi = (uint4*)(wsb + 16777216);             //  2 MB
    uint4* xiBlo = (uint4*)(wsb + 18874368);             //  2 MB
    float* normP = (float*)(wsb + 20971520);             //  64 KB
    float* normI = (float*)(wsb + 21037056);             //  16 KB
    float* candV = (float*)(wsb + 21053440);             //  candBytes
    int*   candI = (int*)  (wsb + 21053440 + candBytes); //  candBytes
    char*  tail  = wsb + 21053440 + 2 * candBytes;
    float* a2    = (float*)(tail);                       //  64 KB
    float* a1    = (float*)(tail + 65536);               //  16 KB
    float* s1p   = (float*)(tail + 81920);               //  1 KB
    float* s1i   = (float*)(tail + 82944);               //  1 KB
    float* s2p   = (float*)(tail + 83968);               //  512
    float* s2i   = (float*)(tail + 84480);               //  512
    // Aliased AFTER dist kernel completes (xpB/xiB dead by then):
    float* H1Tp  = (float*)(wsb + 0);                    // 8 MB
    float* H2Tp  = (float*)(wsb + 8388608);              // 4 MB
    float* H1Ti  = (float*)(wsb + 16777216);             // 2 MB
    float* H2Ti  = (float*)(wsb + 18874368);             // 1 MB

    // passthrough channels 0..255
    copy_kernel<<<1024, 256, 0, stream>>>((const float4*)inp_cont, (float4*)out, 262144);

    // norms from original fp32
    norms_kernel<<<80, 256, 0, stream>>>(inp_cont, peers_cont, normI, normP);

    // fp16 hi/lo fragment-ready conversion
    convert_kernel<<<256, 256, 0, stream>>>(inp_cont, xiBhi, xiBlo, 4096);
    convert_kernel<<<1024, 256, 0, stream>>>(peers_cont, xpBhi, xpBlo, 16384);

    // MFMA distance + top-k
    dist_topk_mfma<<<64 * nsplit, 128, 0, stream>>>(xpBhi, xpBlo, xiBhi, xiBlo,
                                                    normI, normP, candV, candI, nsplit);

    // MLP branch (reuses xpB/xiB space)
    mlp_gemm_kernel<256, 128, true, false><<<128, 256, 0, stream>>>(
        peers_cont, 16384, W1, b1, nullptr, nullptr, nullptr, 0.0f, H1Tp);
    mlp_gemm_kernel<256, 128, true, false><<<32, 256, 0, stream>>>(
        inp_cont, 4096, W1, b1, nullptr, nullptr, nullptr, 0.0f, H1Ti);
    colstats_kernel<<<128, 256, 0, stream>>>(H1Tp, 16384, s1p, 128);
    colstats_kernel<<<128, 256, 0, stream>>>(H1Ti, 4096, s1i, 128);
    mlp_gemm_kernel<128, 64, false, true><<<128, 256, 0, stream>>>(
        H1Tp, 16384, W2, b2, s1p, g1, be1, 1.0f / 16384.0f, H2Tp);
    mlp_gemm_kernel<128, 64, false, true><<<32, 256, 0, stream>>>(
        H1Ti, 4096, W2, b2, s1i, g1, be1, 1.0f / 4096.0f, H2Ti);
    colstats_kernel<<<64, 256, 0, stream>>>(H2Tp, 16384, s2p, 64);
    colstats_kernel<<<64, 256, 0, stream>>>(H2Ti, 4096, s2i, 64);
    a_kernel<<<64, 256, 0, stream>>>(H2Tp, 16384, s2p, g2, be2, cw2, cb2, a2, 1.0f / 16384.0f);
    a_kernel<<<16, 256, 0, stream>>>(H2Ti, 4096, s2i, g2, be2, cw1, cb1, a1, 1.0f / 4096.0f);

    // final gather
    out_kernel<<<64, 256, 0, stream>>>(candV, candI, a1, a2, peers_style, out, ncand);
}

// Round 7
// 487.109 us; speedup vs baseline: 2.4566x; 1.1964x over previous
//
#include <hip/hip_runtime.h>
#include <math.h>

#define NROWS 4096
#define MCOLS 16384
#define CDIM  256

typedef _Float16 half8 __attribute__((ext_vector_type(8)));
typedef float f32x4 __attribute__((ext_vector_type(4)));

static __device__ __forceinline__ float softplusf(float x) {
    return fmaxf(x, 0.0f) + log1pf(expf(-fabsf(x)));
}

// Untied-output MFMA: forces A/B/C into VGPRs (no AGPR staging copies).
static __device__ __forceinline__ f32x4 mfma16(half8 a, half8 b, f32x4 c) {
    f32x4 d;
    asm("v_mfma_f32_16x16x32_f16 %0, %1, %2, %3"
        : "=&v"(d) : "v"(a), "v"(b), "v"(c));
    return d;
}

#define TOPK_UPDATE(BV, BI, WORST, WP, V, IDX)                                 \
    if ((V) < (WORST)) {                                                       \
        BV[WP] = (V); BI[WP] = (IDX);                                          \
        WORST = BV[0]; WP = 0;                                                 \
        _Pragma("unroll")                                                      \
        for (int _q = 1; _q < 8; ++_q)                                         \
            if (BV[_q] > WORST) { WORST = BV[_q]; WP = _q; }                   \
    }

// ---------------------------------------------------------------------------
// Passthrough copy
// ---------------------------------------------------------------------------
__global__ __launch_bounds__(256)
void copy_kernel(const float4* __restrict__ src, float4* __restrict__ dst, int n4) {
    int i = blockIdx.x * blockDim.x + threadIdx.x;
    if (i < n4) dst[i] = src[i];
}

// ---------------------------------------------------------------------------
// Column norms from ORIGINAL fp32 data (fp64 accumulate).
// ---------------------------------------------------------------------------
__global__ __launch_bounds__(256)
void norms_kernel(const float* __restrict__ xiT, const float* __restrict__ xpT,
                  float* __restrict__ normI, float* __restrict__ normP) {
    int i = blockIdx.x * blockDim.x + threadIdx.x;
    if (i >= MCOLS + NROWS) return;
    const float* p;
    int base;
    if (i < MCOLS) { p = xpT; base = (i >> 12) * (CDIM * 4096) + (i & 4095); }
    else           { p = xiT; base = i - MCOLS; }
    double s = 0.0;
    for (int c = 0; c < CDIM; ++c) {
        float v = p[base + c * 4096];
        s = fma((double)v, (double)v, s);
    }
    if (i < MCOLS) normP[i] = (float)s;
    else           normI[i - MCOLS] = (float)s;
}

// ---------------------------------------------------------------------------
// fp32 [K=256][cols] -> fragment-ready fp16 hi/lo.
// chunk (ct*8 + kt)*64 + lane holds 8 halves:
//   element = x[col = ct*16 + (lane&15)][k = kt*32 + (lane>>4)*8 + j]
// ---------------------------------------------------------------------------
__global__ __launch_bounds__(256)
void convert_kernel(const float* __restrict__ src, uint4* __restrict__ dhi,
                    uint4* __restrict__ dlo, int ncols) {
    __shared__ float S[64][65];
    const int t = threadIdx.x;
    const int tilesPerRow = ncols >> 6;
    const int colbase = (blockIdx.x % tilesPerRow) << 6;
    const int ktbase  = (blockIdx.x / tilesPerRow) << 6;
    const int b = colbase >> 12;
    const int pixbase = colbase & 4095;
    const float* sp = src + (size_t)b * (CDIM * 4096) + (size_t)ktbase * 4096 + pixbase;

    for (int i = t; i < 4096; i += 256) {
        int kk = i >> 6, cc = i & 63;
        S[kk][cc] = sp[kk * 4096 + cc];
    }
    __syncthreads();

    const int l = t & 63;
#pragma unroll
    for (int s = 0; s < 2; ++s) {
        const int pid  = (t >> 6) + 4 * s;
        const int ct_l = pid & 3;
        const int kt_l = pid >> 2;
        const int c_l  = ct_l * 16 + (l & 15);
        const int k_l  = kt_l * 32 + ((l >> 4) << 3);
        half8 h, lo;
#pragma unroll
        for (int j = 0; j < 8; ++j) {
            float v = S[k_l + j][c_l];
            _Float16 hv = (_Float16)v;
            h[j]  = hv;
            lo[j] = (_Float16)(v - (float)hv);
        }
        const int ct_g = (colbase >> 4) + ct_l;
        const int kt_g = (ktbase >> 5) + kt_l;
        const size_t off = (size_t)(ct_g * 8 + kt_g) * 64 + l;
        dhi[off] = *reinterpret_cast<uint4*>(&h);
        dlo[off] = *reinterpret_cast<uint4*>(&lo);
    }
}

// ---------------------------------------------------------------------------
// MFMA distance + per-row top-8.
// Grid: 64 rowtiles (64 rows) * nsplit colsplits; 128 threads = 2 waves.
// ---------------------------------------------------------------------------
__global__ __launch_bounds__(128, 2)
void dist_topk_mfma(const uint4* __restrict__ xpBhi, const uint4* __restrict__ xpBlo,
                    const uint4* __restrict__ xiBhi, const uint4* __restrict__ xiBlo,
                    const float* __restrict__ normI, const float* __restrict__ normP,
                    float* __restrict__ candV, int* __restrict__ candI,
                    int nsplit) {
    __shared__ __align__(16) char Abuf[2][16384];   // [buf][part*8192 + kt*1024 + lane*16]
    __shared__ __align__(16) float nPl[2048];

    const int t = threadIdx.x;
    const int w = t >> 6;
    const int l = t & 63;
    const int rt = blockIdx.x / nsplit;
    const int cs = blockIdx.x % nsplit;
    const int niter = (MCOLS / 16) / nsplit;
    const int span  = MCOLS / nsplit;
    const int colbase = cs * span;
    const int ncand = nsplit * 8;

    for (int i = t; i < span; i += 128) nPl[i] = normP[colbase + i];

    // xi fragments: rowgroups rgA = w, rgB = w+2
    uint4 bhA[8], blA[8], bhB[8], blB[8];
    const int ctA = rt * 4 + w;
    const int ctB = ctA + 2;
#pragma unroll
    for (int kt = 0; kt < 8; ++kt) {
        bhA[kt] = xiBhi[(size_t)(ctA * 8 + kt) * 64 + l];
        blA[kt] = xiBlo[(size_t)(ctA * 8 + kt) * 64 + l];
        bhB[kt] = xiBhi[(size_t)(ctB * 8 + kt) * 64 + l];
        blB[kt] = xiBlo[(size_t)(ctB * 8 + kt) * 64 + l];
    }

    const float nIA = normI[rt * 64 + w * 16 + (l & 15)];
    const float nIB = normI[rt * 64 + (w + 2) * 16 + (l & 15)];

    float bvA[8], bvB[8]; int biA[8], biB[8];
#pragma unroll
    for (int j = 0; j < 8; ++j) { bvA[j] = 3.4e38f; bvB[j] = 3.4e38f; biA[j] = -1; biB[j] = -1; }
    float worstA = 3.4e38f, worstB = 3.4e38f;
    int wpA = 0, wpB = 0;

    const char* gb = (w & 1) ? (const char*)xpBlo : (const char*)xpBhi;
    auto stage = [&](int it, int buf) {
        const char* src = gb + (size_t)(cs * niter + it) * 8192 + l * 16;
        char* db = &Abuf[buf][w * 8192];
#pragma unroll
        for (int kt = 0; kt < 8; ++kt)
            __builtin_amdgcn_global_load_lds(
                (const __attribute__((address_space(1))) void*)(src + kt * 1024),
                (__attribute__((address_space(3))) void*)(db + kt * 1024),
                16, 0, 0);
    };

    stage(0, 0);
    asm volatile("s_waitcnt vmcnt(0)" ::: "memory");
    __syncthreads();

    for (int it = 0; it < niter; ++it) {
        if (it < niter - 1) stage(it + 1, (it + 1) & 1);

        const char* Ab = Abuf[it & 1];
        const int lo4 = (l >> 4) << 2;
        const float4 np4 = *reinterpret_cast<const float4*>(&nPl[it * 16 + lo4]);
        const int cb = colbase + it * 16 + lo4;

        f32x4 hhA = {0.f,0.f,0.f,0.f}, hlA = {0.f,0.f,0.f,0.f}, lhA = {0.f,0.f,0.f,0.f};
        f32x4 hhB = {0.f,0.f,0.f,0.f}, hlB = {0.f,0.f,0.f,0.f}, lhB = {0.f,0.f,0.f,0.f};
        __builtin_amdgcn_s_setprio(1);
#pragma unroll
        for (int kt = 0; kt < 8; ++kt) {
            const half8 ah = *reinterpret_cast<const half8*>(Ab + kt * 1024 + l * 16);
            const half8 al = *reinterpret_cast<const half8*>(Ab + 8192 + kt * 1024 + l * 16);
            const half8 vhA = *reinterpret_cast<const half8*>(&bhA[kt]);
            const half8 vlA = *reinterpret_cast<const half8*>(&blA[kt]);
            const half8 vhB = *reinterpret_cast<const half8*>(&bhB[kt]);
            const half8 vlB = *reinterpret_cast<const half8*>(&blB[kt]);
            hhA = mfma16(ah, vhA, hhA);
            hlA = mfma16(ah, vlA, hlA);
            lhA = mfma16(al, vhA, lhA);
            hhB = mfma16(ah, vhB, hhB);
            hlB = mfma16(ah, vlB, hlB);
            lhB = mfma16(al, vhB, lhB);
        }
        __builtin_amdgcn_s_setprio(0);

        const float npv[4] = {np4.x, np4.y, np4.z, np4.w};
#pragma unroll
        for (int j = 0; j < 4; ++j) {
            const float sA = hhA[j] + hlA[j] + lhA[j];
            const float dA = fmaxf(nIA + npv[j] - 2.0f * sA, 0.0f);
            TOPK_UPDATE(bvA, biA, worstA, wpA, dA, cb + j);
            const float sB = hhB[j] + hlB[j] + lhB[j];
            const float dB = fmaxf(nIB + npv[j] - 2.0f * sB, 0.0f);
            TOPK_UPDATE(bvB, biB, worstB, wpB, dB, cb + j);
        }

        asm volatile("s_waitcnt vmcnt(0)" ::: "memory");
        __builtin_amdgcn_s_barrier();
    }

    // merge scratch aliased onto Abuf (staging dead now)
    float* mVal = (float*)&Abuf[0][0];
    int*   mIdx = (int*)&Abuf[0][8192];

#define DUMP_AND_MERGE(BV, BI, ROWOFF)                                          \
    {                                                                           \
        __syncthreads();                                                        \
        _Pragma("unroll")                                                       \
        for (int j = 0; j < 8; ++j) { mVal[t * 8 + j] = BV[j]; mIdx[t * 8 + j] = BI[j]; } \
        __syncthreads();                                                        \
        if (t < 32) {                                                           \
            float sv[8]; int si[8];                                             \
            _Pragma("unroll")                                                   \
            for (int j = 0; j < 8; ++j) { sv[j] = 3.4e38f; si[j] = -1; }        \
            float wv = 3.4e38f; int wp = 0;                                     \
            for (int g = 0; g < 4; ++g) {                                       \
                const int fl = ((t >> 4) << 6) + (t & 15) + 16 * g;             \
                _Pragma("unroll")                                               \
                for (int j = 0; j < 8; ++j) {                                   \
                    const float v = mVal[fl * 8 + j];                           \
                    TOPK_UPDATE(sv, si, wv, wp, v, mIdx[fl * 8 + j]);           \
                }                                                               \
            }                                                                   \
            for (int a = 1; a < 8; ++a) {                                       \
                float v = sv[a]; int ii = si[a]; int b2 = a - 1;                \
                while (b2 >= 0 && sv[b2] > v) { sv[b2+1] = sv[b2]; si[b2+1] = si[b2]; --b2; } \
                sv[b2+1] = v; si[b2+1] = ii;                                    \
            }                                                                   \
            const int row = rt * 64 + (ROWOFF) + t;                             \
            _Pragma("unroll")                                                   \
            for (int j = 0; j < 8; ++j) {                                       \
                candV[row * ncand + cs * 8 + j] = sv[j];                        \
                candI[row * ncand + cs * 8 + j] = si[j];                        \
            }                                                                   \
        }                                                                       \
    }

    DUMP_AND_MERGE(bvA, biA, 0)
    DUMP_AND_MERGE(bvB, biB, 32)
#undef DUMP_AND_MERGE
}

// ---------------------------------------------------------------------------
// MLP layer 1 (CIN=256 chunked 2x128, COUT=128, pixel-layout input, no BN).
// Grid 160: blocks 0..127 peers, 128..159 input.
// ---------------------------------------------------------------------------
__global__ __launch_bounds__(256)
void gemm1_kernel(const float* __restrict__ Xp, const float* __restrict__ Xi,
                  const float* __restrict__ W, const float* __restrict__ bias,
                  float* __restrict__ outP, float* __restrict__ outI) {
    __shared__ __align__(16) float Wl[128][132];
    const int t = threadIdx.x;
    const bool isP = blockIdx.x < 128;
    const float* X = isP ? Xp : Xi;
    const int rows = isP ? 16384 : 4096;
    const int blk  = isP ? blockIdx.x : blockIdx.x - 128;
    float* outT = isP ? outP : outI;

    const int r   = blk * 128 + (t & 63);
    const int r2  = r + 64;
    const int chb = (t >> 6) * 32;

    float acc0[32], acc1[32];
#pragma unroll
    for (int q = 0; q < 32; ++q) { acc0[q] = 0.0f; acc1[q] = 0.0f; }

    for (int half = 0; half < 2; ++half) {
        __syncthreads();
        for (int i = t; i < 128 * 128; i += 256) {
            int k = i >> 7, c = i & 127;
            Wl[c][k] = W[k * 256 + half * 128 + c];
        }
        __syncthreads();
#pragma unroll 2
        for (int c = 0; c < 128; ++c) {
            const int cg = half * 128 + c;
            const float x0 = X[(r  >> 12) * (CDIM * 4096) + cg * 4096 + (r  & 4095)];
            const float x1 = X[(r2 >> 12) * (CDIM * 4096) + cg * 4096 + (r2 & 4095)];
#pragma unroll
            for (int q = 0; q < 8; ++q) {
                const float4 wv = *reinterpret_cast<const float4*>(&Wl[c][chb + 4 * q]);
                acc0[4 * q + 0] = fmaf(x0, wv.x, acc0[4 * q + 0]);
                acc0[4 * q + 1] = fmaf(x0, wv.y, acc0[4 * q + 1]);
                acc0[4 * q + 2] = fmaf(x0, wv.z, acc0[4 * q + 2]);
                acc0[4 * q + 3] = fmaf(x0, wv.w, acc0[4 * q + 3]);
                acc1[4 * q + 0] = fmaf(x1, wv.x, acc1[4 * q + 0]);
                acc1[4 * q + 1] = fmaf(x1, wv.y, acc1[4 * q + 1]);
                acc1[4 * q + 2] = fmaf(x1, wv.z, acc1[4 * q + 2]);
                acc1[4 * q + 3] = fmaf(x1, wv.w, acc1[4 * q + 3]);
            }
        }
    }
#pragma unroll
    for (int q = 0; q < 32; ++q) {
        const int k = chb + q;
        const float b = bias[k];
        outT[k * rows + r]  = acc0[q] + b;
        outT[k * rows + r2] = acc1[q] + b;
    }
}

// ---------------------------------------------------------------------------
// MLP layer 2 (CIN=128, COUT=64, [C][rows] input, BN+ReLU on input).
// Grid 160: blocks 0..127 peers, 128..159 input.
// ---------------------------------------------------------------------------
__global__ __launch_bounds__(256)
void gemm2_kernel(const float* __restrict__ Hp, const float* __restrict__ Hi,
                  const float* __restrict__ W, const float* __restrict__ bias,
                  const float* __restrict__ statsP, const float* __restrict__ statsI,
                  const float* __restrict__ g, const float* __restrict__ be,
                  float* __restrict__ outP, float* __restrict__ outI) {
    __shared__ __align__(16) float Wl[128][68];
    __shared__ float scL[128], shL[128];
    const int t = threadIdx.x;
    const bool isP = blockIdx.x < 128;
    const float* X = isP ? Hp : Hi;
    const float* stats = isP ? statsP : statsI;
    const float invDenom = isP ? (1.0f / 16384.0f) : (1.0f / 4096.0f);
    const int rows = isP ? 16384 : 4096;
    const int blk  = isP ? blockIdx.x : blockIdx.x - 128;
    float* outT = isP ? outP : outI;

    for (int i = t; i < 128 * 64; i += 256) {
        int k = i >> 7, c = i & 127;
        Wl[c][k] = W[k * 128 + c];
    }
    if (t < 128) {
        float mean = stats[t] * invDenom;
        float var  = stats[128 + t] * invDenom - mean * mean;
        float sc   = rsqrtf(var + 1e-5f) * g[t];
        scL[t] = sc;
        shL[t] = be[t] - mean * sc;
    }
    __syncthreads();

    const int r   = blk * 128 + (t & 63);
    const int r2  = r + 64;
    const int chb = (t >> 6) * 16;

    float acc0[16], acc1[16];
#pragma unroll
    for (int q = 0; q < 16; ++q) { acc0[q] = 0.0f; acc1[q] = 0.0f; }

#pragma unroll 2
    for (int c = 0; c < 128; ++c) {
        float x0 = X[c * rows + r];
        float x1 = X[c * rows + r2];
        x0 = fmaxf(fmaf(x0, scL[c], shL[c]), 0.0f);
        x1 = fmaxf(fmaf(x1, scL[c], shL[c]), 0.0f);
#pragma unroll
        for (int q = 0; q < 4; ++q) {
            const float4 wv = *reinterpret_cast<const float4*>(&Wl[c][chb + 4 * q]);
            acc0[4 * q + 0] = fmaf(x0, wv.x, acc0[4 * q + 0]);
            acc0[4 * q + 1] = fmaf(x0, wv.y, acc0[4 * q + 1]);
            acc0[4 * q + 2] = fmaf(x0, wv.z, acc0[4 * q + 2]);
            acc0[4 * q + 3] = fmaf(x0, wv.w, acc0[4 * q + 3]);
            acc1[4 * q + 0] = fmaf(x1, wv.x, acc1[4 * q + 0]);
            acc1[4 * q + 1] = fmaf(x1, wv.y, acc1[4 * q + 1]);
            acc1[4 * q + 2] = fmaf(x1, wv.z, acc1[4 * q + 2]);
            acc1[4 * q + 3] = fmaf(x1, wv.w, acc1[4 * q + 3]);
        }
    }
#pragma unroll
    for (int q = 0; q < 16; ++q) {
        const int k = chb + q;
        const float b = bias[k];
        outT[k * rows + r]  = acc0[q] + b;
        outT[k * rows + r2] = acc1[q] + b;
    }
}

// ---------------------------------------------------------------------------
// Column stats for peers+input in one launch. Grid = 2*C.
// ---------------------------------------------------------------------------
__global__ __launch_bounds__(256)
void colstats2x_kernel(const float* __restrict__ Hp, const float* __restrict__ Hi,
                       int C, float* __restrict__ statsP, float* __restrict__ statsI) {
    __shared__ float rs[256], rq[256];
    const bool isP = blockIdx.x < (unsigned)C;
    const int c = isP ? blockIdx.x : blockIdx.x - C;
    const float* H = isP ? Hp : Hi;
    const int rows = isP ? 16384 : 4096;
    float* stats = isP ? statsP : statsI;
    const int t = threadIdx.x;
    float s = 0.0f, q = 0.0f;
    for (int r = t; r < rows; r += 256) {
        float v = H[c * rows + r];
        s += v;
        q = fmaf(v, v, q);
    }
    rs[t] = s; rq[t] = q;
    __syncthreads();
    for (int st = 128; st > 0; st >>= 1) {
        if (t < st) { rs[t] += rs[t + st]; rq[t] += rq[t + st]; }
        __syncthreads();
    }
    if (t == 0) { stats[c] = rs[0]; stats[C + c] = rq[0]; }
}

// ---------------------------------------------------------------------------
// a-scores for peers+input in one launch. Grid = 80 (64 peers + 16 input).
// ---------------------------------------------------------------------------
__global__ __launch_bounds__(256)
void a2x_kernel(const float* __restrict__ Hp, const float* __restrict__ Hi,
                const float* __restrict__ statsP, const float* __restrict__ statsI,
                const float* __restrict__ g, const float* __restrict__ be,
                const float* __restrict__ cwP, const float* __restrict__ cbP,
                const float* __restrict__ cwI, const float* __restrict__ cbI,
                float* __restrict__ aP, float* __restrict__ aI) {
    __shared__ float scL[64], shL[64], cwL[64];
    const bool isP = blockIdx.x < 64;
    const float* H = isP ? Hp : Hi;
    const float* stats = isP ? statsP : statsI;
    const float* cw = isP ? cwP : cwI;
    const float* cb = isP ? cbP : cbI;
    float* aout = isP ? aP : aI;
    const int rows = isP ? 16384 : 4096;
    const float invDenom = isP ? (1.0f / 16384.0f) : (1.0f / 4096.0f);
    const int blk = isP ? blockIdx.x : blockIdx.x - 64;
    const int t = threadIdx.x;
    if (t < 64) {
        float mean = stats[t] * invDenom;
        float var  = stats[64 + t] * invDenom - mean * mean;
        float sc   = rsqrtf(var + 1e-5f) * g[t];
        scL[t] = sc;
        shL[t] = be[t] - mean * sc;
        cwL[t] = cw[t];
    }
    __syncthreads();
    const int row = blk * 256 + t;
    if (row < rows) {
        float a = 0.0f;
        for (int c = 0; c < 64; ++c) {
            float v = H[c * rows + row];
            a += fmaxf(fmaf(v, scL[c], shL[c]), 0.0f) * cwL[c];
        }
        aout[row] = a + cb[0];
    }
}

// ---------------------------------------------------------------------------
// Final: merge ncand candidates/row, softplus->softmax over kNN, gather style.
// ---------------------------------------------------------------------------
__global__ __launch_bounds__(256)
void out_kernel(const float* __restrict__ candV, const int* __restrict__ candI,
                const float* __restrict__ a1, const float* __restrict__ a2,
                const float* __restrict__ PS, float* __restrict__ dout, int ncand) {
    __shared__ float wL[64][8];
    __shared__ int   aL[64][8];
    const int t  = threadIdx.x;
    const int nb = blockIdx.x * 64;

    if (t < 64) {
        const int row = nb + t;
        float sv[8]; int si[8];
#pragma unroll
        for (int j = 0; j < 8; ++j) { sv[j] = 3.4e38f; si[j] = 0; }
        float w2 = 3.4e38f; int wp = 0;
        for (int k = 0; k < ncand; ++k) {
            const float v = candV[row * ncand + k];
            TOPK_UPDATE(sv, si, w2, wp, v, candI[row * ncand + k]);
        }
        for (int a = 1; a < 8; ++a) {
            float v = sv[a]; int ii = si[a]; int b = a - 1;
            while (b >= 0 && sv[b] > v) { sv[b + 1] = sv[b]; si[b + 1] = si[b]; --b; }
            sv[b + 1] = v; si[b + 1] = ii;
        }
        const float kth = sv[4];
        int cnt = 5;
        while (cnt < 8 && sv[cnt] <= kth) ++cnt;

        const float arow = a1[row];
        float s[8], e[8];
        float mx = -1e30f;
#pragma unroll
        for (int j = 0; j < 8; ++j) s[j] = 0.0f;
        for (int j = 0; j < cnt; ++j) {
            s[j] = softplusf(arow + a2[si[j]]);
            mx = fmaxf(mx, s[j]);
        }
        float Z = 0.0f;
        for (int j = 0; j < 8; ++j) {
            e[j] = (j < cnt) ? expf(s[j] - mx) : 0.0f;
            Z += e[j];
        }
        for (int j = 0; j < 8; ++j) {
            const int ix = (j < cnt) ? si[j] : si[0];
            wL[t][j] = e[j] / Z;
            aL[t][j] = (ix >> 12) * (CDIM * 4096) + (ix & 4095);
        }
    }
    __syncthreads();

    const int rl  = t & 63;
    const int grp = t >> 6;
    float w[8]; int ab[8];
#pragma unroll
    for (int j = 0; j < 8; ++j) { w[j] = wL[rl][j]; ab[j] = aL[rl][j]; }
    const int n = nb + rl;
    for (int c = grp * 64; c < grp * 64 + 64; ++c) {
        float acc = 0.0f;
#pragma unroll
        for (int j = 0; j < 8; ++j) acc += w[j] * PS[ab[j] + c * 4096];
        dout[(CDIM + c) * 4096 + n] = acc;
    }
}

// ---------------------------------------------------------------------------
extern "C" void kernel_launch(void* const* d_in, const int* in_sizes, int n_in,
                              void* d_out, int out_size, void* d_ws, size_t ws_size,
                              hipStream_t stream) {
    const float* inp_cont    = (const float*)d_in[0];
    const float* peers_cont  = (const float*)d_in[2];
    const float* peers_style = (const float*)d_in[3];
    const float* W1  = (const float*)d_in[4];
    const float* b1  = (const float*)d_in[5];
    const float* g1  = (const float*)d_in[6];
    const float* be1 = (const float*)d_in[7];
    const float* W2  = (const float*)d_in[8];
    const float* b2  = (const float*)d_in[9];
    const float* g2  = (const float*)d_in[10];
    const float* be2 = (const float*)d_in[11];
    const float* cw1 = (const float*)d_in[12];
    const float* cb1 = (const float*)d_in[13];
    const float* cw2 = (const float*)d_in[14];
    const float* cb2 = (const float*)d_in[15];
    float* out = (float*)d_out;
    char*  wsb = (char*)d_ws;

    int nsplit;
    if      (ws_size >= (size_t)25400000) nsplit = 16;
    else if (ws_size >= (size_t)23300000) nsplit = 8;
    else return;
    const int ncand = nsplit * 8;
    const size_t candBytes = (size_t)NROWS * ncand * 4;

    // workspace layout (bytes)
    uint4* xpBhi = (uint4*)(wsb + 0);                    //  8 MB
    uint4* xpBlo = (uint4*)(wsb + 8388608);              //  8 MB
    uint4* xiBhi = (uint4*)(wsb + 16777216);             //  2 MB
    uint4* xiBlo = (uint4*)(wsb + 18874368);             //  2 MB
    float* normP = (float*)(wsb + 20971520);             //  64 KB
    float* normI = (float*)(wsb + 21037056);             //  16 KB
    float* candV = (float*)(wsb + 21053440);             //  candBytes
    int*   candI = (int*)  (wsb + 21053440 + candBytes); //  candBytes
    char*  tail  = wsb + 21053440 + 2 * candBytes;
    float* a2    = (float*)(tail);                       //  64 KB
    float* a1    = (float*)(tail + 65536);               //  16 KB
    float* s1p   = (float*)(tail + 81920);               //  1 KB
    float* s1i   = (float*)(tail + 82944);               //  1 KB
    float* s2p   = (float*)(tail + 83968);               //  512
    float* s2i   = (float*)(tail + 84480);               //  512
    // Aliased AFTER dist kernel completes (xpB/xiB dead by then):
    float* H1Tp  = (float*)(wsb + 0);                    // 8 MB
    float* H2Tp  = (float*)(wsb + 8388608);              // 4 MB
    float* H1Ti  = (float*)(wsb + 16777216);             // 2 MB
    float* H2Ti  = (float*)(wsb + 18874368);             // 1 MB

    copy_kernel<<<1024, 256, 0, stream>>>((const float4*)inp_cont, (float4*)out, 262144);
    norms_kernel<<<80, 256, 0, stream>>>(inp_cont, peers_cont, normI, normP);
    convert_kernel<<<256, 256, 0, stream>>>(inp_cont, xiBhi, xiBlo, 4096);
    convert_kernel<<<1024, 256, 0, stream>>>(peers_cont, xpBhi, xpBlo, 16384);

    dist_topk_mfma<<<64 * nsplit, 128, 0, stream>>>(xpBhi, xpBlo, xiBhi, xiBlo,
                                                    normI, normP, candV, candI, nsplit);

    gemm1_kernel<<<160, 256, 0, stream>>>(peers_cont, inp_cont, W1, b1, H1Tp, H1Ti);
    colstats2x_kernel<<<256, 256, 0, stream>>>(H1Tp, H1Ti, 128, s1p, s1i);
    gemm2_kernel<<<160, 256, 0, stream>>>(H1Tp, H1Ti, W2, b2, s1p, s1i, g1, be1, H2Tp, H2Ti);
    colstats2x_kernel<<<128, 256, 0, stream>>>(H2Tp, H2Ti, 64, s2p, s2i);
    a2x_kernel<<<80, 256, 0, stream>>>(H2Tp, H2Ti, s2p, s2i, g2, be2,
                                       cw2, cb2, cw1, cb1, a2, a1);

    out_kernel<<<64, 256, 0, stream>>>(candV, candI, a1, a2, peers_style, out, ncand);
}

// Round 9
// 480.466 us; speedup vs baseline: 2.4906x; 1.0138x over previous
//
#include <hip/hip_runtime.h>
#include <math.h>

#define NROWS 4096
#define MCOLS 16384
#define CDIM  256

typedef _Float16 half8 __attribute__((ext_vector_type(8)));
typedef float f32x4 __attribute__((ext_vector_type(4)));

static __device__ __forceinline__ float softplusf(float x) {
    return fmaxf(x, 0.0f) + log1pf(expf(-fabsf(x)));
}

#define TOPK_UPDATE(BV, BI, WORST, WP, V, IDX)                                 \
    if ((V) < (WORST)) {                                                       \
        BV[WP] = (V); BI[WP] = (IDX);                                          \
        WORST = BV[0]; WP = 0;                                                 \
        _Pragma("unroll")                                                      \
        for (int _q = 1; _q < 8; ++_q)                                         \
            if (BV[_q] > WORST) { WORST = BV[_q]; WP = _q; }                   \
    }

// ---------------------------------------------------------------------------
// Passthrough copy
// ---------------------------------------------------------------------------
__global__ __launch_bounds__(256)
void copy_kernel(const float4* __restrict__ src, float4* __restrict__ dst, int n4) {
    int i = blockIdx.x * blockDim.x + threadIdx.x;
    if (i < n4) dst[i] = src[i];
}

// ---------------------------------------------------------------------------
// Column norms from ORIGINAL fp32 data (fp64 accumulate).
// ---------------------------------------------------------------------------
__global__ __launch_bounds__(256)
void norms_kernel(const float* __restrict__ xiT, const float* __restrict__ xpT,
                  float* __restrict__ normI, float* __restrict__ normP) {
    int i = blockIdx.x * blockDim.x + threadIdx.x;
    if (i >= MCOLS + NROWS) return;
    const float* p;
    int base;
    if (i < MCOLS) { p = xpT; base = (i >> 12) * (CDIM * 4096) + (i & 4095); }
    else           { p = xiT; base = i - MCOLS; }
    double s = 0.0;
    for (int c = 0; c < CDIM; ++c) {
        float v = p[base + c * 4096];
        s = fma((double)v, (double)v, s);
    }
    if (i < MCOLS) normP[i] = (float)s;
    else           normI[i - MCOLS] = (float)s;
}

// ---------------------------------------------------------------------------
// fp32 [K=256][cols] -> fragment-ready fp16 hi/lo.
// chunk (ct*8 + kt)*64 + lane holds 8 halves:
//   element = x[col = ct*16 + (lane&15)][k = kt*32 + (lane>>4)*8 + j]
// ---------------------------------------------------------------------------
__global__ __launch_bounds__(256)
void convert_kernel(const float* __restrict__ src, uint4* __restrict__ dhi,
                    uint4* __restrict__ dlo, int ncols) {
    __shared__ float S[64][65];
    const int t = threadIdx.x;
    const int tilesPerRow = ncols >> 6;
    const int colbase = (blockIdx.x % tilesPerRow) << 6;
    const int ktbase  = (blockIdx.x / tilesPerRow) << 6;
    const int b = colbase >> 12;
    const int pixbase = colbase & 4095;
    const float* sp = src + (size_t)b * (CDIM * 4096) + (size_t)ktbase * 4096 + pixbase;

    for (int i = t; i < 4096; i += 256) {
        int kk = i >> 6, cc = i & 63;
        S[kk][cc] = sp[kk * 4096 + cc];
    }
    __syncthreads();

    const int l = t & 63;
#pragma unroll
    for (int s = 0; s < 2; ++s) {
        const int pid  = (t >> 6) + 4 * s;
        const int ct_l = pid & 3;
        const int kt_l = pid >> 2;
        const int c_l  = ct_l * 16 + (l & 15);
        const int k_l  = kt_l * 32 + ((l >> 4) << 3);
        half8 h, lo;
#pragma unroll
        for (int j = 0; j < 8; ++j) {
            float v = S[k_l + j][c_l];
            _Float16 hv = (_Float16)v;
            h[j]  = hv;
            lo[j] = (_Float16)(v - (float)hv);
        }
        const int ct_g = (colbase >> 4) + ct_l;
        const int kt_g = (ktbase >> 5) + kt_l;
        const size_t off = (size_t)(ct_g * 8 + kt_g) * 64 + l;
        dhi[off] = *reinterpret_cast<uint4*>(&h);
        dlo[off] = *reinterpret_cast<uint4*>(&lo);
    }
}

// ---------------------------------------------------------------------------
// MFMA distance + per-row top-8.
// Grid: 64 rowtiles (64 rows) * nsplit colsplits; 128 threads = 2 waves.
// Chained Markidis: acc0 = hh+lh (in-MFMA), acc1 = hl; sum at epilogue.
// Register demand kept < 256-cap so xi fragments stay in arch VGPRs.
// ---------------------------------------------------------------------------
__global__ __launch_bounds__(128, 2)
void dist_topk_mfma(const uint4* __restrict__ xpBhi, const uint4* __restrict__ xpBlo,
                    const uint4* __restrict__ xiBhi, const uint4* __restrict__ xiBlo,
                    const float* __restrict__ normI, const float* __restrict__ normP,
                    float* __restrict__ candV, int* __restrict__ candI,
                    int nsplit) {
    __shared__ __align__(16) char Abuf[2][16384];   // [buf][part*8192 + kt*1024 + lane*16]
    __shared__ __align__(16) float nPl[2048];

    const int t = threadIdx.x;
    const int w = t >> 6;
    const int l = t & 63;
    const int rt = blockIdx.x / nsplit;
    const int cs = blockIdx.x % nsplit;
    const int niter = (MCOLS / 16) / nsplit;
    const int span  = MCOLS / nsplit;
    const int colbase = cs * span;
    const int ncand = nsplit * 8;

    for (int i = t; i < span; i += 128) nPl[i] = normP[colbase + i];

    // xi fragments: rowgroups rgA = w, rgB = w+2
    uint4 bhA[8], blA[8], bhB[8], blB[8];
    const int ctA = rt * 4 + w;
    const int ctB = ctA + 2;
#pragma unroll
    for (int kt = 0; kt < 8; ++kt) {
        bhA[kt] = xiBhi[(size_t)(ctA * 8 + kt) * 64 + l];
        blA[kt] = xiBlo[(size_t)(ctA * 8 + kt) * 64 + l];
        bhB[kt] = xiBhi[(size_t)(ctB * 8 + kt) * 64 + l];
        blB[kt] = xiBlo[(size_t)(ctB * 8 + kt) * 64 + l];
    }

    const float nIA = normI[rt * 64 + w * 16 + (l & 15)];
    const float nIB = normI[rt * 64 + (w + 2) * 16 + (l & 15)];

    float bvA[8], bvB[8]; int biA[8], biB[8];
#pragma unroll
    for (int j = 0; j < 8; ++j) { bvA[j] = 3.4e38f; bvB[j] = 3.4e38f; biA[j] = -1; biB[j] = -1; }
    float worstA = 3.4e38f, worstB = 3.4e38f;
    int wpA = 0, wpB = 0;

    // staging bases hoisted out of loop
    const char* gb = (w & 1) ? (const char*)xpBlo : (const char*)xpBhi;
    const char* srcBase = gb + (size_t)(cs * niter) * 8192 + l * 16;
    char* dbBase = &Abuf[0][w * 8192];

    auto stage = [&](int it, int buf) {
        const char* src = srcBase + (size_t)it * 8192;
        char* db = dbBase + buf * 16384;
#pragma unroll
        for (int kt = 0; kt < 8; ++kt)
            __builtin_amdgcn_global_load_lds(
                (const __attribute__((address_space(1))) void*)(src + kt * 1024),
                (__attribute__((address_space(3))) void*)(db + kt * 1024),
                16, 0, 0);
    };

    stage(0, 0);
    asm volatile("s_waitcnt vmcnt(0)" ::: "memory");
    __syncthreads();

    for (int it = 0; it < niter; ++it) {
        if (it < niter - 1) stage(it + 1, (it + 1) & 1);

        const char* Ab = Abuf[it & 1];
        const int lo4 = (l >> 4) << 2;
        const float4 np4 = *reinterpret_cast<const float4*>(&nPl[it * 16 + lo4]);
        const int cb = colbase + it * 16 + lo4;

        f32x4 a0A = {0.f,0.f,0.f,0.f}, a1A = {0.f,0.f,0.f,0.f};
        f32x4 a0B = {0.f,0.f,0.f,0.f}, a1B = {0.f,0.f,0.f,0.f};
        __builtin_amdgcn_s_setprio(1);
#pragma unroll
        for (int kt = 0; kt < 8; ++kt) {
            const half8 ah = *reinterpret_cast<const half8*>(Ab + kt * 1024 + l * 16);
            const half8 al = *reinterpret_cast<const half8*>(Ab + 8192 + kt * 1024 + l * 16);
            const half8 vhA = *reinterpret_cast<const half8*>(&bhA[kt]);
            const half8 vlA = *reinterpret_cast<const half8*>(&blA[kt]);
            const half8 vhB = *reinterpret_cast<const half8*>(&bhB[kt]);
            const half8 vlB = *reinterpret_cast<const half8*>(&blB[kt]);
            a0A = __builtin_amdgcn_mfma_f32_16x16x32_f16(ah, vhA, a0A, 0, 0, 0);
            a0B = __builtin_amdgcn_mfma_f32_16x16x32_f16(ah, vhB, a0B, 0, 0, 0);
            a1A = __builtin_amdgcn_mfma_f32_16x16x32_f16(ah, vlA, a1A, 0, 0, 0);
            a1B = __builtin_amdgcn_mfma_f32_16x16x32_f16(ah, vlB, a1B, 0, 0, 0);
            a0A = __builtin_amdgcn_mfma_f32_16x16x32_f16(al, vhA, a0A, 0, 0, 0);
            a0B = __builtin_amdgcn_mfma_f32_16x16x32_f16(al, vhB, a0B, 0, 0, 0);
        }
        __builtin_amdgcn_s_setprio(0);

        const float npv[4] = {np4.x, np4.y, np4.z, np4.w};
#pragma unroll
        for (int j = 0; j < 4; ++j) {
            const float sA = a0A[j] + a1A[j];
            const float dA = fmaxf(nIA + npv[j] - 2.0f * sA, 0.0f);
            TOPK_UPDATE(bvA, biA, worstA, wpA, dA, cb + j);
            const float sB = a0B[j] + a1B[j];
            const float dB = fmaxf(nIB + npv[j] - 2.0f * sB, 0.0f);
            TOPK_UPDATE(bvB, biB, worstB, wpB, dB, cb + j);
        }

        asm volatile("s_waitcnt vmcnt(0)" ::: "memory");
        __builtin_amdgcn_s_barrier();
    }

    // merge scratch aliased onto Abuf (staging dead now)
    float* mVal = (float*)&Abuf[0][0];
    int*   mIdx = (int*)&Abuf[0][8192];

#define DUMP_AND_MERGE(BV, BI, ROWOFF)                                          \
    {                                                                           \
        __syncthreads();                                                        \
        _Pragma("unroll")                                                       \
        for (int j = 0; j < 8; ++j) { mVal[t * 8 + j] = BV[j]; mIdx[t * 8 + j] = BI[j]; } \
        __syncthreads();                                                        \
        if (t < 32) {                                                           \
            float sv[8]; int si[8];                                             \
            _Pragma("unroll")                                                   \
            for (int j = 0; j < 8; ++j) { sv[j] = 3.4e38f; si[j] = -1; }        \
            float wv = 3.4e38f; int wp = 0;                                     \
            for (int g = 0; g < 4; ++g) {                                       \
                const int fl = ((t >> 4) << 6) + (t & 15) + 16 * g;             \
                _Pragma("unroll")                                               \
                for (int j = 0; j < 8; ++j) {                                   \
                    const float v = mVal[fl * 8 + j];                           \
                    TOPK_UPDATE(sv, si, wv, wp, v, mIdx[fl * 8 + j]);           \
                }                                                               \
            }                                                                   \
            for (int a = 1; a < 8; ++a) {                                       \
                float v = sv[a]; int ii = si[a]; int b2 = a - 1;                \
                while (b2 >= 0 && sv[b2] > v) { sv[b2+1] = sv[b2]; si[b2+1] = si[b2]; --b2; } \
                sv[b2+1] = v; si[b2+1] = ii;                                    \
            }                                                                   \
            const int row = rt * 64 + (ROWOFF) + t;                             \
            _Pragma("unroll")                                                   \
            for (int j = 0; j < 8; ++j) {                                       \
                candV[row * ncand + cs * 8 + j] = sv[j];                        \
                candI[row * ncand + cs * 8 + j] = si[j];                        \
            }                                                                   \
        }                                                                       \
    }

    DUMP_AND_MERGE(bvA, biA, 0)
    DUMP_AND_MERGE(bvB, biB, 32)
#undef DUMP_AND_MERGE
}

// ---------------------------------------------------------------------------
// MLP layer 1 (CIN=256 chunked 2x128, COUT=128, pixel-layout, no BN).
// 64-row blocks: grid 320 (0..255 peers, 256..319 input), 1 row/thread.
// ---------------------------------------------------------------------------
__global__ __launch_bounds__(256)
void gemm1_kernel(const float* __restrict__ Xp, const float* __restrict__ Xi,
                  const float* __restrict__ W, const float* __restrict__ bias,
                  float* __restrict__ outP, float* __restrict__ outI) {
    __shared__ __align__(16) float Wl[128][132];
    const int t = threadIdx.x;
    const bool isP = blockIdx.x < 256;
    const float* X = isP ? Xp : Xi;
    const int rows = isP ? 16384 : 4096;
    const int blk  = isP ? blockIdx.x : blockIdx.x - 256;
    float* outT = isP ? outP : outI;

    const int r   = blk * 64 + (t & 63);
    const int chb = (t >> 6) * 32;

    float acc[32];
#pragma unroll
    for (int q = 0; q < 32; ++q) acc[q] = 0.0f;

    for (int half = 0; half < 2; ++half) {
        __syncthreads();
        for (int i = t; i < 128 * 128; i += 256) {
            int k = i >> 7, c = i & 127;
            Wl[c][k] = W[k * 256 + half * 128 + c];
        }
        __syncthreads();
#pragma unroll 2
        for (int c = 0; c < 128; ++c) {
            const int cg = half * 128 + c;
            const float x = X[(r >> 12) * (CDIM * 4096) + cg * 4096 + (r & 4095)];
#pragma unroll
            for (int q = 0; q < 8; ++q) {
                const float4 wv = *reinterpret_cast<const float4*>(&Wl[c][chb + 4 * q]);
                acc[4 * q + 0] = fmaf(x, wv.x, acc[4 * q + 0]);
                acc[4 * q + 1] = fmaf(x, wv.y, acc[4 * q + 1]);
                acc[4 * q + 2] = fmaf(x, wv.z, acc[4 * q + 2]);
                acc[4 * q + 3] = fmaf(x, wv.w, acc[4 * q + 3]);
            }
        }
    }
#pragma unroll
    for (int q = 0; q < 32; ++q) {
        const int k = chb + q;
        outT[k * rows + r] = acc[q] + bias[k];
    }
}

// ---------------------------------------------------------------------------
// MLP layer 2 (CIN=128, COUT=64, [C][rows] input, BN+ReLU on input).
// 64-row blocks: grid 320 (0..255 peers, 256..319 input), 1 row/thread.
// ---------------------------------------------------------------------------
__global__ __launch_bounds__(256)
void gemm2_kernel(const float* __restrict__ Hp, const float* __restrict__ Hi,
                  const float* __restrict__ W, const float* __restrict__ bias,
                  const float* __restrict__ statsP, const float* __restrict__ statsI,
                  const float* __restrict__ g, const float* __restrict__ be,
                  float* __restrict__ outP, float* __restrict__ outI) {
    __shared__ __align__(16) float Wl[128][68];
    __shared__ float scL[128], shL[128];
    const int t = threadIdx.x;
    const bool isP = blockIdx.x < 256;
    const float* X = isP ? Hp : Hi;
    const float* stats = isP ? statsP : statsI;
    const float invDenom = isP ? (1.0f / 16384.0f) : (1.0f / 4096.0f);
    const int rows = isP ? 16384 : 4096;
    const int blk  = isP ? blockIdx.x : blockIdx.x - 256;
    float* outT = isP ? outP : outI;

    for (int i = t; i < 128 * 64; i += 256) {
        int k = i >> 7, c = i & 127;
        Wl[c][k] = W[k * 128 + c];
    }
    if (t < 128) {
        float mean = stats[t] * invDenom;
        float var  = stats[128 + t] * invDenom - mean * mean;
        float sc   = rsqrtf(var + 1e-5f) * g[t];
        scL[t] = sc;
        shL[t] = be[t] - mean * sc;
    }
    __syncthreads();

    const int r   = blk * 64 + (t & 63);
    const int chb = (t >> 6) * 16;

    float acc[16];
#pragma unroll
    for (int q = 0; q < 16; ++q) acc[q] = 0.0f;

#pragma unroll 2
    for (int c = 0; c < 128; ++c) {
        float x = X[c * rows + r];
        x = fmaxf(fmaf(x, scL[c], shL[c]), 0.0f);
#pragma unroll
        for (int q = 0; q < 4; ++q) {
            const float4 wv = *reinterpret_cast<const float4*>(&Wl[c][chb + 4 * q]);
            acc[4 * q + 0] = fmaf(x, wv.x, acc[4 * q + 0]);
            acc[4 * q + 1] = fmaf(x, wv.y, acc[4 * q + 1]);
            acc[4 * q + 2] = fmaf(x, wv.z, acc[4 * q + 2]);
            acc[4 * q + 3] = fmaf(x, wv.w, acc[4 * q + 3]);
        }
    }
#pragma unroll
    for (int q = 0; q < 16; ++q) {
        const int k = chb + q;
        outT[k * rows + r] = acc[q] + bias[k];
    }
}

// ---------------------------------------------------------------------------
// Column stats for peers+input in one launch. Grid = 2*C.
// ---------------------------------------------------------------------------
__global__ __launch_bounds__(256)
void colstats2x_kernel(const float* __restrict__ Hp, const float* __restrict__ Hi,
                       int C, float* __restrict__ statsP, float* __restrict__ statsI) {
    __shared__ float rs[256], rq[256];
    const bool isP = blockIdx.x < (unsigned)C;
    const int c = isP ? blockIdx.x : blockIdx.x - C;
    const float* H = isP ? Hp : Hi;
    const int rows = isP ? 16384 : 4096;
    float* stats = isP ? statsP : statsI;
    const int t = threadIdx.x;
    float s = 0.0f, q = 0.0f;
    for (int r = t; r < rows; r += 256) {
        float v = H[c * rows + r];
        s += v;
        q = fmaf(v, v, q);
    }
    rs[t] = s; rq[t] = q;
    __syncthreads();
    for (int st = 128; st > 0; st >>= 1) {
        if (t < st) { rs[t] += rs[t + st]; rq[t] += rq[t + st]; }
        __syncthreads();
    }
    if (t == 0) { stats[c] = rs[0]; stats[C + c] = rq[0]; }
}

// ---------------------------------------------------------------------------
// a-scores for peers+input in one launch. Grid = 80.
// ---------------------------------------------------------------------------
__global__ __launch_bounds__(256)
void a2x_kernel(const float* __restrict__ Hp, const float* __restrict__ Hi,
                const float* __restrict__ statsP, const float* __restrict__ statsI,
                const float* __restrict__ g, const float* __restrict__ be,
                const float* __restrict__ cwP, const float* __restrict__ cbP,
                const float* __restrict__ cwI, const float* __restrict__ cbI,
                float* __restrict__ aP, float* __restrict__ aI) {
    __shared__ float scL[64], shL[64], cwL[64];
    const bool isP = blockIdx.x < 64;
    const float* H = isP ? Hp : Hi;
    const float* stats = isP ? statsP : statsI;
    const float* cw = isP ? cwP : cwI;
    const float* cb = isP ? cbP : cbI;
    float* aout = isP ? aP : aI;
    const int rows = isP ? 16384 : 4096;
    const float invDenom = isP ? (1.0f / 16384.0f) : (1.0f / 4096.0f);
    const int blk = isP ? blockIdx.x : blockIdx.x - 64;
    const int t = threadIdx.x;
    if (t < 64) {
        float mean = stats[t] * invDenom;
        float var  = stats[64 + t] * invDenom - mean * mean;
        float sc   = rsqrtf(var + 1e-5f) * g[t];
        scL[t] = sc;
        shL[t] = be[t] - mean * sc;
        cwL[t] = cw[t];
    }
    __syncthreads();
    const int row = blk * 256 + t;
    if (row < rows) {
        float a = 0.0f;
        for (int c = 0; c < 64; ++c) {
            float v = H[c * rows + row];
            a += fmaxf(fmaf(v, scL[c], shL[c]), 0.0f) * cwL[c];
        }
        aout[row] = a + cb[0];
    }
}

// ---------------------------------------------------------------------------
// Final: merge ncand candidates/row, softplus->softmax over kNN, gather style.
// ---------------------------------------------------------------------------
__global__ __launch_bounds__(256)
void out_kernel(const float* __restrict__ candV, const int* __restrict__ candI,
                const float* __restrict__ a1, const float* __restrict__ a2,
                const float* __restrict__ PS, float* __restrict__ dout, int ncand) {
    __shared__ float wL[64][8];
    __shared__ int   aL[64][8];
    const int t  = threadIdx.x;
    const int nb = blockIdx.x * 64;

    if (t < 64) {
        const int row = nb + t;
        float sv[8]; int si[8];
#pragma unroll
        for (int j = 0; j < 8; ++j) { sv[j] = 3.4e38f; si[j] = 0; }
        float w2 = 3.4e38f; int wp = 0;
        for (int k = 0; k < ncand; ++k) {
            const float v = candV[row * ncand + k];
            TOPK_UPDATE(sv, si, w2, wp, v, candI[row * ncand + k]);
        }
        for (int a = 1; a < 8; ++a) {
            float v = sv[a]; int ii = si[a]; int b = a - 1;
            while (b >= 0 && sv[b] > v) { sv[b + 1] = sv[b]; si[b + 1] = si[b]; --b; }
            sv[b + 1] = v; si[b + 1] = ii;
        }
        const float kth = sv[4];
        int cnt = 5;
        while (cnt < 8 && sv[cnt] <= kth) ++cnt;

        const float arow = a1[row];
        float s[8], e[8];
        float mx = -1e30f;
#pragma unroll
        for (int j = 0; j < 8; ++j) s[j] = 0.0f;
        for (int j = 0; j < cnt; ++j) {
            s[j] = softplusf(arow + a2[si[j]]);
            mx = fmaxf(mx, s[j]);
        }
        float Z = 0.0f;
        for (int j = 0; j < 8; ++j) {
            e[j] = (j < cnt) ? expf(s[j] - mx) : 0.0f;
            Z += e[j];
        }
        for (int j = 0; j < 8; ++j) {
            const int ix = (j < cnt) ? si[j] : si[0];
            wL[t][j] = e[j] / Z;
            aL[t][j] = (ix >> 12) * (CDIM * 4096) + (ix & 4095);
        }
    }
    __syncthreads();

    const int rl  = t & 63;
    const int grp = t >> 6;
    float w[8]; int ab[8];
#pragma unroll
    for (int j = 0; j < 8; ++j) { w[j] = wL[rl][j]; ab[j] = aL[rl][j]; }
    const int n = nb + rl;
    for (int c = grp * 64; c < grp * 64 + 64; ++c) {
        float acc = 0.0f;
#pragma unroll
        for (int j = 0; j < 8; ++j) acc += w[j] * PS[ab[j] + c * 4096];
        dout[(CDIM + c) * 4096 + n] = acc;
    }
}

// ---------------------------------------------------------------------------
extern "C" void kernel_launch(void* const* d_in, const int* in_sizes, int n_in,
                              void* d_out, int out_size, void* d_ws, size_t ws_size,
                              hipStream_t stream) {
    const float* inp_cont    = (const float*)d_in[0];
    const float* peers_cont  = (const float*)d_in[2];
    const float* peers_style = (const float*)d_in[3];
    const float* W1  = (const float*)d_in[4];
    const float* b1  = (const float*)d_in[5];
    const float* g1  = (const float*)d_in[6];
    const float* be1 = (const float*)d_in[7];
    const float* W2  = (const float*)d_in[8];
    const float* b2  = (const float*)d_in[9];
    const float* g2  = (const float*)d_in[10];
    const float* be2 = (const float*)d_in[11];
    const float* cw1 = (const float*)d_in[12];
    const float* cb1 = (const float*)d_in[13];
    const float* cw2 = (const float*)d_in[14];
    const float* cb2 = (const float*)d_in[15];
    float* out = (float*)d_out;
    char*  wsb = (char*)d_ws;

    int nsplit;
    if      (ws_size >= (size_t)25400000) nsplit = 16;
    else if (ws_size >= (size_t)23300000) nsplit = 8;
    else return;
    const int ncand = nsplit * 8;
    const size_t candBytes = (size_t)NROWS * ncand * 4;

    // workspace layout (bytes)
    uint4* xpBhi = (uint4*)(wsb + 0);                    //  8 MB
    uint4* xpBlo = (uint4*)(wsb + 8388608);              //  8 MB
    uint4* xiBhi = (uint4*)(wsb + 16777216);             //  2 MB
    uint4* xiBlo = (uint4*)(wsb + 18874368);             //  2 MB
    float* normP = (float*)(wsb + 20971520);             //  64 KB
    float* normI = (float*)(wsb + 21037056);             //  16 KB
    float* candV = (float*)(wsb + 21053440);             //  candBytes
    int*   candI = (int*)  (wsb + 21053440 + candBytes); //  candBytes
    char*  tail  = wsb + 21053440 + 2 * candBytes;
    float* a2    = (float*)(tail);                       //  64 KB
    float* a1    = (float*)(tail + 65536);               //  16 KB
    float* s1p   = (float*)(tail + 81920);               //  1 KB
    float* s1i   = (float*)(tail + 82944);               //  1 KB
    float* s2p   = (float*)(tail + 83968);               //  512
    float* s2i   = (float*)(tail + 84480);               //  512
    // Aliased AFTER dist kernel completes (xpB/xiB dead by then):
    float* H1Tp  = (float*)(wsb + 0);                    // 8 MB
    float* H2Tp  = (float*)(wsb + 8388608);              // 4 MB
    float* H1Ti  = (float*)(wsb + 16777216);             // 2 MB
    float* H2Ti  = (float*)(wsb + 18874368);             // 1 MB

    copy_kernel<<<1024, 256, 0, stream>>>((const float4*)inp_cont, (float4*)out, 262144);
    norms_kernel<<<80, 256, 0, stream>>>(inp_cont, peers_cont, normI, normP);
    convert_kernel<<<256, 256, 0, stream>>>(inp_cont, xiBhi, xiBlo, 4096);
    convert_kernel<<<1024, 256, 0, stream>>>(peers_cont, xpBhi, xpBlo, 16384);

    dist_topk_mfma<<<64 * nsplit, 128, 0, stream>>>(xpBhi, xpBlo, xiBhi, xiBlo,
                                                    normI, normP, candV, candI, nsplit);

    gemm1_kernel<<<320, 256, 0, stream>>>(peers_cont, inp_cont, W1, b1, H1Tp, H1Ti);
    colstats2x_kernel<<<256, 256, 0, stream>>>(H1Tp, H1Ti, 128, s1p, s1i);
    gemm2_kernel<<<320, 256, 0, stream>>>(H1Tp, H1Ti, W2, b2, s1p, s1i, g1, be1, H2Tp, H2Ti);
    colstats2x_kernel<<<128, 256, 0, stream>>>(H2Tp, H2Ti, 64, s2p, s2i);
    a2x_kernel<<<80, 256, 0, stream>>>(H2Tp, H2Ti, s2p, s2i, g2, be2,
                                       cw2, cb2, cw1, cb1, a2, a1);

    out_kernel<<<64, 256, 0, stream>>>(candV, candI, a1, a2, peers_style, out, ncand);
}

// Round 10
// 471.040 us; speedup vs baseline: 2.5404x; 1.0200x over previous
//
#include <hip/hip_runtime.h>
#include <math.h>

#define NROWS 4096
#define MCOLS 16384
#define CDIM  256

typedef _Float16 half8 __attribute__((ext_vector_type(8)));
typedef float f32x4 __attribute__((ext_vector_type(4)));

static __device__ __forceinline__ float softplusf(float x) {
    return fmaxf(x, 0.0f) + log1pf(expf(-fabsf(x)));
}

#define TOPK_UPDATE(BV, BI, WORST, WP, V, IDX)                                 \
    if ((V) < (WORST)) {                                                       \
        BV[WP] = (V); BI[WP] = (IDX);                                          \
        WORST = BV[0]; WP = 0;                                                 \
        _Pragma("unroll")                                                      \
        for (int _q = 1; _q < 8; ++_q)                                         \
            if (BV[_q] > WORST) { WORST = BV[_q]; WP = _q; }                   \
    }

// ---------------------------------------------------------------------------
// Passthrough copy
// ---------------------------------------------------------------------------
__global__ __launch_bounds__(256)
void copy_kernel(const float4* __restrict__ src, float4* __restrict__ dst, int n4) {
    int i = blockIdx.x * blockDim.x + threadIdx.x;
    if (i < n4) dst[i] = src[i];
}

// ---------------------------------------------------------------------------
// Column norms from ORIGINAL fp32 data (fp64 accumulate).
// ---------------------------------------------------------------------------
__global__ __launch_bounds__(256)
void norms_kernel(const float* __restrict__ xiT, const float* __restrict__ xpT,
                  float* __restrict__ normI, float* __restrict__ normP) {
    int i = blockIdx.x * blockDim.x + threadIdx.x;
    if (i >= MCOLS + NROWS) return;
    const float* p;
    int base;
    if (i < MCOLS) { p = xpT; base = (i >> 12) * (CDIM * 4096) + (i & 4095); }
    else           { p = xiT; base = i - MCOLS; }
    double s = 0.0;
    for (int c = 0; c < CDIM; ++c) {
        float v = p[base + c * 4096];
        s = fma((double)v, (double)v, s);
    }
    if (i < MCOLS) normP[i] = (float)s;
    else           normI[i - MCOLS] = (float)s;
}

// ---------------------------------------------------------------------------
// fp32 [K=256][cols] -> fragment-ready fp16 hi/lo.
// chunk (ct*8 + kt)*64 + lane holds 8 halves:
//   element = x[col = ct*16 + (lane&15)][k = kt*32 + (lane>>4)*8 + j]
// ---------------------------------------------------------------------------
__global__ __launch_bounds__(256)
void convert_kernel(const float* __restrict__ src, uint4* __restrict__ dhi,
                    uint4* __restrict__ dlo, int ncols) {
    __shared__ float S[64][65];
    const int t = threadIdx.x;
    const int tilesPerRow = ncols >> 6;
    const int colbase = (blockIdx.x % tilesPerRow) << 6;
    const int ktbase  = (blockIdx.x / tilesPerRow) << 6;
    const int b = colbase >> 12;
    const int pixbase = colbase & 4095;
    const float* sp = src + (size_t)b * (CDIM * 4096) + (size_t)ktbase * 4096 + pixbase;

    for (int i = t; i < 4096; i += 256) {
        int kk = i >> 6, cc = i & 63;
        S[kk][cc] = sp[kk * 4096 + cc];
    }
    __syncthreads();

    const int l = t & 63;
#pragma unroll
    for (int s = 0; s < 2; ++s) {
        const int pid  = (t >> 6) + 4 * s;
        const int ct_l = pid & 3;
        const int kt_l = pid >> 2;
        const int c_l  = ct_l * 16 + (l & 15);
        const int k_l  = kt_l * 32 + ((l >> 4) << 3);
        half8 h, lo;
#pragma unroll
        for (int j = 0; j < 8; ++j) {
            float v = S[k_l + j][c_l];
            _Float16 hv = (_Float16)v;
            h[j]  = hv;
            lo[j] = (_Float16)(v - (float)hv);
        }
        const int ct_g = (colbase >> 4) + ct_l;
        const int kt_g = (ktbase >> 5) + kt_l;
        const size_t off = (size_t)(ct_g * 8 + kt_g) * 64 + l;
        dhi[off] = *reinterpret_cast<uint4*>(&h);
        dlo[off] = *reinterpret_cast<uint4*>(&lo);
    }
}

// ---------------------------------------------------------------------------
// MFMA distance + per-row top-8.
// Grid: 32 rowtiles (128 rows) * nsplit colsplits; 256 threads = 4 waves.
// Per iter: 32 cols. Wave w: rowgroups w and w+4 (16 rows each).
// LDS: 2 x 32KB staging (hi 16KB + lo 16KB, 2 col-chunks each) + 8KB norms.
// Swapped operands: lane holds ONE xi row (lane&15), 4 xp cols per colfrag.
// ---------------------------------------------------------------------------
__global__ __launch_bounds__(256, 2)
void dist_topk_mfma(const uint4* __restrict__ xpBhi, const uint4* __restrict__ xpBlo,
                    const uint4* __restrict__ xiBhi, const uint4* __restrict__ xiBlo,
                    const float* __restrict__ normI, const float* __restrict__ normP,
                    float* __restrict__ candV, int* __restrict__ candI,
                    int nsplit) {
    __shared__ __align__(16) char Abuf[2][32768];  // [buf][part 16KB][ct 8KB][kt 1KB][lane 16B]
    __shared__ __align__(16) float nPl[2048];

    const int t = threadIdx.x;
    const int w = t >> 6;        // wave 0..3
    const int l = t & 63;
    const int rt = blockIdx.x / nsplit;     // 0..31
    const int cs = blockIdx.x % nsplit;
    const int niter = (MCOLS / 32) / nsplit;    // 32 (ns=16) or 64 (ns=8)
    const int span  = MCOLS / nsplit;
    const int colbase = cs * span;
    const int ncand = nsplit * 8;

    for (int i = t; i < span; i += 256) nPl[i] = normP[colbase + i];

    // xi fragments: rowgroups rgA = w, rgB = w+4 (8 rowgroups per 128-row tile)
    uint4 bhA[8], blA[8], bhB[8], blB[8];
    const int ctA = rt * 8 + w;
    const int ctB = ctA + 4;
#pragma unroll
    for (int kt = 0; kt < 8; ++kt) {
        bhA[kt] = xiBhi[(size_t)(ctA * 8 + kt) * 64 + l];
        blA[kt] = xiBlo[(size_t)(ctA * 8 + kt) * 64 + l];
        bhB[kt] = xiBhi[(size_t)(ctB * 8 + kt) * 64 + l];
        blB[kt] = xiBlo[(size_t)(ctB * 8 + kt) * 64 + l];
    }

    const float nIA = normI[rt * 128 + w * 16 + (l & 15)];
    const float nIB = normI[rt * 128 + (w + 4) * 16 + (l & 15)];

    float bvA[8], bvB[8]; int biA[8], biB[8];
#pragma unroll
    for (int j = 0; j < 8; ++j) { bvA[j] = 3.4e38f; bvB[j] = 3.4e38f; biA[j] = -1; biB[j] = -1; }
    float worstA = 3.4e38f, worstB = 3.4e38f;
    int wpA = 0, wpB = 0;

    // wave 0: hi-ct0, wave 1: hi-ct1, wave 2: lo-ct0, wave 3: lo-ct1
    const char* gb = (w >= 2) ? (const char*)xpBlo : (const char*)xpBhi;
    const char* srcBase = gb + (size_t)(cs * niter * 2 + (w & 1)) * 8192 + l * 16;
    char* dbBase = &Abuf[0][(w >> 1) * 16384 + (w & 1) * 8192];

    auto stage = [&](int it, int buf) {
        const char* src = srcBase + (size_t)it * 16384;
        char* db = dbBase + buf * 32768;
#pragma unroll
        for (int kt = 0; kt < 8; ++kt)
            __builtin_amdgcn_global_load_lds(
                (const __attribute__((address_space(1))) void*)(src + kt * 1024),
                (__attribute__((address_space(3))) void*)(db + kt * 1024),
                16, 0, 0);
    };

    stage(0, 0);
    asm volatile("s_waitcnt vmcnt(0)" ::: "memory");
    __syncthreads();

    for (int it = 0; it < niter; ++it) {
        if (it < niter - 1) stage(it + 1, (it + 1) & 1);

        const char* Ab = Abuf[it & 1];
        const int lo4 = (l >> 4) << 2;

        f32x4 a0A[2], a1A[2], a0B[2], a1B[2];
#pragma unroll
        for (int c = 0; c < 2; ++c) {
            a0A[c] = f32x4{0.f,0.f,0.f,0.f}; a1A[c] = f32x4{0.f,0.f,0.f,0.f};
            a0B[c] = f32x4{0.f,0.f,0.f,0.f}; a1B[c] = f32x4{0.f,0.f,0.f,0.f};
        }
        __builtin_amdgcn_s_setprio(1);
#pragma unroll
        for (int kt = 0; kt < 8; ++kt) {
            const half8 vhA = *reinterpret_cast<const half8*>(&bhA[kt]);
            const half8 vlA = *reinterpret_cast<const half8*>(&blA[kt]);
            const half8 vhB = *reinterpret_cast<const half8*>(&bhB[kt]);
            const half8 vlB = *reinterpret_cast<const half8*>(&blB[kt]);
#pragma unroll
            for (int c = 0; c < 2; ++c) {
                const half8 ah = *reinterpret_cast<const half8*>(Ab + c * 8192 + kt * 1024 + l * 16);
                const half8 al = *reinterpret_cast<const half8*>(Ab + 16384 + c * 8192 + kt * 1024 + l * 16);
                a0A[c] = __builtin_amdgcn_mfma_f32_16x16x32_f16(ah, vhA, a0A[c], 0, 0, 0);
                a0B[c] = __builtin_amdgcn_mfma_f32_16x16x32_f16(ah, vhB, a0B[c], 0, 0, 0);
                a1A[c] = __builtin_amdgcn_mfma_f32_16x16x32_f16(ah, vlA, a1A[c], 0, 0, 0);
                a1B[c] = __builtin_amdgcn_mfma_f32_16x16x32_f16(ah, vlB, a1B[c], 0, 0, 0);
                a0A[c] = __builtin_amdgcn_mfma_f32_16x16x32_f16(al, vhA, a0A[c], 0, 0, 0);
                a0B[c] = __builtin_amdgcn_mfma_f32_16x16x32_f16(al, vhB, a0B[c], 0, 0, 0);
            }
        }
        __builtin_amdgcn_s_setprio(0);

#pragma unroll
        for (int c = 0; c < 2; ++c) {
            const float4 np4 = *reinterpret_cast<const float4*>(&nPl[it * 32 + c * 16 + lo4]);
            const int cb = colbase + it * 32 + c * 16 + lo4;
            const float npv[4] = {np4.x, np4.y, np4.z, np4.w};
#pragma unroll
            for (int j = 0; j < 4; ++j) {
                const float sA = a0A[c][j] + a1A[c][j];
                const float dA = fmaxf(nIA + npv[j] - 2.0f * sA, 0.0f);
                TOPK_UPDATE(bvA, biA, worstA, wpA, dA, cb + j);
                const float sB = a0B[c][j] + a1B[c][j];
                const float dB = fmaxf(nIB + npv[j] - 2.0f * sB, 0.0f);
                TOPK_UPDATE(bvB, biB, worstB, wpB, dB, cb + j);
            }
        }

        asm volatile("s_waitcnt vmcnt(0)" ::: "memory");
        __builtin_amdgcn_s_barrier();
    }

    // merge scratch aliased onto Abuf (staging dead now)
    float* mVal = (float*)&Abuf[0][0];        // 2048 floats = 8KB
    int*   mIdx = (int*)&Abuf[0][8192];       // 2048 ints  = 8KB

#define DUMP_AND_MERGE(BV, BI, ROWOFF)                                          \
    {                                                                           \
        __syncthreads();                                                        \
        _Pragma("unroll")                                                       \
        for (int j = 0; j < 8; ++j) { mVal[t * 8 + j] = BV[j]; mIdx[t * 8 + j] = BI[j]; } \
        __syncthreads();                                                        \
        if (t < 64) {                                                           \
            float sv[8]; int si[8];                                             \
            _Pragma("unroll")                                                   \
            for (int j = 0; j < 8; ++j) { sv[j] = 3.4e38f; si[j] = -1; }        \
            float wv = 3.4e38f; int wp = 0;                                     \
            for (int g = 0; g < 4; ++g) {                                       \
                const int fl = ((t >> 4) << 6) + (t & 15) + 16 * g;             \
                _Pragma("unroll")                                               \
                for (int j = 0; j < 8; ++j) {                                   \
                    const float v = mVal[fl * 8 + j];                           \
                    TOPK_UPDATE(sv, si, wv, wp, v, mIdx[fl * 8 + j]);           \
                }                                                               \
            }                                                                   \
            for (int a = 1; a < 8; ++a) {                                       \
                float v = sv[a]; int ii = si[a]; int b2 = a - 1;                \
                while (b2 >= 0 && sv[b2] > v) { sv[b2+1] = sv[b2]; si[b2+1] = si[b2]; --b2; } \
                sv[b2+1] = v; si[b2+1] = ii;                                    \
            }                                                                   \
            const int row = rt * 128 + (ROWOFF) + t;                            \
            _Pragma("unroll")                                                   \
            for (int j = 0; j < 8; ++j) {                                       \
                candV[row * ncand + cs * 8 + j] = sv[j];                        \
                candI[row * ncand + cs * 8 + j] = si[j];                        \
            }                                                                   \
        }                                                                       \
    }

    DUMP_AND_MERGE(bvA, biA, 0)
    DUMP_AND_MERGE(bvB, biB, 64)
#undef DUMP_AND_MERGE
}

// ---------------------------------------------------------------------------
// MLP layer 1 (CIN=256 chunked 2x128, COUT=128, pixel-layout, no BN).
// 64-row blocks: grid 320 (0..255 peers, 256..319 input), 1 row/thread.
// ---------------------------------------------------------------------------
__global__ __launch_bounds__(256)
void gemm1_kernel(const float* __restrict__ Xp, const float* __restrict__ Xi,
                  const float* __restrict__ W, const float* __restrict__ bias,
                  float* __restrict__ outP, float* __restrict__ outI) {
    __shared__ __align__(16) float Wl[128][132];
    const int t = threadIdx.x;
    const bool isP = blockIdx.x < 256;
    const float* X = isP ? Xp : Xi;
    const int rows = isP ? 16384 : 4096;
    const int blk  = isP ? blockIdx.x : blockIdx.x - 256;
    float* outT = isP ? outP : outI;

    const int r   = blk * 64 + (t & 63);
    const int chb = (t >> 6) * 32;

    float acc[32];
#pragma unroll
    for (int q = 0; q < 32; ++q) acc[q] = 0.0f;

    for (int half = 0; half < 2; ++half) {
        __syncthreads();
        for (int i = t; i < 128 * 128; i += 256) {
            int k = i >> 7, c = i & 127;
            Wl[c][k] = W[k * 256 + half * 128 + c];
        }
        __syncthreads();
#pragma unroll 2
        for (int c = 0; c < 128; ++c) {
            const int cg = half * 128 + c;
            const float x = X[(r >> 12) * (CDIM * 4096) + cg * 4096 + (r & 4095)];
#pragma unroll
            for (int q = 0; q < 8; ++q) {
                const float4 wv = *reinterpret_cast<const float4*>(&Wl[c][chb + 4 * q]);
                acc[4 * q + 0] = fmaf(x, wv.x, acc[4 * q + 0]);
                acc[4 * q + 1] = fmaf(x, wv.y, acc[4 * q + 1]);
                acc[4 * q + 2] = fmaf(x, wv.z, acc[4 * q + 2]);
                acc[4 * q + 3] = fmaf(x, wv.w, acc[4 * q + 3]);
            }
        }
    }
#pragma unroll
    for (int q = 0; q < 32; ++q) {
        const int k = chb + q;
        outT[k * rows + r] = acc[q] + bias[k];
    }
}

// ---------------------------------------------------------------------------
// MLP layer 2 (CIN=128, COUT=64, [C][rows] input, BN+ReLU on input).
// 64-row blocks: grid 320 (0..255 peers, 256..319 input), 1 row/thread.
// ---------------------------------------------------------------------------
__global__ __launch_bounds__(256)
void gemm2_kernel(const float* __restrict__ Hp, const float* __restrict__ Hi,
                  const float* __restrict__ W, const float* __restrict__ bias,
                  const float* __restrict__ statsP, const float* __restrict__ statsI,
                  const float* __restrict__ g, const float* __restrict__ be,
                  float* __restrict__ outP, float* __restrict__ outI) {
    __shared__ __align__(16) float Wl[128][68];
    __shared__ float scL[128], shL[128];
    const int t = threadIdx.x;
    const bool isP = blockIdx.x < 256;
    const float* X = isP ? Hp : Hi;
    const float* stats = isP ? statsP : statsI;
    const float invDenom = isP ? (1.0f / 16384.0f) : (1.0f / 4096.0f);
    const int rows = isP ? 16384 : 4096;
    const int blk  = isP ? blockIdx.x : blockIdx.x - 256;
    float* outT = isP ? outP : outI;

    for (int i = t; i < 128 * 64; i += 256) {
        int k = i >> 7, c = i & 127;
        Wl[c][k] = W[k * 128 + c];
    }
    if (t < 128) {
        float mean = stats[t] * invDenom;
        float var  = stats[128 + t] * invDenom - mean * mean;
        float sc   = rsqrtf(var + 1e-5f) * g[t];
        scL[t] = sc;
        shL[t] = be[t] - mean * sc;
    }
    __syncthreads();

    const int r   = blk * 64 + (t & 63);
    const int chb = (t >> 6) * 16;

    float acc[16];
#pragma unroll
    for (int q = 0; q < 16; ++q) acc[q] = 0.0f;

#pragma unroll 2
    for (int c = 0; c < 128; ++c) {
        float x = X[c * rows + r];
        x = fmaxf(fmaf(x, scL[c], shL[c]), 0.0f);
#pragma unroll
        for (int q = 0; q < 4; ++q) {
            const float4 wv = *reinterpret_cast<const float4*>(&Wl[c][chb + 4 * q]);
            acc[4 * q + 0] = fmaf(x, wv.x, acc[4 * q + 0]);
            acc[4 * q + 1] = fmaf(x, wv.y, acc[4 * q + 1]);
            acc[4 * q + 2] = fmaf(x, wv.z, acc[4 * q + 2]);
            acc[4 * q + 3] = fmaf(x, wv.w, acc[4 * q + 3]);
        }
    }
#pragma unroll
    for (int q = 0; q < 16; ++q) {
        const int k = chb + q;
        outT[k * rows + r] = acc[q] + bias[k];
    }
}

// ---------------------------------------------------------------------------
// Column stats for peers+input in one launch. Grid = 2*C.
// ---------------------------------------------------------------------------
__global__ __launch_bounds__(256)
void colstats2x_kernel(const float* __restrict__ Hp, const float* __restrict__ Hi,
                       int C, float* __restrict__ statsP, float* __restrict__ statsI) {
    __shared__ float rs[256], rq[256];
    const bool isP = blockIdx.x < (unsigned)C;
    const int c = isP ? blockIdx.x : blockIdx.x - C;
    const float* H = isP ? Hp : Hi;
    const int rows = isP ? 16384 : 4096;
    float* stats = isP ? statsP : statsI;
    const int t = threadIdx.x;
    float s = 0.0f, q = 0.0f;
    for (int r = t; r < rows; r += 256) {
        float v = H[c * rows + r];
        s += v;
        q = fmaf(v, v, q);
    }
    rs[t] = s; rq[t] = q;
    __syncthreads();
    for (int st = 128; st > 0; st >>= 1) {
        if (t < st) { rs[t] += rs[t + st]; rq[t] += rq[t + st]; }
        __syncthreads();
    }
    if (t == 0) { stats[c] = rs[0]; stats[C + c] = rq[0]; }
}

// ---------------------------------------------------------------------------
// a-scores for peers+input in one launch. Grid = 80.
// ---------------------------------------------------------------------------
__global__ __launch_bounds__(256)
void a2x_kernel(const float* __restrict__ Hp, const float* __restrict__ Hi,
                const float* __restrict__ statsP, const float* __restrict__ statsI,
                const float* __restrict__ g, const float* __restrict__ be,
                const float* __restrict__ cwP, const float* __restrict__ cbP,
                const float* __restrict__ cwI, const float* __restrict__ cbI,
                float* __restrict__ aP, float* __restrict__ aI) {
    __shared__ float scL[64], shL[64], cwL[64];
    const bool isP = blockIdx.x < 64;
    const float* H = isP ? Hp : Hi;
    const float* stats = isP ? statsP : statsI;
    const float* cw = isP ? cwP : cwI;
    const float* cb = isP ? cbP : cbI;
    float* aout = isP ? aP : aI;
    const int rows = isP ? 16384 : 4096;
    const float invDenom = isP ? (1.0f / 16384.0f) : (1.0f / 4096.0f);
    const int blk = isP ? blockIdx.x : blockIdx.x - 64;
    const int t = threadIdx.x;
    if (t < 64) {
        float mean = stats[t] * invDenom;
        float var  = stats[64 + t] * invDenom - mean * mean;
        float sc   = rsqrtf(var + 1e-5f) * g[t];
        scL[t] = sc;
        shL[t] = be[t] - mean * sc;
        cwL[t] = cw[t];
    }
    __syncthreads();
    const int row = blk * 256 + t;
    if (row < rows) {
        float a = 0.0f;
        for (int c = 0; c < 64; ++c) {
            float v = H[c * rows + row];
            a += fmaxf(fmaf(v, scL[c], shL[c]), 0.0f) * cwL[c];
        }
        aout[row] = a + cb[0];
    }
}

// ---------------------------------------------------------------------------
// Final: merge ncand candidates/row, softplus->softmax over kNN, gather style.
// ---------------------------------------------------------------------------
__global__ __launch_bounds__(256)
void out_kernel(const float* __restrict__ candV, const int* __restrict__ candI,
                const float* __restrict__ a1, const float* __restrict__ a2,
                const float* __restrict__ PS, float* __restrict__ dout, int ncand) {
    __shared__ float wL[64][8];
    __shared__ int   aL[64][8];
    const int t  = threadIdx.x;
    const int nb = blockIdx.x * 64;

    if (t < 64) {
        const int row = nb + t;
        float sv[8]; int si[8];
#pragma unroll
        for (int j = 0; j < 8; ++j) { sv[j] = 3.4e38f; si[j] = 0; }
        float w2 = 3.4e38f; int wp = 0;
        for (int k = 0; k < ncand; ++k) {
            const float v = candV[row * ncand + k];
            TOPK_UPDATE(sv, si, w2, wp, v, candI[row * ncand + k]);
        }
        for (int a = 1; a < 8; ++a) {
            float v = sv[a]; int ii = si[a]; int b = a - 1;
            while (b >= 0 && sv[b] > v) { sv[b + 1] = sv[b]; si[b + 1] = si[b]; --b; }
            sv[b + 1] = v; si[b + 1] = ii;
        }
        const float kth = sv[4];
        int cnt = 5;
        while (cnt < 8 && sv[cnt] <= kth) ++cnt;

        const float arow = a1[row];
        float s[8], e[8];
        float mx = -1e30f;
#pragma unroll
        for (int j = 0; j < 8; ++j) s[j] = 0.0f;
        for (int j = 0; j < cnt; ++j) {
            s[j] = softplusf(arow + a2[si[j]]);
            mx = fmaxf(mx, s[j]);
        }
        float Z = 0.0f;
        for (int j = 0; j < 8; ++j) {
            e[j] = (j < cnt) ? expf(s[j] - mx) : 0.0f;
            Z += e[j];
        }
        for (int j = 0; j < 8; ++j) {
            const int ix = (j < cnt) ? si[j] : si[0];
            wL[t][j] = e[j] / Z;
            aL[t][j] = (ix >> 12) * (CDIM * 4096) + (ix & 4095);
        }
    }
    __syncthreads();

    const int rl  = t & 63;
    const int grp = t >> 6;
    float w[8]; int ab[8];
#pragma unroll
    for (int j = 0; j < 8; ++j) { w[j] = wL[rl][j]; ab[j] = aL[rl][j]; }
    const int n = nb + rl;
    for (int c = grp * 64; c < grp * 64 + 64; ++c) {
        float acc = 0.0f;
#pragma unroll
        for (int j = 0; j < 8; ++j) acc += w[j] * PS[ab[j] + c * 4096];
        dout[(CDIM + c) * 4096 + n] = acc;
    }
}

// ---------------------------------------------------------------------------
extern "C" void kernel_launch(void* const* d_in, const int* in_sizes, int n_in,
                              void* d_out, int out_size, void* d_ws, size_t ws_size,
                              hipStream_t stream) {
    const float* inp_cont    = (const float*)d_in[0];
    const float* peers_cont  = (const float*)d_in[2];
    const float* peers_style = (const float*)d_in[3];
    const float* W1  = (const float*)d_in[4];
    const float* b1  = (const float*)d_in[5];
    const float* g1  = (const float*)d_in[6];
    const float* be1 = (const float*)d_in[7];
    const float* W2  = (const float*)d_in[8];
    const float* b2  = (const float*)d_in[9];
    const float* g2  = (const float*)d_in[10];
    const float* be2 = (const float*)d_in[11];
    const float* cw1 = (const float*)d_in[12];
    const float* cb1 = (const float*)d_in[13];
    const float* cw2 = (const float*)d_in[14];
    const float* cb2 = (const float*)d_in[15];
    float* out = (float*)d_out;
    char*  wsb = (char*)d_ws;

    int nsplit;
    if      (ws_size >= (size_t)25400000) nsplit = 16;
    else if (ws_size >= (size_t)23300000) nsplit = 8;
    else return;
    const int ncand = nsplit * 8;
    const size_t candBytes = (size_t)NROWS * ncand * 4;

    // workspace layout (bytes)
    uint4* xpBhi = (uint4*)(wsb + 0);                    //  8 MB
    uint4* xpBlo = (uint4*)(wsb + 8388608);              //  8 MB
    uint4* xiBhi = (uint4*)(wsb + 16777216);             //  2 MB
    uint4* xiBlo = (uint4*)(wsb + 18874368);             //  2 MB
    float* normP = (float*)(wsb + 20971520);             //  64 KB
    float* normI = (float*)(wsb + 21037056);             //  16 KB
    float* candV = (float*)(wsb + 21053440);             //  candBytes
    int*   candI = (int*)  (wsb + 21053440 + candBytes); //  candBytes
    char*  tail  = wsb + 21053440 + 2 * candBytes;
    float* a2    = (float*)(tail);                       //  64 KB
    float* a1    = (float*)(tail + 65536);               //  16 KB
    float* s1p   = (float*)(tail + 81920);               //  1 KB
    float* s1i   = (float*)(tail + 82944);               //  1 KB
    float* s2p   = (float*)(tail + 83968);               //  512
    float* s2i   = (float*)(tail + 84480);               //  512
    // Aliased AFTER dist kernel completes (xpB/xiB dead by then):
    float* H1Tp  = (float*)(wsb + 0);                    // 8 MB
    float* H2Tp  = (float*)(wsb + 8388608);              // 4 MB
    float* H1Ti  = (float*)(wsb + 16777216);             // 2 MB
    float* H2Ti  = (float*)(wsb + 18874368);             // 1 MB

    copy_kernel<<<1024, 256, 0, stream>>>((const float4*)inp_cont, (float4*)out, 262144);
    norms_kernel<<<80, 256, 0, stream>>>(inp_cont, peers_cont, normI, normP);
    convert_kernel<<<256, 256, 0, stream>>>(inp_cont, xiBhi, xiBlo, 4096);
    convert_kernel<<<1024, 256, 0, stream>>>(peers_cont, xpBhi, xpBlo, 16384);

    dist_topk_mfma<<<32 * nsplit, 256, 0, stream>>>(xpBhi, xpBlo, xiBhi, xiBlo,
                                                    normI, normP, candV, candI, nsplit);

    gemm1_kernel<<<320, 256, 0, stream>>>(peers_cont, inp_cont, W1, b1, H1Tp, H1Ti);
    colstats2x_kernel<<<256, 256, 0, stream>>>(H1Tp, H1Ti, 128, s1p, s1i);
    gemm2_kernel<<<320, 256, 0, stream>>>(H1Tp, H1Ti, W2, b2, s1p, s1i, g1, be1, H2Tp, H2Ti);
    colstats2x_kernel<<<128, 256, 0, stream>>>(H2Tp, H2Ti, 64, s2p, s2i);
    a2x_kernel<<<80, 256, 0, stream>>>(H2Tp, H2Ti, s2p, s2i, g2, be2,
                                       cw2, cb2, cw1, cb1, a2, a1);

    out_kernel<<<64, 256, 0, stream>>>(candV, candI, a1, a2, peers_style, out, ncand);
}

// Round 11
// 467.223 us; speedup vs baseline: 2.5612x; 1.0082x over previous
//
#include <hip/hip_runtime.h>
#include <math.h>

#define NROWS 4096
#define MCOLS 16384
#define CDIM  256

typedef _Float16 half8 __attribute__((ext_vector_type(8)));
typedef float f32x4 __attribute__((ext_vector_type(4)));

static __device__ __forceinline__ float softplusf(float x) {
    return fmaxf(x, 0.0f) + log1pf(expf(-fabsf(x)));
}

// Classic top-8 update (used in small merge phases only)
#define TOPK_UPDATE(BV, BI, WORST, WP, V, IDX)                                 \
    if ((V) < (WORST)) {                                                       \
        BV[WP] = (V); BI[WP] = (IDX);                                          \
        WORST = BV[0]; WP = 0;                                                 \
        _Pragma("unroll")                                                      \
        for (int _q = 1; _q < 8; ++_q)                                         \
            if (BV[_q] > WORST) { WORST = BV[_q]; WP = _q; }                   \
    }

// Hot-loop top-8: slot index in 3 LSBs of the value; worst = max-tree; gate =
// min(tau, worst) where tau is the row-shared exact upper bound on row-8th.
#define TOPK_FAST(BV, BI, WORST, GATE, TAU, V, IDX)                            \
    if ((V) < (GATE)) {                                                        \
        const int _wp = __float_as_int(WORST) & 7;                             \
        BV[_wp] = __uint_as_float((__float_as_uint(V) & ~7u) | (unsigned)_wp); \
        BI[_wp] = (IDX);                                                       \
        const float _m0 = fmaxf(fmaxf(BV[0], BV[1]), fmaxf(BV[2], BV[3]));     \
        const float _m1 = fmaxf(fmaxf(BV[4], BV[5]), fmaxf(BV[6], BV[7]));     \
        WORST = fmaxf(_m0, _m1);                                               \
        GATE = fminf(TAU, WORST);                                              \
    }

// ---------------------------------------------------------------------------
// Passthrough copy
// ---------------------------------------------------------------------------
__global__ __launch_bounds__(256)
void copy_kernel(const float4* __restrict__ src, float4* __restrict__ dst, int n4) {
    int i = blockIdx.x * blockDim.x + threadIdx.x;
    if (i < n4) dst[i] = src[i];
}

// ---------------------------------------------------------------------------
// Column norms from ORIGINAL fp32 data (fp64 accumulate).
// ---------------------------------------------------------------------------
__global__ __launch_bounds__(256)
void norms_kernel(const float* __restrict__ xiT, const float* __restrict__ xpT,
                  float* __restrict__ normI, float* __restrict__ normP) {
    int i = blockIdx.x * blockDim.x + threadIdx.x;
    if (i >= MCOLS + NROWS) return;
    const float* p;
    int base;
    if (i < MCOLS) { p = xpT; base = (i >> 12) * (CDIM * 4096) + (i & 4095); }
    else           { p = xiT; base = i - MCOLS; }
    double s = 0.0;
    for (int c = 0; c < CDIM; ++c) {
        float v = p[base + c * 4096];
        s = fma((double)v, (double)v, s);
    }
    if (i < MCOLS) normP[i] = (float)s;
    else           normI[i - MCOLS] = (float)s;
}

// ---------------------------------------------------------------------------
// fp32 [K=256][cols] -> fragment-ready fp16 hi/lo.
// chunk (ct*8 + kt)*64 + lane holds 8 halves:
//   element = x[col = ct*16 + (lane&15)][k = kt*32 + (lane>>4)*8 + j]
// ---------------------------------------------------------------------------
__global__ __launch_bounds__(256)
void convert_kernel(const float* __restrict__ src, uint4* __restrict__ dhi,
                    uint4* __restrict__ dlo, int ncols) {
    __shared__ float S[64][65];
    const int t = threadIdx.x;
    const int tilesPerRow = ncols >> 6;
    const int colbase = (blockIdx.x % tilesPerRow) << 6;
    const int ktbase  = (blockIdx.x / tilesPerRow) << 6;
    const int b = colbase >> 12;
    const int pixbase = colbase & 4095;
    const float* sp = src + (size_t)b * (CDIM * 4096) + (size_t)ktbase * 4096 + pixbase;

    for (int i = t; i < 4096; i += 256) {
        int kk = i >> 6, cc = i & 63;
        S[kk][cc] = sp[kk * 4096 + cc];
    }
    __syncthreads();

    const int l = t & 63;
#pragma unroll
    for (int s = 0; s < 2; ++s) {
        const int pid  = (t >> 6) + 4 * s;
        const int ct_l = pid & 3;
        const int kt_l = pid >> 2;
        const int c_l  = ct_l * 16 + (l & 15);
        const int k_l  = kt_l * 32 + ((l >> 4) << 3);
        half8 h, lo;
#pragma unroll
        for (int j = 0; j < 8; ++j) {
            float v = S[k_l + j][c_l];
            _Float16 hv = (_Float16)v;
            h[j]  = hv;
            lo[j] = (_Float16)(v - (float)hv);
        }
        const int ct_g = (colbase >> 4) + ct_l;
        const int kt_g = (ktbase >> 5) + kt_l;
        const size_t off = (size_t)(ct_g * 8 + kt_g) * 64 + l;
        dhi[off] = *reinterpret_cast<uint4*>(&h);
        dlo[off] = *reinterpret_cast<uint4*>(&lo);
    }
}

// ---------------------------------------------------------------------------
// MFMA distance + per-row top-8.
// Grid: 32 rowtiles (128 rows) * nsplit colsplits; 256 threads = 4 waves.
// Selection: slot-in-LSB top-8 + row-shared exact bound tau (2x shfl_xor).
// ---------------------------------------------------------------------------
__global__ __launch_bounds__(256, 2)
void dist_topk_mfma(const uint4* __restrict__ xpBhi, const uint4* __restrict__ xpBlo,
                    const uint4* __restrict__ xiBhi, const uint4* __restrict__ xiBlo,
                    const float* __restrict__ normI, const float* __restrict__ normP,
                    float* __restrict__ candV, int* __restrict__ candI,
                    int nsplit) {
    __shared__ __align__(16) char Abuf[2][32768];  // [buf][part 16KB][ct 8KB][kt 1KB][lane 16B]
    __shared__ __align__(16) float nPl[2048];

    const int t = threadIdx.x;
    const int w = t >> 6;        // wave 0..3
    const int l = t & 63;
    const int rt = blockIdx.x / nsplit;     // 0..31
    const int cs = blockIdx.x % nsplit;
    const int niter = (MCOLS / 32) / nsplit;
    const int span  = MCOLS / nsplit;
    const int colbase = cs * span;
    const int ncand = nsplit * 8;

    for (int i = t; i < span; i += 256) nPl[i] = normP[colbase + i];

    // xi fragments: rowgroups rgA = w, rgB = w+4
    uint4 bhA[8], blA[8], bhB[8], blB[8];
    const int ctA = rt * 8 + w;
    const int ctB = ctA + 4;
#pragma unroll
    for (int kt = 0; kt < 8; ++kt) {
        bhA[kt] = xiBhi[(size_t)(ctA * 8 + kt) * 64 + l];
        blA[kt] = xiBlo[(size_t)(ctA * 8 + kt) * 64 + l];
        bhB[kt] = xiBhi[(size_t)(ctB * 8 + kt) * 64 + l];
        blB[kt] = xiBlo[(size_t)(ctB * 8 + kt) * 64 + l];
    }

    const float nIA = normI[rt * 128 + w * 16 + (l & 15)];
    const float nIB = normI[rt * 128 + (w + 4) * 16 + (l & 15)];

    // top-8 buffers: value has slot index in 3 LSBs
    float bvA[8], bvB[8]; int biA[8], biB[8];
#pragma unroll
    for (int j = 0; j < 8; ++j) {
        bvA[j] = __uint_as_float((0x7f7ffff8u) | (unsigned)j);
        bvB[j] = bvA[j];
        biA[j] = -1; biB[j] = -1;
    }
    float worstA = bvA[7], worstB = bvB[7];
    float tauA = bvA[7], tauB = bvB[7];
    float gateA = bvA[7], gateB = bvB[7];

    const char* gb = (w >= 2) ? (const char*)xpBlo : (const char*)xpBhi;
    const char* srcBase = gb + (size_t)(cs * niter * 2 + (w & 1)) * 8192 + l * 16;
    char* dbBase = &Abuf[0][(w >> 1) * 16384 + (w & 1) * 8192];

    auto stage = [&](int it, int buf) {
        const char* src = srcBase + (size_t)it * 16384;
        char* db = dbBase + buf * 32768;
#pragma unroll
        for (int kt = 0; kt < 8; ++kt)
            __builtin_amdgcn_global_load_lds(
                (const __attribute__((address_space(1))) void*)(src + kt * 1024),
                (__attribute__((address_space(3))) void*)(db + kt * 1024),
                16, 0, 0);
    };

    stage(0, 0);
    asm volatile("s_waitcnt vmcnt(0)" ::: "memory");
    __syncthreads();

    for (int it = 0; it < niter; ++it) {
        if (it < niter - 1) stage(it + 1, (it + 1) & 1);

        const char* Ab = Abuf[it & 1];
        const int lo4 = (l >> 4) << 2;

        f32x4 a0A[2], a1A[2], a0B[2], a1B[2];
#pragma unroll
        for (int c = 0; c < 2; ++c) {
            a0A[c] = f32x4{0.f,0.f,0.f,0.f}; a1A[c] = f32x4{0.f,0.f,0.f,0.f};
            a0B[c] = f32x4{0.f,0.f,0.f,0.f}; a1B[c] = f32x4{0.f,0.f,0.f,0.f};
        }
        __builtin_amdgcn_s_setprio(1);
#pragma unroll
        for (int kt = 0; kt < 8; ++kt) {
            const half8 vhA = *reinterpret_cast<const half8*>(&bhA[kt]);
            const half8 vlA = *reinterpret_cast<const half8*>(&blA[kt]);
            const half8 vhB = *reinterpret_cast<const half8*>(&bhB[kt]);
            const half8 vlB = *reinterpret_cast<const half8*>(&blB[kt]);
#pragma unroll
            for (int c = 0; c < 2; ++c) {
                const half8 ah = *reinterpret_cast<const half8*>(Ab + c * 8192 + kt * 1024 + l * 16);
                const half8 al = *reinterpret_cast<const half8*>(Ab + 16384 + c * 8192 + kt * 1024 + l * 16);
                a0A[c] = __builtin_amdgcn_mfma_f32_16x16x32_f16(ah, vhA, a0A[c], 0, 0, 0);
                a0B[c] = __builtin_amdgcn_mfma_f32_16x16x32_f16(ah, vhB, a0B[c], 0, 0, 0);
                a1A[c] = __builtin_amdgcn_mfma_f32_16x16x32_f16(ah, vlA, a1A[c], 0, 0, 0);
                a1B[c] = __builtin_amdgcn_mfma_f32_16x16x32_f16(ah, vlB, a1B[c], 0, 0, 0);
                a0A[c] = __builtin_amdgcn_mfma_f32_16x16x32_f16(al, vhA, a0A[c], 0, 0, 0);
                a0B[c] = __builtin_amdgcn_mfma_f32_16x16x32_f16(al, vhB, a0B[c], 0, 0, 0);
            }
        }
        __builtin_amdgcn_s_setprio(0);

#pragma unroll
        for (int c = 0; c < 2; ++c) {
            const float4 np4 = *reinterpret_cast<const float4*>(&nPl[it * 32 + c * 16 + lo4]);
            const int cb = colbase + it * 32 + c * 16 + lo4;
            const float npv[4] = {np4.x, np4.y, np4.z, np4.w};
#pragma unroll
            for (int j = 0; j < 4; ++j) {
                const float sA = a0A[c][j] + a1A[c][j];
                const float dA = fmaxf(nIA + npv[j] - 2.0f * sA, 0.0f);
                TOPK_FAST(bvA, biA, worstA, gateA, tauA, dA, cb + j);
                const float sB = a0B[c][j] + a1B[c][j];
                const float dB = fmaxf(nIB + npv[j] - 2.0f * sB, 0.0f);
                TOPK_FAST(bvB, biB, worstB, gateB, tauB, dB, cb + j);
            }
        }

        // row-shared exact bound: min over the row's 4 lanes of lane-worst
        {
            float w1 = fminf(worstA, __shfl_xor(worstA, 16));
            tauA = fminf(w1, __shfl_xor(w1, 32));
            gateA = fminf(tauA, worstA);
            float w2 = fminf(worstB, __shfl_xor(worstB, 16));
            tauB = fminf(w2, __shfl_xor(w2, 32));
            gateB = fminf(tauB, worstB);
        }

        asm volatile("s_waitcnt vmcnt(0)" ::: "memory");
        __builtin_amdgcn_s_barrier();
    }

    // merge scratch aliased onto Abuf (staging dead now)
    float* mVal = (float*)&Abuf[0][0];
    int*   mIdx = (int*)&Abuf[0][8192];

#define DUMP_AND_MERGE(BV, BI, ROWOFF)                                          \
    {                                                                           \
        __syncthreads();                                                        \
        _Pragma("unroll")                                                       \
        for (int j = 0; j < 8; ++j) { mVal[t * 8 + j] = BV[j]; mIdx[t * 8 + j] = BI[j]; } \
        __syncthreads();                                                        \
        if (t < 64) {                                                           \
            float sv[8]; int si[8];                                             \
            _Pragma("unroll")                                                   \
            for (int j = 0; j < 8; ++j) { sv[j] = 3.4e38f; si[j] = -1; }        \
            float wv = 3.4e38f; int wp = 0;                                     \
            for (int g = 0; g < 4; ++g) {                                       \
                const int fl = ((t >> 4) << 6) + (t & 15) + 16 * g;             \
                _Pragma("unroll")                                               \
                for (int j = 0; j < 8; ++j) {                                   \
                    const float v = mVal[fl * 8 + j];                           \
                    TOPK_UPDATE(sv, si, wv, wp, v, mIdx[fl * 8 + j]);           \
                }                                                               \
            }                                                                   \
            for (int a = 1; a < 8; ++a) {                                       \
                float v = sv[a]; int ii = si[a]; int b2 = a - 1;                \
                while (b2 >= 0 && sv[b2] > v) { sv[b2+1] = sv[b2]; si[b2+1] = si[b2]; --b2; } \
                sv[b2+1] = v; si[b2+1] = ii;                                    \
            }                                                                   \
            const int row = rt * 128 + (ROWOFF) + t;                            \
            _Pragma("unroll")                                                   \
            for (int j = 0; j < 8; ++j) {                                       \
                candV[row * ncand + cs * 8 + j] = sv[j];                        \
                candI[row * ncand + cs * 8 + j] = si[j];                        \
            }                                                                   \
        }                                                                       \
    }

    DUMP_AND_MERGE(bvA, biA, 0)
    DUMP_AND_MERGE(bvB, biB, 64)
#undef DUMP_AND_MERGE
}

// ---------------------------------------------------------------------------
// MLP layer 1 (CIN=256 chunked 2x128, COUT=128, pixel-layout, no BN).
// ---------------------------------------------------------------------------
__global__ __launch_bounds__(256)
void gemm1_kernel(const float* __restrict__ Xp, const float* __restrict__ Xi,
                  const float* __restrict__ W, const float* __restrict__ bias,
                  float* __restrict__ outP, float* __restrict__ outI) {
    __shared__ __align__(16) float Wl[128][132];
    const int t = threadIdx.x;
    const bool isP = blockIdx.x < 256;
    const float* X = isP ? Xp : Xi;
    const int rows = isP ? 16384 : 4096;
    const int blk  = isP ? blockIdx.x : blockIdx.x - 256;
    float* outT = isP ? outP : outI;

    const int r   = blk * 64 + (t & 63);
    const int chb = (t >> 6) * 32;

    float acc[32];
#pragma unroll
    for (int q = 0; q < 32; ++q) acc[q] = 0.0f;

    for (int half = 0; half < 2; ++half) {
        __syncthreads();
        for (int i = t; i < 128 * 128; i += 256) {
            int k = i >> 7, c = i & 127;
            Wl[c][k] = W[k * 256 + half * 128 + c];
        }
        __syncthreads();
#pragma unroll 2
        for (int c = 0; c < 128; ++c) {
            const int cg = half * 128 + c;
            const float x = X[(r >> 12) * (CDIM * 4096) + cg * 4096 + (r & 4095)];
#pragma unroll
            for (int q = 0; q < 8; ++q) {
                const float4 wv = *reinterpret_cast<const float4*>(&Wl[c][chb + 4 * q]);
                acc[4 * q + 0] = fmaf(x, wv.x, acc[4 * q + 0]);
                acc[4 * q + 1] = fmaf(x, wv.y, acc[4 * q + 1]);
                acc[4 * q + 2] = fmaf(x, wv.z, acc[4 * q + 2]);
                acc[4 * q + 3] = fmaf(x, wv.w, acc[4 * q + 3]);
            }
        }
    }
#pragma unroll
    for (int q = 0; q < 32; ++q) {
        const int k = chb + q;
        outT[k * rows + r] = acc[q] + bias[k];
    }
}

// ---------------------------------------------------------------------------
// MLP layer 2 (CIN=128, COUT=64, BN+ReLU on input).
// ---------------------------------------------------------------------------
__global__ __launch_bounds__(256)
void gemm2_kernel(const float* __restrict__ Hp, const float* __restrict__ Hi,
                  const float* __restrict__ W, const float* __restrict__ bias,
                  const float* __restrict__ statsP, const float* __restrict__ statsI,
                  const float* __restrict__ g, const float* __restrict__ be,
                  float* __restrict__ outP, float* __restrict__ outI) {
    __shared__ __align__(16) float Wl[128][68];
    __shared__ float scL[128], shL[128];
    const int t = threadIdx.x;
    const bool isP = blockIdx.x < 256;
    const float* X = isP ? Hp : Hi;
    const float* stats = isP ? statsP : statsI;
    const float invDenom = isP ? (1.0f / 16384.0f) : (1.0f / 4096.0f);
    const int rows = isP ? 16384 : 4096;
    const int blk  = isP ? blockIdx.x : blockIdx.x - 256;
    float* outT = isP ? outP : outI;

    for (int i = t; i < 128 * 64; i += 256) {
        int k = i >> 7, c = i & 127;
        Wl[c][k] = W[k * 128 + c];
    }
    if (t < 128) {
        float mean = stats[t] * invDenom;
        float var  = stats[128 + t] * invDenom - mean * mean;
        float sc   = rsqrtf(var + 1e-5f) * g[t];
        scL[t] = sc;
        shL[t] = be[t] - mean * sc;
    }
    __syncthreads();

    const int r   = blk * 64 + (t & 63);
    const int chb = (t >> 6) * 16;

    float acc[16];
#pragma unroll
    for (int q = 0; q < 16; ++q) acc[q] = 0.0f;

#pragma unroll 2
    for (int c = 0; c < 128; ++c) {
        float x = X[c * rows + r];
        x = fmaxf(fmaf(x, scL[c], shL[c]), 0.0f);
#pragma unroll
        for (int q = 0; q < 4; ++q) {
            const float4 wv = *reinterpret_cast<const float4*>(&Wl[c][chb + 4 * q]);
            acc[4 * q + 0] = fmaf(x, wv.x, acc[4 * q + 0]);
            acc[4 * q + 1] = fmaf(x, wv.y, acc[4 * q + 1]);
            acc[4 * q + 2] = fmaf(x, wv.z, acc[4 * q + 2]);
            acc[4 * q + 3] = fmaf(x, wv.w, acc[4 * q + 3]);
        }
    }
#pragma unroll
    for (int q = 0; q < 16; ++q) {
        const int k = chb + q;
        outT[k * rows + r] = acc[q] + bias[k];
    }
}

// ---------------------------------------------------------------------------
// Column stats for peers+input in one launch. Grid = 2*C.
// ---------------------------------------------------------------------------
__global__ __launch_bounds__(256)
void colstats2x_kernel(const float* __restrict__ Hp, const float* __restrict__ Hi,
                       int C, float* __restrict__ statsP, float* __restrict__ statsI) {
    __shared__ float rs[256], rq[256];
    const bool isP = blockIdx.x < (unsigned)C;
    const int c = isP ? blockIdx.x : blockIdx.x - C;
    const float* H = isP ? Hp : Hi;
    const int rows = isP ? 16384 : 4096;
    float* stats = isP ? statsP : statsI;
    const int t = threadIdx.x;
    float s = 0.0f, q = 0.0f;
    for (int r = t; r < rows; r += 256) {
        float v = H[c * rows + r];
        s += v;
        q = fmaf(v, v, q);
    }
    rs[t] = s; rq[t] = q;
    __syncthreads();
    for (int st = 128; st > 0; st >>= 1) {
        if (t < st) { rs[t] += rs[t + st]; rq[t] += rq[t + st]; }
        __syncthreads();
    }
    if (t == 0) { stats[c] = rs[0]; stats[C + c] = rq[0]; }
}

// ---------------------------------------------------------------------------
// a-scores for peers+input in one launch. Grid = 80.
// ---------------------------------------------------------------------------
__global__ __launch_bounds__(256)
void a2x_kernel(const float* __restrict__ Hp, const float* __restrict__ Hi,
                const float* __restrict__ statsP, const float* __restrict__ statsI,
                const float* __restrict__ g, const float* __restrict__ be,
                const float* __restrict__ cwP, const float* __restrict__ cbP,
                const float* __restrict__ cwI, const float* __restrict__ cbI,
                float* __restrict__ aP, float* __restrict__ aI) {
    __shared__ float scL[64], shL[64], cwL[64];
    const bool isP = blockIdx.x < 64;
    const float* H = isP ? Hp : Hi;
    const float* stats = isP ? statsP : statsI;
    const float* cw = isP ? cwP : cwI;
    const float* cb = isP ? cbP : cbI;
    float* aout = isP ? aP : aI;
    const int rows = isP ? 16384 : 4096;
    const float invDenom = isP ? (1.0f / 16384.0f) : (1.0f / 4096.0f);
    const int blk = isP ? blockIdx.x : blockIdx.x - 64;
    const int t = threadIdx.x;
    if (t < 64) {
        float mean = stats[t] * invDenom;
        float var  = stats[64 + t] * invDenom - mean * mean;
        float sc   = rsqrtf(var + 1e-5f) * g[t];
        scL[t] = sc;
        shL[t] = be[t] - mean * sc;
        cwL[t] = cw[t];
    }
    __syncthreads();
    const int row = blk * 256 + t;
    if (row < rows) {
        float a = 0.0f;
        for (int c = 0; c < 64; ++c) {
            float v = H[c * rows + row];
            a += fmaxf(fmaf(v, scL[c], shL[c]), 0.0f) * cwL[c];
        }
        aout[row] = a + cb[0];
    }
}

// ---------------------------------------------------------------------------
// Final: merge ncand candidates/row, softplus->softmax over kNN, gather style.
// ---------------------------------------------------------------------------
__global__ __launch_bounds__(256)
void out_kernel(const float* __restrict__ candV, const int* __restrict__ candI,
                const float* __restrict__ a1, const float* __restrict__ a2,
                const float* __restrict__ PS, float* __restrict__ dout, int ncand) {
    __shared__ float wL[64][8];
    __shared__ int   aL[64][8];
    const int t  = threadIdx.x;
    const int nb = blockIdx.x * 64;

    if (t < 64) {
        const int row = nb + t;
        float sv[8]; int si[8];
#pragma unroll
        for (int j = 0; j < 8; ++j) { sv[j] = 3.4e38f; si[j] = 0; }
        float w2 = 3.4e38f; int wp = 0;
        for (int k = 0; k < ncand; ++k) {
            const float v = candV[row * ncand + k];
            TOPK_UPDATE(sv, si, w2, wp, v, candI[row * ncand + k]);
        }
        for (int a = 1; a < 8; ++a) {
            float v = sv[a]; int ii = si[a]; int b = a - 1;
            while (b >= 0 && sv[b] > v) { sv[b + 1] = sv[b]; si[b + 1] = si[b]; --b; }
            sv[b + 1] = v; si[b + 1] = ii;
        }
        const float kth = sv[4];
        int cnt = 5;
        while (cnt < 8 && sv[cnt] <= kth) ++cnt;

        const float arow = a1[row];
        float s[8], e[8];
        float mx = -1e30f;
#pragma unroll
        for (int j = 0; j < 8; ++j) s[j] = 0.0f;
        for (int j = 0; j < cnt; ++j) {
            s[j] = softplusf(arow + a2[si[j]]);
            mx = fmaxf(mx, s[j]);
        }
        float Z = 0.0f;
        for (int j = 0; j < 8; ++j) {
            e[j] = (j < cnt) ? expf(s[j] - mx) : 0.0f;
            Z += e[j];
        }
        for (int j = 0; j < 8; ++j) {
            const int ix = (j < cnt) ? si[j] : si[0];
            wL[t][j] = e[j] / Z;
            aL[t][j] = (ix >> 12) * (CDIM * 4096) + (ix & 4095);
        }
    }
    __syncthreads();

    const int rl  = t & 63;
    const int grp = t >> 6;
    float w[8]; int ab[8];
#pragma unroll
    for (int j = 0; j < 8; ++j) { w[j] = wL[rl][j]; ab[j] = aL[rl][j]; }
    const int n = nb + rl;
    for (int c = grp * 64; c < grp * 64 + 64; ++c) {
        float acc = 0.0f;
#pragma unroll
        for (int j = 0; j < 8; ++j) acc += w[j] * PS[ab[j] + c * 4096];
        dout[(CDIM + c) * 4096 + n] = acc;
    }
}

// ---------------------------------------------------------------------------
extern "C" void kernel_launch(void* const* d_in, const int* in_sizes, int n_in,
                              void* d_out, int out_size, void* d_ws, size_t ws_size,
                              hipStream_t stream) {
    const float* inp_cont    = (const float*)d_in[0];
    const float* peers_cont  = (const float*)d_in[2];
    const float* peers_style = (const float*)d_in[3];
    const float* W1  = (const float*)d_in[4];
    const float* b1  = (const float*)d_in[5];
    const float* g1  = (const float*)d_in[6];
    const float* be1 = (const float*)d_in[7];
    const float* W2  = (const float*)d_in[8];
    const float* b2  = (const float*)d_in[9];
    const float* g2  = (const float*)d_in[10];
    const float* be2 = (const float*)d_in[11];
    const float* cw1 = (const float*)d_in[12];
    const float* cb1 = (const float*)d_in[13];
    const float* cw2 = (const float*)d_in[14];
    const float* cb2 = (const float*)d_in[15];
    float* out = (float*)d_out;
    char*  wsb = (char*)d_ws;

    int nsplit;
    if      (ws_size >= (size_t)25400000) nsplit = 16;
    else if (ws_size >= (size_t)23300000) nsplit = 8;
    else return;
    const int ncand = nsplit * 8;
    const size_t candBytes = (size_t)NROWS * ncand * 4;

    // workspace layout (bytes)
    uint4* xpBhi = (uint4*)(wsb + 0);                    //  8 MB
    uint4* xpBlo = (uint4*)(wsb + 8388608);              //  8 MB
    uint4* xiBhi = (uint4*)(wsb + 16777216);             //  2 MB
    uint4* xiBlo = (uint4*)(wsb + 18874368);             //  2 MB
    float* normP = (float*)(wsb + 20971520);             //  64 KB
    float* normI = (float*)(wsb + 21037056);             //  16 KB
    float* candV = (float*)(wsb + 21053440);             //  candBytes
    int*   candI = (int*)  (wsb + 21053440 + candBytes); //  candBytes
    char*  tail  = wsb + 21053440 + 2 * candBytes;
    float* a2    = (float*)(tail);                       //  64 KB
    float* a1    = (float*)(tail + 65536);               //  16 KB
    float* s1p   = (float*)(tail + 81920);               //  1 KB
    float* s1i   = (float*)(tail + 82944);               //  1 KB
    float* s2p   = (float*)(tail + 83968);               //  512
    float* s2i   = (float*)(tail + 84480);               //  512
    // Aliased AFTER dist kernel completes:
    float* H1Tp  = (float*)(wsb + 0);                    // 8 MB
    float* H2Tp  = (float*)(wsb + 8388608);              // 4 MB
    float* H1Ti  = (float*)(wsb + 16777216);             // 2 MB
    float* H2Ti  = (float*)(wsb + 18874368);             // 1 MB

    copy_kernel<<<1024, 256, 0, stream>>>((const float4*)inp_cont, (float4*)out, 262144);
    norms_kernel<<<80, 256, 0, stream>>>(inp_cont, peers_cont, normI, normP);
    convert_kernel<<<256, 256, 0, stream>>>(inp_cont, xiBhi, xiBlo, 4096);
    convert_kernel<<<1024, 256, 0, stream>>>(peers_cont, xpBhi, xpBlo, 16384);

    dist_topk_mfma<<<32 * nsplit, 256, 0, stream>>>(xpBhi, xpBlo, xiBhi, xiBlo,
                                                    normI, normP, candV, candI, nsplit);

    gemm1_kernel<<<320, 256, 0, stream>>>(peers_cont, inp_cont, W1, b1, H1Tp, H1Ti);
    colstats2x_kernel<<<256, 256, 0, stream>>>(H1Tp, H1Ti, 128, s1p, s1i);
    gemm2_kernel<<<320, 256, 0, stream>>>(H1Tp, H1Ti, W2, b2, s1p, s1i, g1, be1, H2Tp, H2Ti);
    colstats2x_kernel<<<128, 256, 0, stream>>>(H2Tp, H2Ti, 64, s2p, s2i);
    a2x_kernel<<<80, 256, 0, stream>>>(H2Tp, H2Ti, s2p, s2i, g2, be2,
                                       cw2, cb2, cw1, cb1, a2, a1);

    out_kernel<<<64, 256, 0, stream>>>(candV, candI, a1, a2, peers_style, out, ncand);
}

// Round 12
// 453.484 us; speedup vs baseline: 2.6388x; 1.0303x over previous
//
#include <hip/hip_runtime.h>
#include <math.h>

#define NROWS 4096
#define MCOLS 16384
#define CDIM  256

typedef _Float16 half8 __attribute__((ext_vector_type(8)));
typedef float f32x4 __attribute__((ext_vector_type(4)));

static __device__ __forceinline__ float softplusf(float x) {
    return fmaxf(x, 0.0f) + log1pf(expf(-fabsf(x)));
}

// Classic top-8 update (merge phases only)
#define TOPK_UPDATE(BV, BI, WORST, WP, V, IDX)                                 \
    if ((V) < (WORST)) {                                                       \
        BV[WP] = (V); BI[WP] = (IDX);                                          \
        WORST = BV[0]; WP = 0;                                                 \
        _Pragma("unroll")                                                      \
        for (int _q = 1; _q < 8; ++_q)                                         \
            if (BV[_q] > WORST) { WORST = BV[_q]; WP = _q; }                   \
    }

// Hot-loop top-8: slot index in 3 LSBs; worst via max-tree; gate = min(tau, worst).
#define TOPK_FAST(BV, BI, WORST, GATE, TAU, V, IDX)                            \
    if ((V) < (GATE)) {                                                        \
        const int _wp = __float_as_int(WORST) & 7;                             \
        BV[_wp] = __uint_as_float((__float_as_uint(V) & ~7u) | (unsigned)_wp); \
        BI[_wp] = (IDX);                                                       \
        const float _m0 = fmaxf(fmaxf(BV[0], BV[1]), fmaxf(BV[2], BV[3]));     \
        const float _m1 = fmaxf(fmaxf(BV[4], BV[5]), fmaxf(BV[6], BV[7]));     \
        WORST = fmaxf(_m0, _m1);                                               \
        GATE = fminf(TAU, WORST);                                              \
    }

// ---------------------------------------------------------------------------
// Passthrough copy
// ---------------------------------------------------------------------------
__global__ __launch_bounds__(256)
void copy_kernel(const float4* __restrict__ src, float4* __restrict__ dst, int n4) {
    int i = blockIdx.x * blockDim.x + threadIdx.x;
    if (i < n4) dst[i] = src[i];
}

// ---------------------------------------------------------------------------
// Column norms, fp32 tree (4 threads/column x 64 channels + shfl combine).
// Grid 320 x 256: cols 0..16383 peers, 16384..20479 input. Coalesced.
// ---------------------------------------------------------------------------
__global__ __launch_bounds__(256)
void norms_kernel(const float* __restrict__ xiT, const float* __restrict__ xpT,
                  float* __restrict__ normI, float* __restrict__ normP) {
    const int t = threadIdx.x;
    const int col = blockIdx.x * 64 + (t >> 2);
    const int sub = t & 3;
    const float* p;
    int base;
    if (col < MCOLS) { p = xpT; base = (col >> 12) * (CDIM * 4096) + (col & 4095); }
    else             { p = xiT; base = col - MCOLS; }
    float s = 0.0f;
#pragma unroll 8
    for (int k = 0; k < 64; ++k) {
        const float v = p[base + (sub * 64 + k) * 4096];
        s = fmaf(v, v, s);
    }
    s += __shfl_xor(s, 1);
    s += __shfl_xor(s, 2);
    if (sub == 0) {
        if (col < MCOLS) normP[col] = s;
        else             normI[col - MCOLS] = s;
    }
}

// ---------------------------------------------------------------------------
// fp32 [K=256][cols] -> fragment-ready fp16 hi/lo.
// chunk (ct*8 + kt)*64 + lane holds 8 halves:
//   element = x[col = ct*16 + (lane&15)][k = kt*32 + (lane>>4)*8 + j]
// ---------------------------------------------------------------------------
__global__ __launch_bounds__(256)
void convert_kernel(const float* __restrict__ src, uint4* __restrict__ dhi,
                    uint4* __restrict__ dlo, int ncols) {
    __shared__ float S[64][65];
    const int t = threadIdx.x;
    const int tilesPerRow = ncols >> 6;
    const int colbase = (blockIdx.x % tilesPerRow) << 6;
    const int ktbase  = (blockIdx.x / tilesPerRow) << 6;
    const int b = colbase >> 12;
    const int pixbase = colbase & 4095;
    const float* sp = src + (size_t)b * (CDIM * 4096) + (size_t)ktbase * 4096 + pixbase;

    for (int i = t; i < 4096; i += 256) {
        int kk = i >> 6, cc = i & 63;
        S[kk][cc] = sp[kk * 4096 + cc];
    }
    __syncthreads();

    const int l = t & 63;
#pragma unroll
    for (int s = 0; s < 2; ++s) {
        const int pid  = (t >> 6) + 4 * s;
        const int ct_l = pid & 3;
        const int kt_l = pid >> 2;
        const int c_l  = ct_l * 16 + (l & 15);
        const int k_l  = kt_l * 32 + ((l >> 4) << 3);
        half8 h, lo;
#pragma unroll
        for (int j = 0; j < 8; ++j) {
            float v = S[k_l + j][c_l];
            _Float16 hv = (_Float16)v;
            h[j]  = hv;
            lo[j] = (_Float16)(v - (float)hv);
        }
        const int ct_g = (colbase >> 4) + ct_l;
        const int kt_g = (ktbase >> 5) + kt_l;
        const size_t off = (size_t)(ct_g * 8 + kt_g) * 64 + l;
        dhi[off] = *reinterpret_cast<uint4*>(&h);
        dlo[off] = *reinterpret_cast<uint4*>(&lo);
    }
}

// ---------------------------------------------------------------------------
// MFMA distance + per-row top-8.
// Grid: 32 rowtiles (128 rows) * nsplit colsplits; 256 threads = 4 waves.
// Selection: all 16 dists to regs, ballot-skip per 8-group, slot-in-LSB top-8,
// row-shared exact bound tau (2x shfl_xor).
// ---------------------------------------------------------------------------
__global__ __launch_bounds__(256, 2)
void dist_topk_mfma(const uint4* __restrict__ xpBhi, const uint4* __restrict__ xpBlo,
                    const uint4* __restrict__ xiBhi, const uint4* __restrict__ xiBlo,
                    const float* __restrict__ normI, const float* __restrict__ normP,
                    float* __restrict__ candV, int* __restrict__ candI,
                    int nsplit) {
    __shared__ __align__(16) char Abuf[2][32768];  // [buf][part 16KB][ct 8KB][kt 1KB][lane 16B]
    __shared__ __align__(16) float nPl[2048];

    const int t = threadIdx.x;
    const int w = t >> 6;        // wave 0..3
    const int l = t & 63;
    const int rt = blockIdx.x / nsplit;     // 0..31
    const int cs = blockIdx.x % nsplit;
    const int niter = (MCOLS / 32) / nsplit;
    const int span  = MCOLS / nsplit;
    const int colbase = cs * span;
    const int ncand = nsplit * 8;

    for (int i = t; i < span; i += 256) nPl[i] = normP[colbase + i];

    // xi fragments: rowgroups rgA = w, rgB = w+4
    uint4 bhA[8], blA[8], bhB[8], blB[8];
    const int ctA = rt * 8 + w;
    const int ctB = ctA + 4;
#pragma unroll
    for (int kt = 0; kt < 8; ++kt) {
        bhA[kt] = xiBhi[(size_t)(ctA * 8 + kt) * 64 + l];
        blA[kt] = xiBlo[(size_t)(ctA * 8 + kt) * 64 + l];
        bhB[kt] = xiBhi[(size_t)(ctB * 8 + kt) * 64 + l];
        blB[kt] = xiBlo[(size_t)(ctB * 8 + kt) * 64 + l];
    }

    const float nIA = normI[rt * 128 + w * 16 + (l & 15)];
    const float nIB = normI[rt * 128 + (w + 4) * 16 + (l & 15)];

    float bvA[8], bvB[8]; int biA[8], biB[8];
#pragma unroll
    for (int j = 0; j < 8; ++j) {
        bvA[j] = __uint_as_float((0x7f7ffff8u) | (unsigned)j);
        bvB[j] = bvA[j];
        biA[j] = -1; biB[j] = -1;
    }
    float worstA = bvA[7], worstB = bvB[7];
    float tauA = bvA[7], tauB = bvB[7];
    float gateA = bvA[7], gateB = bvB[7];

    const char* gb = (w >= 2) ? (const char*)xpBlo : (const char*)xpBhi;
    const char* srcBase = gb + (size_t)(cs * niter * 2 + (w & 1)) * 8192 + l * 16;
    char* dbBase = &Abuf[0][(w >> 1) * 16384 + (w & 1) * 8192];

    auto stage = [&](int it, int buf) {
        const char* src = srcBase + (size_t)it * 16384;
        char* db = dbBase + buf * 32768;
#pragma unroll
        for (int kt = 0; kt < 8; ++kt)
            __builtin_amdgcn_global_load_lds(
                (const __attribute__((address_space(1))) void*)(src + kt * 1024),
                (__attribute__((address_space(3))) void*)(db + kt * 1024),
                16, 0, 0);
    };

    stage(0, 0);
    asm volatile("s_waitcnt vmcnt(0)" ::: "memory");
    __syncthreads();

    for (int it = 0; it < niter; ++it) {
        if (it < niter - 1) stage(it + 1, (it + 1) & 1);

        const char* Ab = Abuf[it & 1];
        const int lo4 = (l >> 4) << 2;

        f32x4 a0A[2], a1A[2], a0B[2], a1B[2];
#pragma unroll
        for (int c = 0; c < 2; ++c) {
            a0A[c] = f32x4{0.f,0.f,0.f,0.f}; a1A[c] = f32x4{0.f,0.f,0.f,0.f};
            a0B[c] = f32x4{0.f,0.f,0.f,0.f}; a1B[c] = f32x4{0.f,0.f,0.f,0.f};
        }
        __builtin_amdgcn_s_setprio(1);
#pragma unroll
        for (int kt = 0; kt < 8; ++kt) {
            const half8 vhA = *reinterpret_cast<const half8*>(&bhA[kt]);
            const half8 vlA = *reinterpret_cast<const half8*>(&blA[kt]);
            const half8 vhB = *reinterpret_cast<const half8*>(&bhB[kt]);
            const half8 vlB = *reinterpret_cast<const half8*>(&blB[kt]);
#pragma unroll
            for (int c = 0; c < 2; ++c) {
                const half8 ah = *reinterpret_cast<const half8*>(Ab + c * 8192 + kt * 1024 + l * 16);
                const half8 al = *reinterpret_cast<const half8*>(Ab + 16384 + c * 8192 + kt * 1024 + l * 16);
                a0A[c] = __builtin_amdgcn_mfma_f32_16x16x32_f16(ah, vhA, a0A[c], 0, 0, 0);
                a0B[c] = __builtin_amdgcn_mfma_f32_16x16x32_f16(ah, vhB, a0B[c], 0, 0, 0);
                a1A[c] = __builtin_amdgcn_mfma_f32_16x16x32_f16(ah, vlA, a1A[c], 0, 0, 0);
                a1B[c] = __builtin_amdgcn_mfma_f32_16x16x32_f16(ah, vlB, a1B[c], 0, 0, 0);
                a0A[c] = __builtin_amdgcn_mfma_f32_16x16x32_f16(al, vhA, a0A[c], 0, 0, 0);
                a0B[c] = __builtin_amdgcn_mfma_f32_16x16x32_f16(al, vhB, a0B[c], 0, 0, 0);
            }
        }
        __builtin_amdgcn_s_setprio(0);

        // all 16 dists into registers
        float dAv[8], dBv[8];
#pragma unroll
        for (int c = 0; c < 2; ++c) {
            const float4 np4 = *reinterpret_cast<const float4*>(&nPl[it * 32 + c * 16 + lo4]);
            const float npv[4] = {np4.x, np4.y, np4.z, np4.w};
#pragma unroll
            for (int j = 0; j < 4; ++j) {
                dAv[c * 4 + j] = fmaxf(nIA + npv[j] - 2.0f * (a0A[c][j] + a1A[c][j]), 0.0f);
                dBv[c * 4 + j] = fmaxf(nIB + npv[j] - 2.0f * (a0B[c][j] + a1B[c][j]), 0.0f);
            }
        }
        const float mnA = fminf(fminf(fminf(dAv[0], dAv[1]), fminf(dAv[2], dAv[3])),
                                fminf(fminf(dAv[4], dAv[5]), fminf(dAv[6], dAv[7])));
        const float mnB = fminf(fminf(fminf(dBv[0], dBv[1]), fminf(dBv[2], dBv[3])),
                                fminf(fminf(dBv[4], dBv[5]), fminf(dBv[6], dBv[7])));
        const int ib = colbase + it * 32 + lo4;
        if (__any(mnA < gateA)) {
#pragma unroll
            for (int q = 0; q < 8; ++q) {
                const int cb = ib + (q >> 2) * 16 + (q & 3);
                TOPK_FAST(bvA, biA, worstA, gateA, tauA, dAv[q], cb);
            }
        }
        if (__any(mnB < gateB)) {
#pragma unroll
            for (int q = 0; q < 8; ++q) {
                const int cb = ib + (q >> 2) * 16 + (q & 3);
                TOPK_FAST(bvB, biB, worstB, gateB, tauB, dBv[q], cb);
            }
        }

        // row-shared exact bound: min over the row's 4 lanes of lane-worst
        {
            float w1 = fminf(worstA, __shfl_xor(worstA, 16));
            tauA = fminf(w1, __shfl_xor(w1, 32));
            gateA = fminf(tauA, worstA);
            float w2 = fminf(worstB, __shfl_xor(worstB, 16));
            tauB = fminf(w2, __shfl_xor(w2, 32));
            gateB = fminf(tauB, worstB);
        }

        asm volatile("s_waitcnt vmcnt(0)" ::: "memory");
        __builtin_amdgcn_s_barrier();
    }

    // merge scratch aliased onto Abuf (staging dead now)
    float* mVal = (float*)&Abuf[0][0];
    int*   mIdx = (int*)&Abuf[0][8192];

#define DUMP_AND_MERGE(BV, BI, ROWOFF)                                          \
    {                                                                           \
        __syncthreads();                                                        \
        _Pragma("unroll")                                                       \
        for (int j = 0; j < 8; ++j) { mVal[t * 8 + j] = BV[j]; mIdx[t * 8 + j] = BI[j]; } \
        __syncthreads();                                                        \
        if (t < 64) {                                                           \
            float sv[8]; int si[8];                                             \
            _Pragma("unroll")                                                   \
            for (int j = 0; j < 8; ++j) { sv[j] = 3.4e38f; si[j] = -1; }        \
            float wv = 3.4e38f; int wp = 0;                                     \
            for (int g = 0; g < 4; ++g) {                                       \
                const int fl = ((t >> 4) << 6) + (t & 15) + 16 * g;             \
                _Pragma("unroll")                                               \
                for (int j = 0; j < 8; ++j) {                                   \
                    const float v = mVal[fl * 8 + j];                           \
                    TOPK_UPDATE(sv, si, wv, wp, v, mIdx[fl * 8 + j]);           \
                }                                                               \
            }                                                                   \
            for (int a = 1; a < 8; ++a) {                                       \
                float v = sv[a]; int ii = si[a]; int b2 = a - 1;                \
                while (b2 >= 0 && sv[b2] > v) { sv[b2+1] = sv[b2]; si[b2+1] = si[b2]; --b2; } \
                sv[b2+1] = v; si[b2+1] = ii;                                    \
            }                                                                   \
            const int row = rt * 128 + (ROWOFF) + t;                            \
            _Pragma("unroll")                                                   \
            for (int j = 0; j < 8; ++j) {                                       \
                candV[row * ncand + cs * 8 + j] = sv[j];                        \
                candI[row * ncand + cs * 8 + j] = si[j];                        \
            }                                                                   \
        }                                                                       \
    }

    DUMP_AND_MERGE(bvA, biA, 0)
    DUMP_AND_MERGE(bvB, biB, 64)
#undef DUMP_AND_MERGE
}

// ---------------------------------------------------------------------------
// MLP layer 1 (CIN=256 chunked 2x128, COUT=128, pixel-layout, no BN).
// ---------------------------------------------------------------------------
__global__ __launch_bounds__(256)
void gemm1_kernel(const float* __restrict__ Xp, const float* __restrict__ Xi,
                  const float* __restrict__ W, const float* __restrict__ bias,
                  float* __restrict__ outP, float* __restrict__ outI) {
    __shared__ __align__(16) float Wl[128][132];
    const int t = threadIdx.x;
    const bool isP = blockIdx.x < 256;
    const float* X = isP ? Xp : Xi;
    const int rows = isP ? 16384 : 4096;
    const int blk  = isP ? blockIdx.x : blockIdx.x - 256;
    float* outT = isP ? outP : outI;

    const int r   = blk * 64 + (t & 63);
    const int chb = (t >> 6) * 32;

    float acc[32];
#pragma unroll
    for (int q = 0; q < 32; ++q) acc[q] = 0.0f;

    for (int half = 0; half < 2; ++half) {
        __syncthreads();
        for (int i = t; i < 128 * 128; i += 256) {
            int k = i >> 7, c = i & 127;
            Wl[c][k] = W[k * 256 + half * 128 + c];
        }
        __syncthreads();
#pragma unroll 2
        for (int c = 0; c < 128; ++c) {
            const int cg = half * 128 + c;
            const float x = X[(r >> 12) * (CDIM * 4096) + cg * 4096 + (r & 4095)];
#pragma unroll
            for (int q = 0; q < 8; ++q) {
                const float4 wv = *reinterpret_cast<const float4*>(&Wl[c][chb + 4 * q]);
                acc[4 * q + 0] = fmaf(x, wv.x, acc[4 * q + 0]);
                acc[4 * q + 1] = fmaf(x, wv.y, acc[4 * q + 1]);
                acc[4 * q + 2] = fmaf(x, wv.z, acc[4 * q + 2]);
                acc[4 * q + 3] = fmaf(x, wv.w, acc[4 * q + 3]);
            }
        }
    }
#pragma unroll
    for (int q = 0; q < 32; ++q) {
        const int k = chb + q;
        outT[k * rows + r] = acc[q] + bias[k];
    }
}

// ---------------------------------------------------------------------------
// MLP layer 2 (CIN=128, COUT=64, BN+ReLU on input).
// ---------------------------------------------------------------------------
__global__ __launch_bounds__(256)
void gemm2_kernel(const float* __restrict__ Hp, const float* __restrict__ Hi,
                  const float* __restrict__ W, const float* __restrict__ bias,
                  const float* __restrict__ statsP, const float* __restrict__ statsI,
                  const float* __restrict__ g, const float* __restrict__ be,
                  float* __restrict__ outP, float* __restrict__ outI) {
    __shared__ __align__(16) float Wl[128][68];
    __shared__ float scL[128], shL[128];
    const int t = threadIdx.x;
    const bool isP = blockIdx.x < 256;
    const float* X = isP ? Hp : Hi;
    const float* stats = isP ? statsP : statsI;
    const float invDenom = isP ? (1.0f / 16384.0f) : (1.0f / 4096.0f);
    const int rows = isP ? 16384 : 4096;
    const int blk  = isP ? blockIdx.x : blockIdx.x - 256;
    float* outT = isP ? outP : outI;

    for (int i = t; i < 128 * 64; i += 256) {
        int k = i >> 7, c = i & 127;
        Wl[c][k] = W[k * 128 + c];
    }
    if (t < 128) {
        float mean = stats[t] * invDenom;
        float var  = stats[128 + t] * invDenom - mean * mean;
        float sc   = rsqrtf(var + 1e-5f) * g[t];
        scL[t] = sc;
        shL[t] = be[t] - mean * sc;
    }
    __syncthreads();

    const int r   = blk * 64 + (t & 63);
    const int chb = (t >> 6) * 16;

    float acc[16];
#pragma unroll
    for (int q = 0; q < 16; ++q) acc[q] = 0.0f;

#pragma unroll 2
    for (int c = 0; c < 128; ++c) {
        float x = X[c * rows + r];
        x = fmaxf(fmaf(x, scL[c], shL[c]), 0.0f);
#pragma unroll
        for (int q = 0; q < 4; ++q) {
            const float4 wv = *reinterpret_cast<const float4*>(&Wl[c][chb + 4 * q]);
            acc[4 * q + 0] = fmaf(x, wv.x, acc[4 * q + 0]);
            acc[4 * q + 1] = fmaf(x, wv.y, acc[4 * q + 1]);
            acc[4 * q + 2] = fmaf(x, wv.z, acc[4 * q + 2]);
            acc[4 * q + 3] = fmaf(x, wv.w, acc[4 * q + 3]);
        }
    }
#pragma unroll
    for (int q = 0; q < 16; ++q) {
        const int k = chb + q;
        outT[k * rows + r] = acc[q] + bias[k];
    }
}

// ---------------------------------------------------------------------------
// Column stats for peers+input in one launch. Grid = 2*C.
// ---------------------------------------------------------------------------
__global__ __launch_bounds__(256)
void colstats2x_kernel(const float* __restrict__ Hp, const float* __restrict__ Hi,
                       int C, float* __restrict__ statsP, float* __restrict__ statsI) {
    __shared__ float rs[256], rq[256];
    const bool isP = blockIdx.x < (unsigned)C;
    const int c = isP ? blockIdx.x : blockIdx.x - C;
    const float* H = isP ? Hp : Hi;
    const int rows = isP ? 16384 : 4096;
    float* stats = isP ? statsP : statsI;
    const int t = threadIdx.x;
    float s = 0.0f, q = 0.0f;
    for (int r = t; r < rows; r += 256) {
        float v = H[c * rows + r];
        s += v;
        q = fmaf(v, v, q);
    }
    rs[t] = s; rq[t] = q;
    __syncthreads();
    for (int st = 128; st > 0; st >>= 1) {
        if (t < st) { rs[t] += rs[t + st]; rq[t] += rq[t + st]; }
        __syncthreads();
    }
    if (t == 0) { stats[c] = rs[0]; stats[C + c] = rq[0]; }
}

// ---------------------------------------------------------------------------
// a-scores for peers+input in one launch. Grid = 80.
// ---------------------------------------------------------------------------
__global__ __launch_bounds__(256)
void a2x_kernel(const float* __restrict__ Hp, const float* __restrict__ Hi,
                const float* __restrict__ statsP, const float* __restrict__ statsI,
                const float* __restrict__ g, const float* __restrict__ be,
                const float* __restrict__ cwP, const float* __restrict__ cbP,
                const float* __restrict__ cwI, const float* __restrict__ cbI,
                float* __restrict__ aP, float* __restrict__ aI) {
    __shared__ float scL[64], shL[64], cwL[64];
    const bool isP = blockIdx.x < 64;
    const float* H = isP ? Hp : Hi;
    const float* stats = isP ? statsP : statsI;
    const float* cw = isP ? cwP : cwI;
    const float* cb = isP ? cbP : cbI;
    float* aout = isP ? aP : aI;
    const int rows = isP ? 16384 : 4096;
    const float invDenom = isP ? (1.0f / 16384.0f) : (1.0f / 4096.0f);
    const int blk = isP ? blockIdx.x : blockIdx.x - 64;
    const int t = threadIdx.x;
    if (t < 64) {
        float mean = stats[t] * invDenom;
        float var  = stats[64 + t] * invDenom - mean * mean;
        float sc   = rsqrtf(var + 1e-5f) * g[t];
        scL[t] = sc;
        shL[t] = be[t] - mean * sc;
        cwL[t] = cw[t];
    }
    __syncthreads();
    const int row = blk * 256 + t;
    if (row < rows) {
        float a = 0.0f;
        for (int c = 0; c < 64; ++c) {
            float v = H[c * rows + row];
            a += fmaxf(fmaf(v, scL[c], shL[c]), 0.0f) * cwL[c];
        }
        aout[row] = a + cb[0];
    }
}

// ---------------------------------------------------------------------------
// Final: merge ncand candidates/row, softplus->softmax over kNN, gather style.
// ---------------------------------------------------------------------------
__global__ __launch_bounds__(256)
void out_kernel(const float* __restrict__ candV, const int* __restrict__ candI,
                const float* __restrict__ a1, const float* __restrict__ a2,
                const float* __restrict__ PS, float* __restrict__ dout, int ncand) {
    __shared__ float wL[64][8];
    __shared__ int   aL[64][8];
    const int t  = threadIdx.x;
    const int nb = blockIdx.x * 64;

    if (t < 64) {
        const int row = nb + t;
        float sv[8]; int si[8];
#pragma unroll
        for (int j = 0; j < 8; ++j) { sv[j] = 3.4e38f; si[j] = 0; }
        float w2 = 3.4e38f; int wp = 0;
        for (int k = 0; k < ncand; ++k) {
            const float v = candV[row * ncand + k];
            TOPK_UPDATE(sv, si, w2, wp, v, candI[row * ncand + k]);
        }
        for (int a = 1; a < 8; ++a) {
            float v = sv[a]; int ii = si[a]; int b = a - 1;
            while (b >= 0 && sv[b] > v) { sv[b + 1] = sv[b]; si[b + 1] = si[b]; --b; }
            sv[b + 1] = v; si[b + 1] = ii;
        }
        const float kth = sv[4];
        int cnt = 5;
        while (cnt < 8 && sv[cnt] <= kth) ++cnt;

        const float arow = a1[row];
        float s[8], e[8];
        float mx = -1e30f;
#pragma unroll
        for (int j = 0; j < 8; ++j) s[j] = 0.0f;
        for (int j = 0; j < cnt; ++j) {
            s[j] = softplusf(arow + a2[si[j]]);
            mx = fmaxf(mx, s[j]);
        }
        float Z = 0.0f;
        for (int j = 0; j < 8; ++j) {
            e[j] = (j < cnt) ? expf(s[j] - mx) : 0.0f;
            Z += e[j];
        }
        for (int j = 0; j < 8; ++j) {
            const int ix = (j < cnt) ? si[j] : si[0];
            wL[t][j] = e[j] / Z;
            aL[t][j] = (ix >> 12) * (CDIM * 4096) + (ix & 4095);
        }
    }
    __syncthreads();

    const int rl  = t & 63;
    const int grp = t >> 6;
    float w[8]; int ab[8];
#pragma unroll
    for (int j = 0; j < 8; ++j) { w[j] = wL[rl][j]; ab[j] = aL[rl][j]; }
    const int n = nb + rl;
    for (int c = grp * 64; c < grp * 64 + 64; ++c) {
        float acc = 0.0f;
#pragma unroll
        for (int j = 0; j < 8; ++j) acc += w[j] * PS[ab[j] + c * 4096];
        dout[(CDIM + c) * 4096 + n] = acc;
    }
}

// ---------------------------------------------------------------------------
extern "C" void kernel_launch(void* const* d_in, const int* in_sizes, int n_in,
                              void* d_out, int out_size, void* d_ws, size_t ws_size,
                              hipStream_t stream) {
    const float* inp_cont    = (const float*)d_in[0];
    const float* peers_cont  = (const float*)d_in[2];
    const float* peers_style = (const float*)d_in[3];
    const float* W1  = (const float*)d_in[4];
    const float* b1  = (const float*)d_in[5];
    const float* g1  = (const float*)d_in[6];
    const float* be1 = (const float*)d_in[7];
    const float* W2  = (const float*)d_in[8];
    const float* b2  = (const float*)d_in[9];
    const float* g2  = (const float*)d_in[10];
    const float* be2 = (const float*)d_in[11];
    const float* cw1 = (const float*)d_in[12];
    const float* cb1 = (const float*)d_in[13];
    const float* cw2 = (const float*)d_in[14];
    const float* cb2 = (const float*)d_in[15];
    float* out = (float*)d_out;
    char*  wsb = (char*)d_ws;

    int nsplit;
    if      (ws_size >= (size_t)25400000) nsplit = 16;
    else if (ws_size >= (size_t)23300000) nsplit = 8;
    else return;
    const int ncand = nsplit * 8;
    const size_t candBytes = (size_t)NROWS * ncand * 4;

    // workspace layout (bytes)
    uint4* xpBhi = (uint4*)(wsb + 0);                    //  8 MB
    uint4* xpBlo = (uint4*)(wsb + 8388608);              //  8 MB
    uint4* xiBhi = (uint4*)(wsb + 16777216);             //  2 MB
    uint4* xiBlo = (uint4*)(wsb + 18874368);             //  2 MB
    float* normP = (float*)(wsb + 20971520);             //  64 KB
    float* normI = (float*)(wsb + 21037056);             //  16 KB
    float* candV = (float*)(wsb + 21053440);             //  candBytes
    int*   candI = (int*)  (wsb + 21053440 + candBytes); //  candBytes
    char*  tail  = wsb + 21053440 + 2 * candBytes;
    float* a2    = (float*)(tail);                       //  64 KB
    float* a1    = (float*)(tail + 65536);               //  16 KB
    float* s1p   = (float*)(tail + 81920);               //  1 KB
    float* s1i   = (float*)(tail + 82944);               //  1 KB
    float* s2p   = (float*)(tail + 83968);               //  512
    float* s2i   = (float*)(tail + 84480);               //  512
    // Aliased AFTER dist kernel completes:
    float* H1Tp  = (float*)(wsb + 0);                    // 8 MB
    float* H2Tp  = (float*)(wsb + 8388608);              // 4 MB
    float* H1Ti  = (float*)(wsb + 16777216);             // 2 MB
    float* H2Ti  = (float*)(wsb + 18874368);             // 1 MB

    copy_kernel<<<1024, 256, 0, stream>>>((const float4*)inp_cont, (float4*)out, 262144);
    norms_kernel<<<320, 256, 0, stream>>>(inp_cont, peers_cont, normI, normP);
    convert_kernel<<<256, 256, 0, stream>>>(inp_cont, xiBhi, xiBlo, 4096);
    convert_kernel<<<1024, 256, 0, stream>>>(peers_cont, xpBhi, xpBlo, 16384);

    dist_topk_mfma<<<32 * nsplit, 256, 0, stream>>>(xpBhi, xpBlo, xiBhi, xiBlo,
                                                    normI, normP, candV, candI, nsplit);

    gemm1_kernel<<<320, 256, 0, stream>>>(peers_cont, inp_cont, W1, b1, H1Tp, H1Ti);
    colstats2x_kernel<<<256, 256, 0, stream>>>(H1Tp, H1Ti, 128, s1p, s1i);
    gemm2_kernel<<<320, 256, 0, stream>>>(H1Tp, H1Ti, W2, b2, s1p, s1i, g1, be1, H2Tp, H2Ti);
    colstats2x_kernel<<<128, 256, 0, stream>>>(H2Tp, H2Ti, 64, s2p, s2i);
    a2x_kernel<<<80, 256, 0, stream>>>(H2Tp, H2Ti, s2p, s2i, g2, be2,
                                       cw2, cb2, cw1, cb1, a2, a1);

    out_kernel<<<64, 256, 0, stream>>>(candV, candI, a1, a2, peers_style, out, ncand);
}

// Round 13
// 450.665 us; speedup vs baseline: 2.6553x; 1.0063x over previous
//
#include <hip/hip_runtime.h>
#include <math.h>

#define NROWS 4096
#define MCOLS 16384
#define CDIM  256

typedef _Float16 half8 __attribute__((ext_vector_type(8)));
typedef float f32x4 __attribute__((ext_vector_type(4)));

static __device__ __forceinline__ float softplusf(float x) {
    return fmaxf(x, 0.0f) + log1pf(expf(-fabsf(x)));
}

// Classic top-8 update (merge phases only)
#define TOPK_UPDATE(BV, BI, WORST, WP, V, IDX)                                 \
    if ((V) < (WORST)) {                                                       \
        BV[WP] = (V); BI[WP] = (IDX);                                          \
        WORST = BV[0]; WP = 0;                                                 \
        _Pragma("unroll")                                                      \
        for (int _q = 1; _q < 8; ++_q)                                         \
            if (BV[_q] > WORST) { WORST = BV[_q]; WP = _q; }                   \
    }

// Hot-loop top-8: slot index in 3 LSBs; worst via max-tree; gate = min(tau, worst).
#define TOPK_FAST(BV, BI, WORST, GATE, TAU, V, IDX)                            \
    if ((V) < (GATE)) {                                                        \
        const int _wp = __float_as_int(WORST) & 7;                             \
        BV[_wp] = __uint_as_float((__float_as_uint(V) & ~7u) | (unsigned)_wp); \
        BI[_wp] = (IDX);                                                       \
        const float _m0 = fmaxf(fmaxf(BV[0], BV[1]), fmaxf(BV[2], BV[3]));     \
        const float _m1 = fmaxf(fmaxf(BV[4], BV[5]), fmaxf(BV[6], BV[7]));     \
        WORST = fmaxf(_m0, _m1);                                               \
        GATE = fminf(TAU, WORST);                                              \
    }

// ---------------------------------------------------------------------------
// Passthrough copy
// ---------------------------------------------------------------------------
__global__ __launch_bounds__(256)
void copy_kernel(const float4* __restrict__ src, float4* __restrict__ dst, int n4) {
    int i = blockIdx.x * blockDim.x + threadIdx.x;
    if (i < n4) dst[i] = src[i];
}

// ---------------------------------------------------------------------------
// Column norms, fp32 tree (4 threads/column x 64 channels + shfl combine).
// ---------------------------------------------------------------------------
__global__ __launch_bounds__(256)
void norms_kernel(const float* __restrict__ xiT, const float* __restrict__ xpT,
                  float* __restrict__ normI, float* __restrict__ normP) {
    const int t = threadIdx.x;
    const int col = blockIdx.x * 64 + (t >> 2);
    const int sub = t & 3;
    const float* p;
    int base;
    if (col < MCOLS) { p = xpT; base = (col >> 12) * (CDIM * 4096) + (col & 4095); }
    else             { p = xiT; base = col - MCOLS; }
    float s = 0.0f;
#pragma unroll 8
    for (int k = 0; k < 64; ++k) {
        const float v = p[base + (sub * 64 + k) * 4096];
        s = fmaf(v, v, s);
    }
    s += __shfl_xor(s, 1);
    s += __shfl_xor(s, 2);
    if (sub == 0) {
        if (col < MCOLS) normP[col] = s;
        else             normI[col - MCOLS] = s;
    }
}

// ---------------------------------------------------------------------------
// fp32 [K=256][cols] -> fragment-ready fp16 hi/lo.
// ---------------------------------------------------------------------------
__global__ __launch_bounds__(256)
void convert_kernel(const float* __restrict__ src, uint4* __restrict__ dhi,
                    uint4* __restrict__ dlo, int ncols) {
    __shared__ float S[64][65];
    const int t = threadIdx.x;
    const int tilesPerRow = ncols >> 6;
    const int colbase = (blockIdx.x % tilesPerRow) << 6;
    const int ktbase  = (blockIdx.x / tilesPerRow) << 6;
    const int b = colbase >> 12;
    const int pixbase = colbase & 4095;
    const float* sp = src + (size_t)b * (CDIM * 4096) + (size_t)ktbase * 4096 + pixbase;

    for (int i = t; i < 4096; i += 256) {
        int kk = i >> 6, cc = i & 63;
        S[kk][cc] = sp[kk * 4096 + cc];
    }
    __syncthreads();

    const int l = t & 63;
#pragma unroll
    for (int s = 0; s < 2; ++s) {
        const int pid  = (t >> 6) + 4 * s;
        const int ct_l = pid & 3;
        const int kt_l = pid >> 2;
        const int c_l  = ct_l * 16 + (l & 15);
        const int k_l  = kt_l * 32 + ((l >> 4) << 3);
        half8 h, lo;
#pragma unroll
        for (int j = 0; j < 8; ++j) {
            float v = S[k_l + j][c_l];
            _Float16 hv = (_Float16)v;
            h[j]  = hv;
            lo[j] = (_Float16)(v - (float)hv);
        }
        const int ct_g = (colbase >> 4) + ct_l;
        const int kt_g = (ktbase >> 5) + kt_l;
        const size_t off = (size_t)(ct_g * 8 + kt_g) * 64 + l;
        dhi[off] = *reinterpret_cast<uint4*>(&h);
        dlo[off] = *reinterpret_cast<uint4*>(&lo);
    }
}

// ---------------------------------------------------------------------------
// MFMA distance + per-row top-8.  Counted-vmcnt pipeline (T4):
// stage(it+1) -> vmcnt(8) -> barrier -> compute/select -> raw barrier.
// Selection in v = 0.5*normP - dot domain (affine in d2; ranking-equivalent).
// XCD-aware cs mapping (T1).
// ---------------------------------------------------------------------------
__global__ __launch_bounds__(256, 2)
void dist_topk_mfma(const uint4* __restrict__ xpBhi, const uint4* __restrict__ xpBlo,
                    const uint4* __restrict__ xiBhi, const uint4* __restrict__ xiBlo,
                    const float* __restrict__ normI, const float* __restrict__ normP,
                    float* __restrict__ candV, int* __restrict__ candI,
                    int nsplit) {
    __shared__ __align__(16) char Abuf[2][32768];
    __shared__ __align__(16) float nPl[2048];   // 0.5 * normP

    const int t = threadIdx.x;
    const int w = t >> 6;
    const int l = t & 63;
    // XCD-aware split mapping (bijective): pin each cs span to one XCD's L2
    int rt, cs;
    if (nsplit == 16) { cs = ((blockIdx.x & 7) << 1) | ((blockIdx.x >> 3) & 1); rt = blockIdx.x >> 4; }
    else              { cs = blockIdx.x & 7;                                    rt = blockIdx.x >> 3; }
    const int niter = (MCOLS / 32) / nsplit;
    const int span  = MCOLS / nsplit;
    const int colbase = cs * span;
    const int ncand = nsplit * 8;

    for (int i = t; i < span; i += 256) nPl[i] = 0.5f * normP[colbase + i];

    // xi fragments: rowgroups rgA = w, rgB = w+4
    uint4 bhA[8], blA[8], bhB[8], blB[8];
    const int ctA = rt * 8 + w;
    const int ctB = ctA + 4;
#pragma unroll
    for (int kt = 0; kt < 8; ++kt) {
        bhA[kt] = xiBhi[(size_t)(ctA * 8 + kt) * 64 + l];
        blA[kt] = xiBlo[(size_t)(ctA * 8 + kt) * 64 + l];
        bhB[kt] = xiBhi[(size_t)(ctB * 8 + kt) * 64 + l];
        blB[kt] = xiBlo[(size_t)(ctB * 8 + kt) * 64 + l];
    }

    float bvA[8], bvB[8]; int biA[8], biB[8];
#pragma unroll
    for (int j = 0; j < 8; ++j) {
        bvA[j] = __uint_as_float((0x7f7ffff8u) | (unsigned)j);
        bvB[j] = bvA[j];
        biA[j] = -1; biB[j] = -1;
    }
    float worstA = bvA[7], worstB = bvB[7];
    float tauA = bvA[7], tauB = bvB[7];
    float gateA = bvA[7], gateB = bvB[7];

    const char* gb = (w >= 2) ? (const char*)xpBlo : (const char*)xpBhi;
    const char* srcBase = gb + (size_t)(cs * niter * 2 + (w & 1)) * 8192 + l * 16;
    char* dbBase = &Abuf[0][(w >> 1) * 16384 + (w & 1) * 8192];

    auto stage = [&](int it, int buf) {
        const char* src = srcBase + (size_t)it * 16384;
        char* db = dbBase + buf * 32768;
#pragma unroll
        for (int kt = 0; kt < 8; ++kt)
            __builtin_amdgcn_global_load_lds(
                (const __attribute__((address_space(1))) void*)(src + kt * 1024),
                (__attribute__((address_space(3))) void*)(db + kt * 1024),
                16, 0, 0);
    };

    stage(0, 0);
    asm volatile("s_waitcnt vmcnt(0)" ::: "memory");
    __builtin_amdgcn_s_barrier();

    for (int it = 0; it < niter; ++it) {
        if (it < niter - 1) {
            stage(it + 1, (it + 1) & 1);
            // stage(it) landed; stage(it+1)'s 8 loads stay in flight
            asm volatile("s_waitcnt vmcnt(8)" ::: "memory");
        } else {
            asm volatile("s_waitcnt vmcnt(0)" ::: "memory");
        }
        __builtin_amdgcn_s_barrier();
        __builtin_amdgcn_sched_barrier(0);

        const char* Ab = Abuf[it & 1];
        const int lo4 = (l >> 4) << 2;

        f32x4 a0A[2], a1A[2], a0B[2], a1B[2];
#pragma unroll
        for (int c = 0; c < 2; ++c) {
            a0A[c] = f32x4{0.f,0.f,0.f,0.f}; a1A[c] = f32x4{0.f,0.f,0.f,0.f};
            a0B[c] = f32x4{0.f,0.f,0.f,0.f}; a1B[c] = f32x4{0.f,0.f,0.f,0.f};
        }
        __builtin_amdgcn_s_setprio(1);
#pragma unroll
        for (int kt = 0; kt < 8; ++kt) {
            const half8 vhA = *reinterpret_cast<const half8*>(&bhA[kt]);
            const half8 vlA = *reinterpret_cast<const half8*>(&blA[kt]);
            const half8 vhB = *reinterpret_cast<const half8*>(&bhB[kt]);
            const half8 vlB = *reinterpret_cast<const half8*>(&blB[kt]);
#pragma unroll
            for (int c = 0; c < 2; ++c) {
                const half8 ah = *reinterpret_cast<const half8*>(Ab + c * 8192 + kt * 1024 + l * 16);
                const half8 al = *reinterpret_cast<const half8*>(Ab + 16384 + c * 8192 + kt * 1024 + l * 16);
                a0A[c] = __builtin_amdgcn_mfma_f32_16x16x32_f16(ah, vhA, a0A[c], 0, 0, 0);
                a0B[c] = __builtin_amdgcn_mfma_f32_16x16x32_f16(ah, vhB, a0B[c], 0, 0, 0);
                a1A[c] = __builtin_amdgcn_mfma_f32_16x16x32_f16(ah, vlA, a1A[c], 0, 0, 0);
                a1B[c] = __builtin_amdgcn_mfma_f32_16x16x32_f16(ah, vlB, a1B[c], 0, 0, 0);
                a0A[c] = __builtin_amdgcn_mfma_f32_16x16x32_f16(al, vhA, a0A[c], 0, 0, 0);
                a0B[c] = __builtin_amdgcn_mfma_f32_16x16x32_f16(al, vhB, a0B[c], 0, 0, 0);
            }
        }
        __builtin_amdgcn_s_setprio(0);

        // v = 0.5*np - dot  (affine in d2 with row-constant offset nI: same ranking)
        float dAv[8], dBv[8];
#pragma unroll
        for (int c = 0; c < 2; ++c) {
            const float4 np4 = *reinterpret_cast<const float4*>(&nPl[it * 32 + c * 16 + lo4]);
            const float npv[4] = {np4.x, np4.y, np4.z, np4.w};
#pragma unroll
            for (int j = 0; j < 4; ++j) {
                dAv[c * 4 + j] = npv[j] - (a0A[c][j] + a1A[c][j]);
                dBv[c * 4 + j] = npv[j] - (a0B[c][j] + a1B[c][j]);
            }
        }
        const float mnA = fminf(fminf(fminf(dAv[0], dAv[1]), fminf(dAv[2], dAv[3])),
                                fminf(fminf(dAv[4], dAv[5]), fminf(dAv[6], dAv[7])));
        const float mnB = fminf(fminf(fminf(dBv[0], dBv[1]), fminf(dBv[2], dBv[3])),
                                fminf(fminf(dBv[4], dBv[5]), fminf(dBv[6], dBv[7])));
        const int ib = colbase + it * 32 + lo4;
        if (__any(mnA < gateA)) {
#pragma unroll
            for (int q = 0; q < 8; ++q) {
                const int cb = ib + (q >> 2) * 16 + (q & 3);
                TOPK_FAST(bvA, biA, worstA, gateA, tauA, dAv[q], cb);
            }
        }
        if (__any(mnB < gateB)) {
#pragma unroll
            for (int q = 0; q < 8; ++q) {
                const int cb = ib + (q >> 2) * 16 + (q & 3);
                TOPK_FAST(bvB, biB, worstB, gateB, tauB, dBv[q], cb);
            }
        }

        {
            float w1 = fminf(worstA, __shfl_xor(worstA, 16));
            tauA = fminf(w1, __shfl_xor(w1, 32));
            gateA = fminf(tauA, worstA);
            float w2 = fminf(worstB, __shfl_xor(worstB, 16));
            tauB = fminf(w2, __shfl_xor(w2, 32));
            gateB = fminf(tauB, worstB);
        }

        // reads of Abuf[it&1] retired (MFMA data-deps); next iter may overwrite
        __builtin_amdgcn_s_barrier();
    }

    // merge scratch aliased onto Abuf (staging dead now)
    float* mVal = (float*)&Abuf[0][0];
    int*   mIdx = (int*)&Abuf[0][8192];

#define DUMP_AND_MERGE(BV, BI, ROWOFF)                                          \
    {                                                                           \
        __syncthreads();                                                        \
        _Pragma("unroll")                                                       \
        for (int j = 0; j < 8; ++j) { mVal[t * 8 + j] = BV[j]; mIdx[t * 8 + j] = BI[j]; } \
        __syncthreads();                                                        \
        if (t < 64) {                                                           \
            float sv[8]; int si[8];                                             \
            _Pragma("unroll")                                                   \
            for (int j = 0; j < 8; ++j) { sv[j] = 3.4e38f; si[j] = -1; }        \
            float wv = 3.4e38f; int wp = 0;                                     \
            for (int g = 0; g < 4; ++g) {                                       \
                const int fl = ((t >> 4) << 6) + (t & 15) + 16 * g;             \
                _Pragma("unroll")                                               \
                for (int j = 0; j < 8; ++j) {                                   \
                    const float v = mVal[fl * 8 + j];                           \
                    TOPK_UPDATE(sv, si, wv, wp, v, mIdx[fl * 8 + j]);           \
                }                                                               \
            }                                                                   \
            for (int a = 1; a < 8; ++a) {                                       \
                float v = sv[a]; int ii = si[a]; int b2 = a - 1;                \
                while (b2 >= 0 && sv[b2] > v) { sv[b2+1] = sv[b2]; si[b2+1] = si[b2]; --b2; } \
                sv[b2+1] = v; si[b2+1] = ii;                                    \
            }                                                                   \
            const int row = rt * 128 + (ROWOFF) + t;                            \
            _Pragma("unroll")                                                   \
            for (int j = 0; j < 8; ++j) {                                       \
                candV[row * ncand + cs * 8 + j] = sv[j];                        \
                candI[row * ncand + cs * 8 + j] = si[j];                        \
            }                                                                   \
        }                                                                       \
    }

    DUMP_AND_MERGE(bvA, biA, 0)
    DUMP_AND_MERGE(bvB, biB, 64)
#undef DUMP_AND_MERGE
}

// ---------------------------------------------------------------------------
// MLP layer 1 (CIN=256 chunked 2x128, COUT=128, pixel-layout, no BN).
// ---------------------------------------------------------------------------
__global__ __launch_bounds__(256)
void gemm1_kernel(const float* __restrict__ Xp, const float* __restrict__ Xi,
                  const float* __restrict__ W, const float* __restrict__ bias,
                  float* __restrict__ outP, float* __restrict__ outI) {
    __shared__ __align__(16) float Wl[128][132];
    const int t = threadIdx.x;
    const bool isP = blockIdx.x < 256;
    const float* X = isP ? Xp : Xi;
    const int rows = isP ? 16384 : 4096;
    const int blk  = isP ? blockIdx.x : blockIdx.x - 256;
    float* outT = isP ? outP : outI;

    const int r   = blk * 64 + (t & 63);
    const int chb = (t >> 6) * 32;

    float acc[32];
#pragma unroll
    for (int q = 0; q < 32; ++q) acc[q] = 0.0f;

    for (int half = 0; half < 2; ++half) {
        __syncthreads();
        for (int i = t; i < 128 * 128; i += 256) {
            int k = i >> 7, c = i & 127;
            Wl[c][k] = W[k * 256 + half * 128 + c];
        }
        __syncthreads();
#pragma unroll 2
        for (int c = 0; c < 128; ++c) {
            const int cg = half * 128 + c;
            const float x = X[(r >> 12) * (CDIM * 4096) + cg * 4096 + (r & 4095)];
#pragma unroll
            for (int q = 0; q < 8; ++q) {
                const float4 wv = *reinterpret_cast<const float4*>(&Wl[c][chb + 4 * q]);
                acc[4 * q + 0] = fmaf(x, wv.x, acc[4 * q + 0]);
                acc[4 * q + 1] = fmaf(x, wv.y, acc[4 * q + 1]);
                acc[4 * q + 2] = fmaf(x, wv.z, acc[4 * q + 2]);
                acc[4 * q + 3] = fmaf(x, wv.w, acc[4 * q + 3]);
            }
        }
    }
#pragma unroll
    for (int q = 0; q < 32; ++q) {
        const int k = chb + q;
        outT[k * rows + r] = acc[q] + bias[k];
    }
}

// ---------------------------------------------------------------------------
// MLP layer 2 (CIN=128, COUT=64, BN+ReLU on input).
// ---------------------------------------------------------------------------
__global__ __launch_bounds__(256)
void gemm2_kernel(const float* __restrict__ Hp, const float* __restrict__ Hi,
                  const float* __restrict__ W, const float* __restrict__ bias,
                  const float* __restrict__ statsP, const float* __restrict__ statsI,
                  const float* __restrict__ g, const float* __restrict__ be,
                  float* __restrict__ outP, float* __restrict__ outI) {
    __shared__ __align__(16) float Wl[128][68];
    __shared__ float scL[128], shL[128];
    const int t = threadIdx.x;
    const bool isP = blockIdx.x < 256;
    const float* X = isP ? Hp : Hi;
    const float* stats = isP ? statsP : statsI;
    const float invDenom = isP ? (1.0f / 16384.0f) : (1.0f / 4096.0f);
    const int rows = isP ? 16384 : 4096;
    const int blk  = isP ? blockIdx.x : blockIdx.x - 256;
    float* outT = isP ? outP : outI;

    for (int i = t; i < 128 * 64; i += 256) {
        int k = i >> 7, c = i & 127;
        Wl[c][k] = W[k * 128 + c];
    }
    if (t < 128) {
        float mean = stats[t] * invDenom;
        float var  = stats[128 + t] * invDenom - mean * mean;
        float sc   = rsqrtf(var + 1e-5f) * g[t];
        scL[t] = sc;
        shL[t] = be[t] - mean * sc;
    }
    __syncthreads();

    const int r   = blk * 64 + (t & 63);
    const int chb = (t >> 6) * 16;

    float acc[16];
#pragma unroll
    for (int q = 0; q < 16; ++q) acc[q] = 0.0f;

#pragma unroll 2
    for (int c = 0; c < 128; ++c) {
        float x = X[c * rows + r];
        x = fmaxf(fmaf(x, scL[c], shL[c]), 0.0f);
#pragma unroll
        for (int q = 0; q < 4; ++q) {
            const float4 wv = *reinterpret_cast<const float4*>(&Wl[c][chb + 4 * q]);
            acc[4 * q + 0] = fmaf(x, wv.x, acc[4 * q + 0]);
            acc[4 * q + 1] = fmaf(x, wv.y, acc[4 * q + 1]);
            acc[4 * q + 2] = fmaf(x, wv.z, acc[4 * q + 2]);
            acc[4 * q + 3] = fmaf(x, wv.w, acc[4 * q + 3]);
        }
    }
#pragma unroll
    for (int q = 0; q < 16; ++q) {
        const int k = chb + q;
        outT[k * rows + r] = acc[q] + bias[k];
    }
}

// ---------------------------------------------------------------------------
// Column stats for peers+input in one launch. Grid = 2*C.
// ---------------------------------------------------------------------------
__global__ __launch_bounds__(256)
void colstats2x_kernel(const float* __restrict__ Hp, const float* __restrict__ Hi,
                       int C, float* __restrict__ statsP, float* __restrict__ statsI) {
    __shared__ float rs[256], rq[256];
    const bool isP = blockIdx.x < (unsigned)C;
    const int c = isP ? blockIdx.x : blockIdx.x - C;
    const float* H = isP ? Hp : Hi;
    const int rows = isP ? 16384 : 4096;
    float* stats = isP ? statsP : statsI;
    const int t = threadIdx.x;
    float s = 0.0f, q = 0.0f;
    for (int r = t; r < rows; r += 256) {
        float v = H[c * rows + r];
        s += v;
        q = fmaf(v, v, q);
    }
    rs[t] = s; rq[t] = q;
    __syncthreads();
    for (int st = 128; st > 0; st >>= 1) {
        if (t < st) { rs[t] += rs[t + st]; rq[t] += rq[t + st]; }
        __syncthreads();
    }
    if (t == 0) { stats[c] = rs[0]; stats[C + c] = rq[0]; }
}

// ---------------------------------------------------------------------------
// a-scores for peers+input in one launch. Grid = 80.
// ---------------------------------------------------------------------------
__global__ __launch_bounds__(256)
void a2x_kernel(const float* __restrict__ Hp, const float* __restrict__ Hi,
                const float* __restrict__ statsP, const float* __restrict__ statsI,
                const float* __restrict__ g, const float* __restrict__ be,
                const float* __restrict__ cwP, const float* __restrict__ cbP,
                const float* __restrict__ cwI, const float* __restrict__ cbI,
                float* __restrict__ aP, float* __restrict__ aI) {
    __shared__ float scL[64], shL[64], cwL[64];
    const bool isP = blockIdx.x < 64;
    const float* H = isP ? Hp : Hi;
    const float* stats = isP ? statsP : statsI;
    const float* cw = isP ? cwP : cwI;
    const float* cb = isP ? cbP : cbI;
    float* aout = isP ? aP : aI;
    const int rows = isP ? 16384 : 4096;
    const float invDenom = isP ? (1.0f / 16384.0f) : (1.0f / 4096.0f);
    const int blk = isP ? blockIdx.x : blockIdx.x - 64;
    const int t = threadIdx.x;
    if (t < 64) {
        float mean = stats[t] * invDenom;
        float var  = stats[64 + t] * invDenom - mean * mean;
        float sc   = rsqrtf(var + 1e-5f) * g[t];
        scL[t] = sc;
        shL[t] = be[t] - mean * sc;
        cwL[t] = cw[t];
    }
    __syncthreads();
    const int row = blk * 256 + t;
    if (row < rows) {
        float a = 0.0f;
        for (int c = 0; c < 64; ++c) {
            float v = H[c * rows + row];
            a += fmaxf(fmaf(v, scL[c], shL[c]), 0.0f) * cwL[c];
        }
        aout[row] = a + cb[0];
    }
}

// ---------------------------------------------------------------------------
// Final: merge ncand candidates/row, softplus->softmax over kNN, gather style.
// candV is monotone in dist (v-domain) -> identical ranking/kth/tie logic.
// ---------------------------------------------------------------------------
__global__ __launch_bounds__(256)
void out_kernel(const float* __restrict__ candV, const int* __restrict__ candI,
                const float* __restrict__ a1, const float* __restrict__ a2,
                const float* __restrict__ PS, float* __restrict__ dout, int ncand) {
    __shared__ float wL[64][8];
    __shared__ int   aL[64][8];
    const int t  = threadIdx.x;
    const int nb = blockIdx.x * 64;

    if (t < 64) {
        const int row = nb + t;
        float sv[8]; int si[8];
#pragma unroll
        for (int j = 0; j < 8; ++j) { sv[j] = 3.4e38f; si[j] = 0; }
        float w2 = 3.4e38f; int wp = 0;
        for (int k = 0; k < ncand; ++k) {
            const float v = candV[row * ncand + k];
            TOPK_UPDATE(sv, si, w2, wp, v, candI[row * ncand + k]);
        }
        for (int a = 1; a < 8; ++a) {
            float v = sv[a]; int ii = si[a]; int b = a - 1;
            while (b >= 0 && sv[b] > v) { sv[b + 1] = sv[b]; si[b + 1] = si[b]; --b; }
            sv[b + 1] = v; si[b + 1] = ii;
        }
        const float kth = sv[4];
        int cnt = 5;
        while (cnt < 8 && sv[cnt] <= kth) ++cnt;

        const float arow = a1[row];
        float s[8], e[8];
        float mx = -1e30f;
#pragma unroll
        for (int j = 0; j < 8; ++j) s[j] = 0.0f;
        for (int j = 0; j < cnt; ++j) {
            s[j] = softplusf(arow + a2[si[j]]);
            mx = fmaxf(mx, s[j]);
        }
        float Z = 0.0f;
        for (int j = 0; j < 8; ++j) {
            e[j] = (j < cnt) ? expf(s[j] - mx) : 0.0f;
            Z += e[j];
        }
        for (int j = 0; j < 8; ++j) {
            const int ix = (j < cnt) ? si[j] : si[0];
            wL[t][j] = e[j] / Z;
            aL[t][j] = (ix >> 12) * (CDIM * 4096) + (ix & 4095);
        }
    }
    __syncthreads();

    const int rl  = t & 63;
    const int grp = t >> 6;
    float w[8]; int ab[8];
#pragma unroll
    for (int j = 0; j < 8; ++j) { w[j] = wL[rl][j]; ab[j] = aL[rl][j]; }
    const int n = nb + rl;
    for (int c = grp * 64; c < grp * 64 + 64; ++c) {
        float acc = 0.0f;
#pragma unroll
        for (int j = 0; j < 8; ++j) acc += w[j] * PS[ab[j] + c * 4096];
        dout[(CDIM + c) * 4096 + n] = acc;
    }
}

// ---------------------------------------------------------------------------
extern "C" void kernel_launch(void* const* d_in, const int* in_sizes, int n_in,
                              void* d_out, int out_size, void* d_ws, size_t ws_size,
                              hipStream_t stream) {
    const float* inp_cont    = (const float*)d_in[0];
    const float* peers_cont  = (const float*)d_in[2];
    const float* peers_style = (const float*)d_in[3];
    const float* W1  = (const float*)d_in[4];
    const float* b1  = (const float*)d_in[5];
    const float* g1  = (const float*)d_in[6];
    const float* be1 = (const float*)d_in[7];
    const float* W2  = (const float*)d_in[8];
    const float* b2  = (const float*)d_in[9];
    const float* g2  = (const float*)d_in[10];
    const float* be2 = (const float*)d_in[11];
    const float* cw1 = (const float*)d_in[12];
    const float* cb1 = (const float*)d_in[13];
    const float* cw2 = (const float*)d_in[14];
    const float* cb2 = (const float*)d_in[15];
    float* out = (float*)d_out;
    char*  wsb = (char*)d_ws;

    int nsplit;
    if      (ws_size >= (size_t)25400000) nsplit = 16;
    else if (ws_size >= (size_t)23300000) nsplit = 8;
    else return;
    const int ncand = nsplit * 8;
    const size_t candBytes = (size_t)NROWS * ncand * 4;

    // workspace layout (bytes)
    uint4* xpBhi = (uint4*)(wsb + 0);                    //  8 MB
    uint4* xpBlo = (uint4*)(wsb + 8388608);              //  8 MB
    uint4* xiBhi = (uint4*)(wsb + 16777216);             //  2 MB
    uint4* xiBlo = (uint4*)(wsb + 18874368);             //  2 MB
    float* normP = (float*)(wsb + 20971520);             //  64 KB
    float* normI = (float*)(wsb + 21037056);             //  16 KB
    float* candV = (float*)(wsb + 21053440);             //  candBytes
    int*   candI = (int*)  (wsb + 21053440 + candBytes); //  candBytes
    char*  tail  = wsb + 21053440 + 2 * candBytes;
    float* a2    = (float*)(tail);                       //  64 KB
    float* a1    = (float*)(tail + 65536);               //  16 KB
    float* s1p   = (float*)(tail + 81920);               //  1 KB
    float* s1i   = (float*)(tail + 82944);               //  1 KB
    float* s2p   = (float*)(tail + 83968);               //  512
    float* s2i   = (float*)(tail + 84480);               //  512
    // Aliased AFTER dist kernel completes:
    float* H1Tp  = (float*)(wsb + 0);                    // 8 MB
    float* H2Tp  = (float*)(wsb + 8388608);              // 4 MB
    float* H1Ti  = (float*)(wsb + 16777216);             // 2 MB
    float* H2Ti  = (float*)(wsb + 18874368);             // 1 MB

    copy_kernel<<<1024, 256, 0, stream>>>((const float4*)inp_cont, (float4*)out, 262144);
    norms_kernel<<<320, 256, 0, stream>>>(inp_cont, peers_cont, normI, normP);
    convert_kernel<<<256, 256, 0, stream>>>(inp_cont, xiBhi, xiBlo, 4096);
    convert_kernel<<<1024, 256, 0, stream>>>(peers_cont, xpBhi, xpBlo, 16384);

    dist_topk_mfma<<<32 * nsplit, 256, 0, stream>>>(xpBhi, xpBlo, xiBhi, xiBlo,
                                                    normI, normP, candV, candI, nsplit);

    gemm1_kernel<<<320, 256, 0, stream>>>(peers_cont, inp_cont, W1, b1, H1Tp, H1Ti);
    colstats2x_kernel<<<256, 256, 0, stream>>>(H1Tp, H1Ti, 128, s1p, s1i);
    gemm2_kernel<<<320, 256, 0, stream>>>(H1Tp, H1Ti, W2, b2, s1p, s1i, g1, be1, H2Tp, H2Ti);
    colstats2x_kernel<<<128, 256, 0, stream>>>(H2Tp, H2Ti, 64, s2p, s2i);
    a2x_kernel<<<80, 256, 0, stream>>>(H2Tp, H2Ti, s2p, s2i, g2, be2,
                                       cw2, cb2, cw1, cb1, a2, a1);

    out_kernel<<<64, 256, 0, stream>>>(candV, candI, a1, a2, peers_style, out, ncand);
}

// Round 14
// 376.597 us; speedup vs baseline: 3.1775x; 1.1967x over previous
//
#include <hip/hip_runtime.h>
#include <math.h>

#define NROWS 4096
#define MCOLS 16384
#define CDIM  256

typedef _Float16 half8 __attribute__((ext_vector_type(8)));
typedef float f32x4 __attribute__((ext_vector_type(4)));

static __device__ __forceinline__ float softplusf(float x) {
    return fmaxf(x, 0.0f) + log1pf(expf(-fabsf(x)));
}

// Classic top-8 update (merge phases only)
#define TOPK_UPDATE(BV, BI, WORST, WP, V, IDX)                                 \
    if ((V) < (WORST)) {                                                       \
        BV[WP] = (V); BI[WP] = (IDX);                                          \
        WORST = BV[0]; WP = 0;                                                 \
        _Pragma("unroll")                                                      \
        for (int _q = 1; _q < 8; ++_q)                                         \
            if (BV[_q] > WORST) { WORST = BV[_q]; WP = _q; }                   \
    }

// Hot-loop top-8: slot index in 3 LSBs; worst via max-tree; gate = min(tau, worst).
#define TOPK_FAST(BV, BI, WORST, GATE, TAU, V, IDX)                            \
    if ((V) < (GATE)) {                                                        \
        const int _wp = __float_as_int(WORST) & 7;                             \
        BV[_wp] = __uint_as_float((__float_as_uint(V) & ~7u) | (unsigned)_wp); \
        BI[_wp] = (IDX);                                                       \
        const float _m0 = fmaxf(fmaxf(BV[0], BV[1]), fmaxf(BV[2], BV[3]));     \
        const float _m1 = fmaxf(fmaxf(BV[4], BV[5]), fmaxf(BV[6], BV[7]));     \
        WORST = fmaxf(_m0, _m1);                                               \
        GATE = fminf(TAU, WORST);                                              \
    }

// ---------------------------------------------------------------------------
// Passthrough copy
// ---------------------------------------------------------------------------
__global__ __launch_bounds__(256)
void copy_kernel(const float4* __restrict__ src, float4* __restrict__ dst, int n4) {
    int i = blockIdx.x * blockDim.x + threadIdx.x;
    if (i < n4) dst[i] = src[i];
}

// ---------------------------------------------------------------------------
// Column norms, fp32 tree (4 threads/column x 64 channels + shfl combine).
// ---------------------------------------------------------------------------
__global__ __launch_bounds__(256)
void norms_kernel(const float* __restrict__ xiT, const float* __restrict__ xpT,
                  float* __restrict__ normI, float* __restrict__ normP) {
    const int t = threadIdx.x;
    const int col = blockIdx.x * 64 + (t >> 2);
    const int sub = t & 3;
    const float* p;
    int base;
    if (col < MCOLS) { p = xpT; base = (col >> 12) * (CDIM * 4096) + (col & 4095); }
    else             { p = xiT; base = col - MCOLS; }
    float s = 0.0f;
#pragma unroll 8
    for (int k = 0; k < 64; ++k) {
        const float v = p[base + (sub * 64 + k) * 4096];
        s = fmaf(v, v, s);
    }
    s += __shfl_xor(s, 1);
    s += __shfl_xor(s, 2);
    if (sub == 0) {
        if (col < MCOLS) normP[col] = s;
        else             normI[col - MCOLS] = s;
    }
}

// ---------------------------------------------------------------------------
// fp32 [K=256][cols] -> fragment-ready fp16 hi/lo.
// ---------------------------------------------------------------------------
__global__ __launch_bounds__(256)
void convert_kernel(const float* __restrict__ src, uint4* __restrict__ dhi,
                    uint4* __restrict__ dlo, int ncols) {
    __shared__ float S[64][65];
    const int t = threadIdx.x;
    const int tilesPerRow = ncols >> 6;
    const int colbase = (blockIdx.x % tilesPerRow) << 6;
    const int ktbase  = (blockIdx.x / tilesPerRow) << 6;
    const int b = colbase >> 12;
    const int pixbase = colbase & 4095;
    const float* sp = src + (size_t)b * (CDIM * 4096) + (size_t)ktbase * 4096 + pixbase;

    for (int i = t; i < 4096; i += 256) {
        int kk = i >> 6, cc = i & 63;
        S[kk][cc] = sp[kk * 4096 + cc];
    }
    __syncthreads();

    const int l = t & 63;
#pragma unroll
    for (int s = 0; s < 2; ++s) {
        const int pid  = (t >> 6) + 4 * s;
        const int ct_l = pid & 3;
        const int kt_l = pid >> 2;
        const int c_l  = ct_l * 16 + (l & 15);
        const int k_l  = kt_l * 32 + ((l >> 4) << 3);
        half8 h, lo;
#pragma unroll
        for (int j = 0; j < 8; ++j) {
            float v = S[k_l + j][c_l];
            _Float16 hv = (_Float16)v;
            h[j]  = hv;
            lo[j] = (_Float16)(v - (float)hv);
        }
        const int ct_g = (colbase >> 4) + ct_l;
        const int kt_g = (ktbase >> 5) + kt_l;
        const size_t off = (size_t)(ct_g * 8 + kt_g) * 64 + l;
        dhi[off] = *reinterpret_cast<uint4*>(&h);
        dlo[off] = *reinterpret_cast<uint4*>(&lo);
    }
}

// ---------------------------------------------------------------------------
// MFMA distance + per-row top-8.  ONE rowgroup (16 rows) per wave so the xi
// fragment set (16 uint4 = 64 regs) FITS in arch VGPRs (no AGPR parking).
// Grid: 64 rowtiles (64 rows) * nsplit; 256 threads = 4 waves.
// Counted-vmcnt pipeline; v = 0.5*normP - dot selection domain; XCD cs map.
// ---------------------------------------------------------------------------
__global__ __launch_bounds__(256, 2)
void dist_topk_mfma(const uint4* __restrict__ xpBhi, const uint4* __restrict__ xpBlo,
                    const uint4* __restrict__ xiBhi, const uint4* __restrict__ xiBlo,
                    const float* __restrict__ normP,
                    float* __restrict__ candV, int* __restrict__ candI,
                    int nsplit) {
    __shared__ __align__(16) char Abuf[2][32768];
    __shared__ __align__(16) float nPl[2048];   // 0.5 * normP

    const int t = threadIdx.x;
    const int w = t >> 6;
    const int l = t & 63;
    int rt, cs;
    if (nsplit == 16) { cs = ((blockIdx.x & 7) << 1) | ((blockIdx.x >> 3) & 1); rt = blockIdx.x >> 4; }
    else              { cs = blockIdx.x & 7;                                    rt = blockIdx.x >> 3; }
    const int niter = (MCOLS / 32) / nsplit;
    const int span  = MCOLS / nsplit;
    const int colbase = cs * span;
    const int ncand = nsplit * 8;

    for (int i = t; i < span; i += 256) nPl[i] = 0.5f * normP[colbase + i];

    // ONE xi rowgroup per wave: ct = rt*4 + w  (16 rows)
    uint4 bh[8], bl[8];
    const int ct = rt * 4 + w;
#pragma unroll
    for (int kt = 0; kt < 8; ++kt) {
        bh[kt] = xiBhi[(size_t)(ct * 8 + kt) * 64 + l];
        bl[kt] = xiBlo[(size_t)(ct * 8 + kt) * 64 + l];
    }

    float bv[8]; int bi[8];
#pragma unroll
    for (int j = 0; j < 8; ++j) {
        bv[j] = __uint_as_float((0x7f7ffff8u) | (unsigned)j);
        bi[j] = -1;
    }
    float worst = bv[7], tau = bv[7], gate = bv[7];

    const char* gb = (w >= 2) ? (const char*)xpBlo : (const char*)xpBhi;
    const char* srcBase = gb + (size_t)(cs * niter * 2 + (w & 1)) * 8192 + l * 16;
    char* dbBase = &Abuf[0][(w >> 1) * 16384 + (w & 1) * 8192];

    auto stage = [&](int it, int buf) {
        const char* src = srcBase + (size_t)it * 16384;
        char* db = dbBase + buf * 32768;
#pragma unroll
        for (int kt = 0; kt < 8; ++kt)
            __builtin_amdgcn_global_load_lds(
                (const __attribute__((address_space(1))) void*)(src + kt * 1024),
                (__attribute__((address_space(3))) void*)(db + kt * 1024),
                16, 0, 0);
    };

    stage(0, 0);
    asm volatile("s_waitcnt vmcnt(0)" ::: "memory");
    __builtin_amdgcn_s_barrier();

    for (int it = 0; it < niter; ++it) {
        if (it < niter - 1) {
            stage(it + 1, (it + 1) & 1);
            asm volatile("s_waitcnt vmcnt(8)" ::: "memory");
        } else {
            asm volatile("s_waitcnt vmcnt(0)" ::: "memory");
        }
        __builtin_amdgcn_s_barrier();
        __builtin_amdgcn_sched_barrier(0);

        const char* Ab = Abuf[it & 1];
        const int lo4 = (l >> 4) << 2;

        f32x4 a0[2], a1[2];
#pragma unroll
        for (int c = 0; c < 2; ++c) {
            a0[c] = f32x4{0.f,0.f,0.f,0.f};
            a1[c] = f32x4{0.f,0.f,0.f,0.f};
        }
        __builtin_amdgcn_s_setprio(1);
#pragma unroll
        for (int kt = 0; kt < 8; ++kt) {
            const half8 vh = *reinterpret_cast<const half8*>(&bh[kt]);
            const half8 vl = *reinterpret_cast<const half8*>(&bl[kt]);
#pragma unroll
            for (int c = 0; c < 2; ++c) {
                const half8 ah = *reinterpret_cast<const half8*>(Ab + c * 8192 + kt * 1024 + l * 16);
                const half8 al = *reinterpret_cast<const half8*>(Ab + 16384 + c * 8192 + kt * 1024 + l * 16);
                a0[c] = __builtin_amdgcn_mfma_f32_16x16x32_f16(ah, vh, a0[c], 0, 0, 0);
                a1[c] = __builtin_amdgcn_mfma_f32_16x16x32_f16(ah, vl, a1[c], 0, 0, 0);
                a0[c] = __builtin_amdgcn_mfma_f32_16x16x32_f16(al, vh, a0[c], 0, 0, 0);
            }
        }
        __builtin_amdgcn_s_setprio(0);

        float dv[8];
#pragma unroll
        for (int c = 0; c < 2; ++c) {
            const float4 np4 = *reinterpret_cast<const float4*>(&nPl[it * 32 + c * 16 + lo4]);
            const float npv[4] = {np4.x, np4.y, np4.z, np4.w};
#pragma unroll
            for (int j = 0; j < 4; ++j)
                dv[c * 4 + j] = npv[j] - (a0[c][j] + a1[c][j]);
        }
        const float mn = fminf(fminf(fminf(dv[0], dv[1]), fminf(dv[2], dv[3])),
                               fminf(fminf(dv[4], dv[5]), fminf(dv[6], dv[7])));
        const int ib = colbase + it * 32 + lo4;
        if (__any(mn < gate)) {
#pragma unroll
            for (int q = 0; q < 8; ++q) {
                const int cb = ib + (q >> 2) * 16 + (q & 3);
                TOPK_FAST(bv, bi, worst, gate, tau, dv[q], cb);
            }
        }

        {
            float w1 = fminf(worst, __shfl_xor(worst, 16));
            tau = fminf(w1, __shfl_xor(w1, 32));
            gate = fminf(tau, worst);
        }

        __builtin_amdgcn_s_barrier();
    }

    // merge scratch aliased onto Abuf
    float* mVal = (float*)&Abuf[0][0];
    int*   mIdx = (int*)&Abuf[0][8192];

    __syncthreads();
#pragma unroll
    for (int j = 0; j < 8; ++j) { mVal[t * 8 + j] = bv[j]; mIdx[t * 8 + j] = bi[j]; }
    __syncthreads();
    if (t < 64) {
        float sv[8]; int si[8];
#pragma unroll
        for (int j = 0; j < 8; ++j) { sv[j] = 3.4e38f; si[j] = -1; }
        float wv = 3.4e38f; int wp = 0;
        for (int g = 0; g < 4; ++g) {
            const int fl = ((t >> 4) << 6) + (t & 15) + 16 * g;
#pragma unroll
            for (int j = 0; j < 8; ++j) {
                const float v = mVal[fl * 8 + j];
                TOPK_UPDATE(sv, si, wv, wp, v, mIdx[fl * 8 + j]);
            }
        }
        for (int a = 1; a < 8; ++a) {
            float v = sv[a]; int ii = si[a]; int b2 = a - 1;
            while (b2 >= 0 && sv[b2] > v) { sv[b2+1] = sv[b2]; si[b2+1] = si[b2]; --b2; }
            sv[b2+1] = v; si[b2+1] = ii;
        }
        const int row = rt * 64 + t;
#pragma unroll
        for (int j = 0; j < 8; ++j) {
            candV[row * ncand + cs * 8 + j] = sv[j];
            candI[row * ncand + cs * 8 + j] = si[j];
        }
    }
}

// ---------------------------------------------------------------------------
// MLP layer 1: CIN=256 (2x128 chunks), 64 outputs per block (4 blocks/CU).
// Grid 640: 0..511 peers (256 rowblocks x 2 cout-halves), 512..639 input.
// ---------------------------------------------------------------------------
__global__ __launch_bounds__(256)
void gemm1_kernel(const float* __restrict__ Xp, const float* __restrict__ Xi,
                  const float* __restrict__ W, const float* __restrict__ bias,
                  float* __restrict__ outP, float* __restrict__ outI) {
    __shared__ __align__(16) float Wl[128][68];
    const int t = threadIdx.x;
    const bool isP = blockIdx.x < 512;
    const int bid  = isP ? blockIdx.x : blockIdx.x - 512;
    const float* X = isP ? Xp : Xi;
    const int rows = isP ? 16384 : 4096;
    float* outT = isP ? outP : outI;
    const int rowblk = bid >> 1;
    const int ch     = bid & 1;          // cout half: outputs ch*64 .. +64

    const int r   = rowblk * 64 + (t & 63);
    const int kgb = (t >> 6) * 16;

    float acc[16];
#pragma unroll
    for (int q = 0; q < 16; ++q) acc[q] = 0.0f;

    for (int half = 0; half < 2; ++half) {
        __syncthreads();
        for (int i = t; i < 128 * 64; i += 256) {
            int k = i >> 7, c = i & 127;
            Wl[c][k] = W[(ch * 64 + k) * 256 + half * 128 + c];
        }
        __syncthreads();
#pragma unroll 2
        for (int c = 0; c < 128; ++c) {
            const int cg = half * 128 + c;
            const float x = X[(r >> 12) * (CDIM * 4096) + cg * 4096 + (r & 4095)];
#pragma unroll
            for (int q = 0; q < 4; ++q) {
                const float4 wv = *reinterpret_cast<const float4*>(&Wl[c][kgb + 4 * q]);
                acc[4 * q + 0] = fmaf(x, wv.x, acc[4 * q + 0]);
                acc[4 * q + 1] = fmaf(x, wv.y, acc[4 * q + 1]);
                acc[4 * q + 2] = fmaf(x, wv.z, acc[4 * q + 2]);
                acc[4 * q + 3] = fmaf(x, wv.w, acc[4 * q + 3]);
            }
        }
    }
#pragma unroll
    for (int q = 0; q < 16; ++q) {
        const int k = ch * 64 + kgb + q;
        outT[k * rows + r] = acc[q] + bias[k];
    }
}

// ---------------------------------------------------------------------------
// MLP layer 2 (CIN=128, COUT=64, BN+ReLU on input). Grid 320.
// ---------------------------------------------------------------------------
__global__ __launch_bounds__(256)
void gemm2_kernel(const float* __restrict__ Hp, const float* __restrict__ Hi,
                  const float* __restrict__ W, const float* __restrict__ bias,
                  const float* __restrict__ statsP, const float* __restrict__ statsI,
                  const float* __restrict__ g, const float* __restrict__ be,
                  float* __restrict__ outP, float* __restrict__ outI) {
    __shared__ __align__(16) float Wl[128][68];
    __shared__ float scL[128], shL[128];
    const int t = threadIdx.x;
    const bool isP = blockIdx.x < 256;
    const float* X = isP ? Hp : Hi;
    const float* stats = isP ? statsP : statsI;
    const float invDenom = isP ? (1.0f / 16384.0f) : (1.0f / 4096.0f);
    const int rows = isP ? 16384 : 4096;
    const int blk  = isP ? blockIdx.x : blockIdx.x - 256;
    float* outT = isP ? outP : outI;

    for (int i = t; i < 128 * 64; i += 256) {
        int k = i >> 7, c = i & 127;
        Wl[c][k] = W[k * 128 + c];
    }
    if (t < 128) {
        float mean = stats[t] * invDenom;
        float var  = stats[128 + t] * invDenom - mean * mean;
        float sc   = rsqrtf(var + 1e-5f) * g[t];
        scL[t] = sc;
        shL[t] = be[t] - mean * sc;
    }
    __syncthreads();

    const int r   = blk * 64 + (t & 63);
    const int chb = (t >> 6) * 16;

    float acc[16];
#pragma unroll
    for (int q = 0; q < 16; ++q) acc[q] = 0.0f;

#pragma unroll 2
    for (int c = 0; c < 128; ++c) {
        float x = X[c * rows + r];
        x = fmaxf(fmaf(x, scL[c], shL[c]), 0.0f);
#pragma unroll
        for (int q = 0; q < 4; ++q) {
            const float4 wv = *reinterpret_cast<const float4*>(&Wl[c][chb + 4 * q]);
            acc[4 * q + 0] = fmaf(x, wv.x, acc[4 * q + 0]);
            acc[4 * q + 1] = fmaf(x, wv.y, acc[4 * q + 1]);
            acc[4 * q + 2] = fmaf(x, wv.z, acc[4 * q + 2]);
            acc[4 * q + 3] = fmaf(x, wv.w, acc[4 * q + 3]);
        }
    }
#pragma unroll
    for (int q = 0; q < 16; ++q) {
        const int k = chb + q;
        outT[k * rows + r] = acc[q] + bias[k];
    }
}

// ---------------------------------------------------------------------------
// Column stats for peers+input in one launch. Grid = 2*C.
// ---------------------------------------------------------------------------
__global__ __launch_bounds__(256)
void colstats2x_kernel(const float* __restrict__ Hp, const float* __restrict__ Hi,
                       int C, float* __restrict__ statsP, float* __restrict__ statsI) {
    __shared__ float rs[256], rq[256];
    const bool isP = blockIdx.x < (unsigned)C;
    const int c = isP ? blockIdx.x : blockIdx.x - C;
    const float* H = isP ? Hp : Hi;
    const int rows = isP ? 16384 : 4096;
    float* stats = isP ? statsP : statsI;
    const int t = threadIdx.x;
    float s = 0.0f, q = 0.0f;
    for (int r = t; r < rows; r += 256) {
        float v = H[c * rows + r];
        s += v;
        q = fmaf(v, v, q);
    }
    rs[t] = s; rq[t] = q;
    __syncthreads();
    for (int st = 128; st > 0; st >>= 1) {
        if (t < st) { rs[t] += rs[t + st]; rq[t] += rq[t + st]; }
        __syncthreads();
    }
    if (t == 0) { stats[c] = rs[0]; stats[C + c] = rq[0]; }
}

// ---------------------------------------------------------------------------
// a-scores for peers+input in one launch. Grid = 80.
// ---------------------------------------------------------------------------
__global__ __launch_bounds__(256)
void a2x_kernel(const float* __restrict__ Hp, const float* __restrict__ Hi,
                const float* __restrict__ statsP, const float* __restrict__ statsI,
                const float* __restrict__ g, const float* __restrict__ be,
                const float* __restrict__ cwP, const float* __restrict__ cbP,
                const float* __restrict__ cwI, const float* __restrict__ cbI,
                float* __restrict__ aP, float* __restrict__ aI) {
    __shared__ float scL[64], shL[64], cwL[64];
    const bool isP = blockIdx.x < 64;
    const float* H = isP ? Hp : Hi;
    const float* stats = isP ? statsP : statsI;
    const float* cw = isP ? cwP : cwI;
    const float* cb = isP ? cbP : cbI;
    float* aout = isP ? aP : aI;
    const int rows = isP ? 16384 : 4096;
    const float invDenom = isP ? (1.0f / 16384.0f) : (1.0f / 4096.0f);
    const int blk = isP ? blockIdx.x : blockIdx.x - 64;
    const int t = threadIdx.x;
    if (t < 64) {
        float mean = stats[t] * invDenom;
        float var  = stats[64 + t] * invDenom - mean * mean;
        float sc   = rsqrtf(var + 1e-5f) * g[t];
        scL[t] = sc;
        shL[t] = be[t] - mean * sc;
        cwL[t] = cw[t];
    }
    __syncthreads();
    const int row = blk * 256 + t;
    if (row < rows) {
        float a = 0.0f;
        for (int c = 0; c < 64; ++c) {
            float v = H[c * rows + row];
            a += fmaxf(fmaf(v, scL[c], shL[c]), 0.0f) * cwL[c];
        }
        aout[row] = a + cb[0];
    }
}

// ---------------------------------------------------------------------------
// Merge candidates -> per-row softmax weights + gather base addresses.
// Grid 16 x 256: one thread per row.
// ---------------------------------------------------------------------------
__global__ __launch_bounds__(256)
void merge_kernel(const float* __restrict__ candV, const int* __restrict__ candI,
                  const float* __restrict__ a1, const float* __restrict__ a2,
                  float* __restrict__ w8, int* __restrict__ gidx, int ncand) {
    const int row = blockIdx.x * 256 + threadIdx.x;
    float sv[8]; int si[8];
#pragma unroll
    for (int j = 0; j < 8; ++j) { sv[j] = 3.4e38f; si[j] = 0; }
    float w2 = 3.4e38f; int wp = 0;
    for (int k = 0; k < ncand; ++k) {
        const float v = candV[row * ncand + k];
        TOPK_UPDATE(sv, si, w2, wp, v, candI[row * ncand + k]);
    }
    for (int a = 1; a < 8; ++a) {
        float v = sv[a]; int ii = si[a]; int b = a - 1;
        while (b >= 0 && sv[b] > v) { sv[b + 1] = sv[b]; si[b + 1] = si[b]; --b; }
        sv[b + 1] = v; si[b + 1] = ii;
    }
    const float kth = sv[4];
    int cnt = 5;
    while (cnt < 8 && sv[cnt] <= kth) ++cnt;

    const float arow = a1[row];
    float s[8], e[8];
    float mx = -1e30f;
#pragma unroll
    for (int j = 0; j < 8; ++j) s[j] = 0.0f;
    for (int j = 0; j < cnt; ++j) {
        s[j] = softplusf(arow + a2[si[j]]);
        mx = fmaxf(mx, s[j]);
    }
    float Z = 0.0f;
    for (int j = 0; j < 8; ++j) {
        e[j] = (j < cnt) ? expf(s[j] - mx) : 0.0f;
        Z += e[j];
    }
#pragma unroll
    for (int j = 0; j < 8; ++j) {
        const int ix = (j < cnt) ? si[j] : si[0];
        w8[row * 8 + j]   = e[j] / Z;
        gidx[row * 8 + j] = (ix >> 12) * (CDIM * 4096) + (ix & 4095);
    }
}

// ---------------------------------------------------------------------------
// Gather: out[(256+c)*4096 + n] = sum_j w8[n][j] * PS[gidx[n][j] + c*4096].
// Grid 1024 = 64 rowtiles x 16 channel chunks; thread: 1 row x 4 channels.
// ---------------------------------------------------------------------------
__global__ __launch_bounds__(256)
void gather_kernel(const float* __restrict__ w8, const int* __restrict__ gidx,
                   const float* __restrict__ PS, float* __restrict__ dout) {
    const int t = threadIdx.x;
    const int rtile = blockIdx.x >> 4;
    const int chunk = blockIdx.x & 15;
    const int row = rtile * 64 + (t & 63);
    const int c0  = chunk * 16 + (t >> 6) * 4;

    float w[8]; int ab[8];
#pragma unroll
    for (int j = 0; j < 8; ++j) { w[j] = w8[row * 8 + j]; ab[j] = gidx[row * 8 + j]; }

#pragma unroll
    for (int cc = 0; cc < 4; ++cc) {
        const int c = c0 + cc;
        float acc = 0.0f;
#pragma unroll
        for (int j = 0; j < 8; ++j) acc += w[j] * PS[ab[j] + c * 4096];
        dout[(CDIM + c) * 4096 + row] = acc;
    }
}

// ---------------------------------------------------------------------------
extern "C" void kernel_launch(void* const* d_in, const int* in_sizes, int n_in,
                              void* d_out, int out_size, void* d_ws, size_t ws_size,
                              hipStream_t stream) {
    const float* inp_cont    = (const float*)d_in[0];
    const float* peers_cont  = (const float*)d_in[2];
    const float* peers_style = (const float*)d_in[3];
    const float* W1  = (const float*)d_in[4];
    const float* b1  = (const float*)d_in[5];
    const float* g1  = (const float*)d_in[6];
    const float* be1 = (const float*)d_in[7];
    const float* W2  = (const float*)d_in[8];
    const float* b2  = (const float*)d_in[9];
    const float* g2  = (const float*)d_in[10];
    const float* be2 = (const float*)d_in[11];
    const float* cw1 = (const float*)d_in[12];
    const float* cb1 = (const float*)d_in[13];
    const float* cw2 = (const float*)d_in[14];
    const float* cb2 = (const float*)d_in[15];
    float* out = (float*)d_out;
    char*  wsb = (char*)d_ws;

    int nsplit;
    if      (ws_size >= (size_t)25400000) nsplit = 16;
    else if (ws_size >= (size_t)23300000) nsplit = 8;
    else return;
    const int ncand = nsplit * 8;
    const size_t candBytes = (size_t)NROWS * ncand * 4;

    // workspace layout (bytes)
    uint4* xpBhi = (uint4*)(wsb + 0);                    //  8 MB
    uint4* xpBlo = (uint4*)(wsb + 8388608);              //  8 MB
    uint4* xiBhi = (uint4*)(wsb + 16777216);             //  2 MB
    uint4* xiBlo = (uint4*)(wsb + 18874368);             //  2 MB
    float* normP = (float*)(wsb + 20971520);             //  64 KB
    float* normI = (float*)(wsb + 21037056);             //  16 KB
    float* candV = (float*)(wsb + 21053440);             //  candBytes
    int*   candI = (int*)  (wsb + 21053440 + candBytes); //  candBytes
    char*  tail  = wsb + 21053440 + 2 * candBytes;
    float* a2    = (float*)(tail);                       //  64 KB
    float* a1    = (float*)(tail + 65536);               //  16 KB
    float* s1p   = (float*)(tail + 81920);               //  1 KB
    float* s1i   = (float*)(tail + 82944);               //  1 KB
    float* s2p   = (float*)(tail + 83968);               //  512
    float* s2i   = (float*)(tail + 84480);               //  512
    // Aliased AFTER dist kernel completes:
    float* H1Tp  = (float*)(wsb + 0);                    // 8 MB
    float* H2Tp  = (float*)(wsb + 8388608);              // 4 MB
    float* H1Ti  = (float*)(wsb + 16777216);             // 2 MB
    float* H2Ti  = (float*)(wsb + 18874368);             // 1 MB (ends 19922944)
    float* w8    = (float*)(wsb + 19922944);             // 128 KB (dead xiBlo tail)
    int*   gidx  = (int*)  (wsb + 20054016);             // 128 KB

    copy_kernel<<<1024, 256, 0, stream>>>((const float4*)inp_cont, (float4*)out, 262144);
    norms_kernel<<<320, 256, 0, stream>>>(inp_cont, peers_cont, normI, normP);
    convert_kernel<<<256, 256, 0, stream>>>(inp_cont, xiBhi, xiBlo, 4096);
    convert_kernel<<<1024, 256, 0, stream>>>(peers_cont, xpBhi, xpBlo, 16384);

    dist_topk_mfma<<<64 * nsplit, 256, 0, stream>>>(xpBhi, xpBlo, xiBhi, xiBlo,
                                                    normP, candV, candI, nsplit);

    gemm1_kernel<<<640, 256, 0, stream>>>(peers_cont, inp_cont, W1, b1, H1Tp, H1Ti);
    colstats2x_kernel<<<256, 256, 0, stream>>>(H1Tp, H1Ti, 128, s1p, s1i);
    gemm2_kernel<<<320, 256, 0, stream>>>(H1Tp, H1Ti, W2, b2, s1p, s1i, g1, be1, H2Tp, H2Ti);
    colstats2x_kernel<<<128, 256, 0, stream>>>(H2Tp, H2Ti, 64, s2p, s2i);
    a2x_kernel<<<80, 256, 0, stream>>>(H2Tp, H2Ti, s2p, s2i, g2, be2,
                                       cw2, cb2, cw1, cb1, a2, a1);

    merge_kernel<<<16, 256, 0, stream>>>(candV, candI, a1, a2, w8, gidx, ncand);
    gather_kernel<<<1024, 256, 0, stream>>>(w8, gidx, peers_style, out);
}

// Round 15
// 343.082 us; speedup vs baseline: 3.4879x; 1.0977x over previous
//
#include <hip/hip_runtime.h>
#include <math.h>

#define NROWS 4096
#define MCOLS 16384
#define CDIM  256

typedef _Float16 half8 __attribute__((ext_vector_type(8)));
typedef float f32x4 __attribute__((ext_vector_type(4)));
typedef float f32x16 __attribute__((ext_vector_type(16)));

static __device__ __forceinline__ float softplusf(float x) {
    return fmaxf(x, 0.0f) + log1pf(expf(-fabsf(x)));
}

// Classic top-8 update (merge phases only)
#define TOPK_UPDATE(BV, BI, WORST, WP, V, IDX)                                 \
    if ((V) < (WORST)) {                                                       \
        BV[WP] = (V); BI[WP] = (IDX);                                          \
        WORST = BV[0]; WP = 0;                                                 \
        _Pragma("unroll")                                                      \
        for (int _q = 1; _q < 8; ++_q)                                         \
            if (BV[_q] > WORST) { WORST = BV[_q]; WP = _q; }                   \
    }

// Hot-loop top-8: slot index in 3 LSBs; worst via max-tree; gate = min(tau, worst).
#define TOPK_FAST(BV, BI, WORST, GATE, TAU, V, IDX)                            \
    if ((V) < (GATE)) {                                                        \
        const int _wp = __float_as_int(WORST) & 7;                             \
        BV[_wp] = __uint_as_float((__float_as_uint(V) & ~7u) | (unsigned)_wp); \
        BI[_wp] = (IDX);                                                       \
        const float _m0 = fmaxf(fmaxf(BV[0], BV[1]), fmaxf(BV[2], BV[3]));     \
        const float _m1 = fmaxf(fmaxf(BV[4], BV[5]), fmaxf(BV[6], BV[7]));     \
        WORST = fmaxf(_m0, _m1);                                               \
        GATE = fminf(TAU, WORST);                                              \
    }

// ---------------------------------------------------------------------------
// Passthrough copy
// ---------------------------------------------------------------------------
__global__ __launch_bounds__(256)
void copy_kernel(const float4* __restrict__ src, float4* __restrict__ dst, int n4) {
    int i = blockIdx.x * blockDim.x + threadIdx.x;
    if (i < n4) dst[i] = src[i];
}

// ---------------------------------------------------------------------------
// Column norms, fp32 tree (4 threads/column x 64 channels + shfl combine).
// ---------------------------------------------------------------------------
__global__ __launch_bounds__(256)
void norms_kernel(const float* __restrict__ xiT, const float* __restrict__ xpT,
                  float* __restrict__ normI, float* __restrict__ normP) {
    const int t = threadIdx.x;
    const int col = blockIdx.x * 64 + (t >> 2);
    const int sub = t & 3;
    const float* p;
    int base;
    if (col < MCOLS) { p = xpT; base = (col >> 12) * (CDIM * 4096) + (col & 4095); }
    else             { p = xiT; base = col - MCOLS; }
    float s = 0.0f;
#pragma unroll 8
    for (int k = 0; k < 64; ++k) {
        const float v = p[base + (sub * 64 + k) * 4096];
        s = fmaf(v, v, s);
    }
    s += __shfl_xor(s, 1);
    s += __shfl_xor(s, 2);
    if (sub == 0) {
        if (col < MCOLS) normP[col] = s;
        else             normI[col - MCOLS] = s;
    }
}

// ---------------------------------------------------------------------------
// fp32 [K=256][cols] -> fragment-ready fp16 hi/lo for 32x32x16 MFMA.
// Chunk (ct32*16 + kt)*64 + lane holds 8 halves:
//   element = x[col = ct32*32 + (lane&31)][k = kt*16 + (lane>>5)*8 + j]
// Tile: 64 cols x 64 k per block (2 col-groups x 4 k-groups = 8 chunks).
// ---------------------------------------------------------------------------
__global__ __launch_bounds__(256)
void convert_kernel(const float* __restrict__ src, uint4* __restrict__ dhi,
                    uint4* __restrict__ dlo, int ncols) {
    __shared__ float S[64][65];
    const int t = threadIdx.x;
    const int tilesPerRow = ncols >> 6;
    const int colbase = (blockIdx.x % tilesPerRow) << 6;
    const int ktbase  = (blockIdx.x / tilesPerRow) << 6;
    const int b = colbase >> 12;
    const int pixbase = colbase & 4095;
    const float* sp = src + (size_t)b * (CDIM * 4096) + (size_t)ktbase * 4096 + pixbase;

    for (int i = t; i < 4096; i += 256) {
        int kk = i >> 6, cc = i & 63;
        S[kk][cc] = sp[kk * 4096 + cc];
    }
    __syncthreads();

    const int l = t & 63;
#pragma unroll
    for (int s = 0; s < 2; ++s) {
        const int pid  = (t >> 6) + 4 * s;   // 0..7
        const int ct_l = pid & 1;            // col group (32 cols)
        const int kt_l = pid >> 1;           // k group (16 k)
        const int c_l  = ct_l * 32 + (l & 31);
        const int k_l  = kt_l * 16 + ((l >> 5) << 3);
        half8 h, lo;
#pragma unroll
        for (int j = 0; j < 8; ++j) {
            float v = S[k_l + j][c_l];
            _Float16 hv = (_Float16)v;
            h[j]  = hv;
            lo[j] = (_Float16)(v - (float)hv);
        }
        const int ct_g = (colbase >> 5) + ct_l;
        const int kt_g = (ktbase >> 4) + kt_l;
        const size_t off = (size_t)(ct_g * 16 + kt_g) * 64 + l;
        dhi[off] = *reinterpret_cast<uint4*>(&h);
        dlo[off] = *reinterpret_cast<uint4*>(&lo);
    }
}

// ---------------------------------------------------------------------------
// MFMA distance + per-row top-8 using 32x32x16 (2x FLOP per LDS byte).
// Grid: 32 rowtiles (128 rows) * nsplit; 256 threads = 4 waves.
// Wave w owns xi group ctg = rt*4+w (32 rows). Per iter: 32 xp cols.
// Swapped operands: A = xp (M=cols), B = xi (N=rows).
// D layout: col = lane&31 -> xi row; row = (r&3)+8*(r>>2)+4*(lane>>5) -> xp col.
// Counted-vmcnt pipeline; v = 0.5*normP - dot domain; XCD cs map.
// ---------------------------------------------------------------------------
__global__ __launch_bounds__(256, 2)
void dist_topk_mfma(const uint4* __restrict__ xpBhi, const uint4* __restrict__ xpBlo,
                    const uint4* __restrict__ xiBhi, const uint4* __restrict__ xiBlo,
                    const float* __restrict__ normP,
                    float* __restrict__ candV, int* __restrict__ candI,
                    int nsplit) {
    __shared__ __align__(16) char Abuf[2][32768];   // [buf][hi 16KB][lo 16KB], kt*1KB, lane*16B
    __shared__ __align__(16) float nPl[2048];       // 0.5 * normP

    const int t = threadIdx.x;
    const int w = t >> 6;
    const int l = t & 63;
    int rt, cs;
    if (nsplit == 16) { cs = ((blockIdx.x & 7) << 1) | ((blockIdx.x >> 3) & 1); rt = blockIdx.x >> 4; }
    else              { cs = blockIdx.x & 7;                                    rt = blockIdx.x >> 3; }
    const int niter = (MCOLS / 32) / nsplit;
    const int span  = MCOLS / nsplit;
    const int colbase = cs * span;
    const int ncand = nsplit * 8;

    for (int i = t; i < span; i += 256) nPl[i] = 0.5f * normP[colbase + i];

    // xi fragments: group ctg = rt*4 + w covers rows rt*128 + w*32 .. +32
    uint4 bh[16], bl[16];
    const int ctg = rt * 4 + w;
#pragma unroll
    for (int kt = 0; kt < 16; ++kt) {
        bh[kt] = xiBhi[(size_t)(ctg * 16 + kt) * 64 + l];
        bl[kt] = xiBlo[(size_t)(ctg * 16 + kt) * 64 + l];
    }

    float bv[8]; int bi[8];
#pragma unroll
    for (int j = 0; j < 8; ++j) {
        bv[j] = __uint_as_float((0x7f7ffff8u) | (unsigned)j);
        bi[j] = -1;
    }
    float worst = bv[7], tau = bv[7], gate = bv[7];

    // staging: wave 0: hi kt0-7, wave 1: hi kt8-15, wave 2: lo kt0-7, wave 3: lo kt8-15
    const char* gb = (w >= 2) ? (const char*)xpBlo : (const char*)xpBhi;
    const char* srcBase = gb + (size_t)(cs * niter) * 16384 + (w & 1) * 8192 + l * 16;
    char* dbBase = &Abuf[0][(w >= 2 ? 16384 : 0) + (w & 1) * 8192];

    auto stage = [&](int it, int buf) {
        const char* src = srcBase + (size_t)it * 16384;
        char* db = dbBase + buf * 32768;
#pragma unroll
        for (int kt = 0; kt < 8; ++kt)
            __builtin_amdgcn_global_load_lds(
                (const __attribute__((address_space(1))) void*)(src + kt * 1024),
                (__attribute__((address_space(3))) void*)(db + kt * 1024),
                16, 0, 0);
    };

    stage(0, 0);
    asm volatile("s_waitcnt vmcnt(0)" ::: "memory");
    __builtin_amdgcn_s_barrier();

    for (int it = 0; it < niter; ++it) {
        if (it < niter - 1) {
            stage(it + 1, (it + 1) & 1);
            asm volatile("s_waitcnt vmcnt(8)" ::: "memory");
        } else {
            asm volatile("s_waitcnt vmcnt(0)" ::: "memory");
        }
        __builtin_amdgcn_s_barrier();
        __builtin_amdgcn_sched_barrier(0);

        const char* Ab = Abuf[it & 1];

        f32x16 a0, a1;
#pragma unroll
        for (int r = 0; r < 16; ++r) { a0[r] = 0.0f; a1[r] = 0.0f; }
        __builtin_amdgcn_s_setprio(1);
#pragma unroll
        for (int kt = 0; kt < 16; ++kt) {
            const half8 ah = *reinterpret_cast<const half8*>(Ab + kt * 1024 + l * 16);
            const half8 al = *reinterpret_cast<const half8*>(Ab + 16384 + kt * 1024 + l * 16);
            const half8 vh = *reinterpret_cast<const half8*>(&bh[kt]);
            const half8 vl = *reinterpret_cast<const half8*>(&bl[kt]);
            a0 = __builtin_amdgcn_mfma_f32_32x32x16_f16(ah, vh, a0, 0, 0, 0);
            a1 = __builtin_amdgcn_mfma_f32_32x32x16_f16(ah, vl, a1, 0, 0, 0);
            a0 = __builtin_amdgcn_mfma_f32_32x32x16_f16(al, vh, a0, 0, 0, 0);
        }
        __builtin_amdgcn_s_setprio(0);

        // dv[r]: xp col = it*32 + (r&3) + 8*(r>>2) + 4*(l>>5)
        float dv[16];
        const int lq = (l >> 5) << 2;
#pragma unroll
        for (int rq = 0; rq < 4; ++rq) {
            const float4 np4 = *reinterpret_cast<const float4*>(&nPl[it * 32 + rq * 8 + lq]);
            const float npv[4] = {np4.x, np4.y, np4.z, np4.w};
#pragma unroll
            for (int j = 0; j < 4; ++j) {
                const int r = rq * 4 + j;
                dv[r] = npv[j] - (a0[r] + a1[r]);
            }
        }
        float mn = dv[0];
#pragma unroll
        for (int r = 1; r < 16; ++r) mn = fminf(mn, dv[r]);
        const int ib = colbase + it * 32 + lq;
        if (__any(mn < gate)) {
#pragma unroll
            for (int r = 0; r < 16; ++r) {
                const int cb = ib + (r & 3) + 8 * (r >> 2);
                TOPK_FAST(bv, bi, worst, gate, tau, dv[r], cb);
            }
        }

        {
            tau = fminf(worst, __shfl_xor(worst, 32));
            gate = fminf(tau, worst);
        }

        __builtin_amdgcn_s_barrier();
    }

    // merge scratch aliased onto Abuf
    float* mVal = (float*)&Abuf[0][0];
    int*   mIdx = (int*)&Abuf[0][8192];

    __syncthreads();
#pragma unroll
    for (int j = 0; j < 8; ++j) { mVal[t * 8 + j] = bv[j]; mIdx[t * 8 + j] = bi[j]; }
    __syncthreads();
    if (t < 128) {
        // row_local = t: wave w_r = t>>5, xi row r32 = t&31; lanes w_r*64+r32 and +32
        const int t1 = ((t >> 5) << 6) + (t & 31);
        const int t2 = t1 + 32;
        float sv[8]; int si[8];
#pragma unroll
        for (int j = 0; j < 8; ++j) { sv[j] = 3.4e38f; si[j] = -1; }
        float wv = 3.4e38f; int wp = 0;
#pragma unroll
        for (int j = 0; j < 8; ++j) {
            const float v1 = mVal[t1 * 8 + j];
            TOPK_UPDATE(sv, si, wv, wp, v1, mIdx[t1 * 8 + j]);
            const float v2 = mVal[t2 * 8 + j];
            TOPK_UPDATE(sv, si, wv, wp, v2, mIdx[t2 * 8 + j]);
        }
        for (int a = 1; a < 8; ++a) {
            float v = sv[a]; int ii = si[a]; int b2 = a - 1;
            while (b2 >= 0 && sv[b2] > v) { sv[b2+1] = sv[b2]; si[b2+1] = si[b2]; --b2; }
            sv[b2+1] = v; si[b2+1] = ii;
        }
        const int row = rt * 128 + t;
#pragma unroll
        for (int j = 0; j < 8; ++j) {
            candV[row * ncand + cs * 8 + j] = sv[j];
            candI[row * ncand + cs * 8 + j] = si[j];
        }
    }
}

// ---------------------------------------------------------------------------
// MLP layer 1: CIN=256 (2x128 chunks), 64 outputs per block (4 blocks/CU).
// Grid 640: 0..511 peers (256 rowblocks x 2 cout-halves), 512..639 input.
// ---------------------------------------------------------------------------
__global__ __launch_bounds__(256)
void gemm1_kernel(const float* __restrict__ Xp, const float* __restrict__ Xi,
                  const float* __restrict__ W, const float* __restrict__ bias,
                  float* __restrict__ outP, float* __restrict__ outI) {
    __shared__ __align__(16) float Wl[128][68];
    const int t = threadIdx.x;
    const bool isP = blockIdx.x < 512;
    const int bid  = isP ? blockIdx.x : blockIdx.x - 512;
    const float* X = isP ? Xp : Xi;
    const int rows = isP ? 16384 : 4096;
    float* outT = isP ? outP : outI;
    const int rowblk = bid >> 1;
    const int ch     = bid & 1;

    const int r   = rowblk * 64 + (t & 63);
    const int kgb = (t >> 6) * 16;

    float acc[16];
#pragma unroll
    for (int q = 0; q < 16; ++q) acc[q] = 0.0f;

    for (int half = 0; half < 2; ++half) {
        __syncthreads();
        for (int i = t; i < 128 * 64; i += 256) {
            int k = i >> 7, c = i & 127;
            Wl[c][k] = W[(ch * 64 + k) * 256 + half * 128 + c];
        }
        __syncthreads();
#pragma unroll 2
        for (int c = 0; c < 128; ++c) {
            const int cg = half * 128 + c;
            const float x = X[(r >> 12) * (CDIM * 4096) + cg * 4096 + (r & 4095)];
#pragma unroll
            for (int q = 0; q < 4; ++q) {
                const float4 wv = *reinterpret_cast<const float4*>(&Wl[c][kgb + 4 * q]);
                acc[4 * q + 0] = fmaf(x, wv.x, acc[4 * q + 0]);
                acc[4 * q + 1] = fmaf(x, wv.y, acc[4 * q + 1]);
                acc[4 * q + 2] = fmaf(x, wv.z, acc[4 * q + 2]);
                acc[4 * q + 3] = fmaf(x, wv.w, acc[4 * q + 3]);
            }
        }
    }
#pragma unroll
    for (int q = 0; q < 16; ++q) {
        const int k = ch * 64 + kgb + q;
        outT[k * rows + r] = acc[q] + bias[k];
    }
}

// ---------------------------------------------------------------------------
// MLP layer 2 (CIN=128, COUT=64, BN+ReLU on input). Grid 320.
// ---------------------------------------------------------------------------
__global__ __launch_bounds__(256)
void gemm2_kernel(const float* __restrict__ Hp, const float* __restrict__ Hi,
                  const float* __restrict__ W, const float* __restrict__ bias,
                  const float* __restrict__ statsP, const float* __restrict__ statsI,
                  const float* __restrict__ g, const float* __restrict__ be,
                  float* __restrict__ outP, float* __restrict__ outI) {
    __shared__ __align__(16) float Wl[128][68];
    __shared__ float scL[128], shL[128];
    const int t = threadIdx.x;
    const bool isP = blockIdx.x < 256;
    const float* X = isP ? Hp : Hi;
    const float* stats = isP ? statsP : statsI;
    const float invDenom = isP ? (1.0f / 16384.0f) : (1.0f / 4096.0f);
    const int rows = isP ? 16384 : 4096;
    const int blk  = isP ? blockIdx.x : blockIdx.x - 256;
    float* outT = isP ? outP : outI;

    for (int i = t; i < 128 * 64; i += 256) {
        int k = i >> 7, c = i & 127;
        Wl[c][k] = W[k * 128 + c];
    }
    if (t < 128) {
        float mean = stats[t] * invDenom;
        float var  = stats[128 + t] * invDenom - mean * mean;
        float sc   = rsqrtf(var + 1e-5f) * g[t];
        scL[t] = sc;
        shL[t] = be[t] - mean * sc;
    }
    __syncthreads();

    const int r   = blk * 64 + (t & 63);
    const int chb = (t >> 6) * 16;

    float acc[16];
#pragma unroll
    for (int q = 0; q < 16; ++q) acc[q] = 0.0f;

#pragma unroll 2
    for (int c = 0; c < 128; ++c) {
        float x = X[c * rows + r];
        x = fmaxf(fmaf(x, scL[c], shL[c]), 0.0f);
#pragma unroll
        for (int q = 0; q < 4; ++q) {
            const float4 wv = *reinterpret_cast<const float4*>(&Wl[c][chb + 4 * q]);
            acc[4 * q + 0] = fmaf(x, wv.x, acc[4 * q + 0]);
            acc[4 * q + 1] = fmaf(x, wv.y, acc[4 * q + 1]);
            acc[4 * q + 2] = fmaf(x, wv.z, acc[4 * q + 2]);
            acc[4 * q + 3] = fmaf(x, wv.w, acc[4 * q + 3]);
        }
    }
#pragma unroll
    for (int q = 0; q < 16; ++q) {
        const int k = chb + q;
        outT[k * rows + r] = acc[q] + bias[k];
    }
}

// ---------------------------------------------------------------------------
// Column stats for peers+input in one launch. Grid = 2*C.
// ---------------------------------------------------------------------------
__global__ __launch_bounds__(256)
void colstats2x_kernel(const float* __restrict__ Hp, const float* __restrict__ Hi,
                       int C, float* __restrict__ statsP, float* __restrict__ statsI) {
    __shared__ float rs[256], rq[256];
    const bool isP = blockIdx.x < (unsigned)C;
    const int c = isP ? blockIdx.x : blockIdx.x - C;
    const float* H = isP ? Hp : Hi;
    const int rows = isP ? 16384 : 4096;
    float* stats = isP ? statsP : statsI;
    const int t = threadIdx.x;
    float s = 0.0f, q = 0.0f;
    for (int r = t; r < rows; r += 256) {
        float v = H[c * rows + r];
        s += v;
        q = fmaf(v, v, q);
    }
    rs[t] = s; rq[t] = q;
    __syncthreads();
    for (int st = 128; st > 0; st >>= 1) {
        if (t < st) { rs[t] += rs[t + st]; rq[t] += rq[t + st]; }
        __syncthreads();
    }
    if (t == 0) { stats[c] = rs[0]; stats[C + c] = rq[0]; }
}

// ---------------------------------------------------------------------------
// a-scores for peers+input in one launch. Grid = 80.
// ---------------------------------------------------------------------------
__global__ __launch_bounds__(256)
void a2x_kernel(const float* __restrict__ Hp, const float* __restrict__ Hi,
                const float* __restrict__ statsP, const float* __restrict__ statsI,
                const float* __restrict__ g, const float* __restrict__ be,
                const float* __restrict__ cwP, const float* __restrict__ cbP,
                const float* __restrict__ cwI, const float* __restrict__ cbI,
                float* __restrict__ aP, float* __restrict__ aI) {
    __shared__ float scL[64], shL[64], cwL[64];
    const bool isP = blockIdx.x < 64;
    const float* H = isP ? Hp : Hi;
    const float* stats = isP ? statsP : statsI;
    const float* cw = isP ? cwP : cwI;
    const float* cb = isP ? cbP : cbI;
    float* aout = isP ? aP : aI;
    const int rows = isP ? 16384 : 4096;
    const float invDenom = isP ? (1.0f / 16384.0f) : (1.0f / 4096.0f);
    const int blk = isP ? blockIdx.x : blockIdx.x - 64;
    const int t = threadIdx.x;
    if (t < 64) {
        float mean = stats[t] * invDenom;
        float var  = stats[64 + t] * invDenom - mean * mean;
        float sc   = rsqrtf(var + 1e-5f) * g[t];
        scL[t] = sc;
        shL[t] = be[t] - mean * sc;
        cwL[t] = cw[t];
    }
    __syncthreads();
    const int row = blk * 256 + t;
    if (row < rows) {
        float a = 0.0f;
        for (int c = 0; c < 64; ++c) {
            float v = H[c * rows + row];
            a += fmaxf(fmaf(v, scL[c], shL[c]), 0.0f) * cwL[c];
        }
        aout[row] = a + cb[0];
    }
}

// ---------------------------------------------------------------------------
// Merge candidates -> per-row softmax weights + gather base addresses.
// ---------------------------------------------------------------------------
__global__ __launch_bounds__(256)
void merge_kernel(const float* __restrict__ candV, const int* __restrict__ candI,
                  const float* __restrict__ a1, const float* __restrict__ a2,
                  float* __restrict__ w8, int* __restrict__ gidx, int ncand) {
    const int row = blockIdx.x * 256 + threadIdx.x;
    float sv[8]; int si[8];
#pragma unroll
    for (int j = 0; j < 8; ++j) { sv[j] = 3.4e38f; si[j] = 0; }
    float w2 = 3.4e38f; int wp = 0;
    for (int k = 0; k < ncand; ++k) {
        const float v = candV[row * ncand + k];
        TOPK_UPDATE(sv, si, w2, wp, v, candI[row * ncand + k]);
    }
    for (int a = 1; a < 8; ++a) {
        float v = sv[a]; int ii = si[a]; int b = a - 1;
        while (b >= 0 && sv[b] > v) { sv[b + 1] = sv[b]; si[b + 1] = si[b]; --b; }
        sv[b + 1] = v; si[b + 1] = ii;
    }
    const float kth = sv[4];
    int cnt = 5;
    while (cnt < 8 && sv[cnt] <= kth) ++cnt;

    const float arow = a1[row];
    float s[8], e[8];
    float mx = -1e30f;
#pragma unroll
    for (int j = 0; j < 8; ++j) s[j] = 0.0f;
    for (int j = 0; j < cnt; ++j) {
        s[j] = softplusf(arow + a2[si[j]]);
        mx = fmaxf(mx, s[j]);
    }
    float Z = 0.0f;
    for (int j = 0; j < 8; ++j) {
        e[j] = (j < cnt) ? expf(s[j] - mx) : 0.0f;
        Z += e[j];
    }
#pragma unroll
    for (int j = 0; j < 8; ++j) {
        const int ix = (j < cnt) ? si[j] : si[0];
        w8[row * 8 + j]   = e[j] / Z;
        gidx[row * 8 + j] = (ix >> 12) * (CDIM * 4096) + (ix & 4095);
    }
}

// ---------------------------------------------------------------------------
// Gather: out[(256+c)*4096 + n] = sum_j w8[n][j] * PS[gidx[n][j] + c*4096].
// ---------------------------------------------------------------------------
__global__ __launch_bounds__(256)
void gather_kernel(const float* __restrict__ w8, const int* __restrict__ gidx,
                   const float* __restrict__ PS, float* __restrict__ dout) {
    const int t = threadIdx.x;
    const int rtile = blockIdx.x >> 4;
    const int chunk = blockIdx.x & 15;
    const int row = rtile * 64 + (t & 63);
    const int c0  = chunk * 16 + (t >> 6) * 4;

    float w[8]; int ab[8];
#pragma unroll
    for (int j = 0; j < 8; ++j) { w[j] = w8[row * 8 + j]; ab[j] = gidx[row * 8 + j]; }

#pragma unroll
    for (int cc = 0; cc < 4; ++cc) {
        const int c = c0 + cc;
        float acc = 0.0f;
#pragma unroll
        for (int j = 0; j < 8; ++j) acc += w[j] * PS[ab[j] + c * 4096];
        dout[(CDIM + c) * 4096 + row] = acc;
    }
}

// ---------------------------------------------------------------------------
extern "C" void kernel_launch(void* const* d_in, const int* in_sizes, int n_in,
                              void* d_out, int out_size, void* d_ws, size_t ws_size,
                              hipStream_t stream) {
    const float* inp_cont    = (const float*)d_in[0];
    const float* peers_cont  = (const float*)d_in[2];
    const float* peers_style = (const float*)d_in[3];
    const float* W1  = (const float*)d_in[4];
    const float* b1  = (const float*)d_in[5];
    const float* g1  = (const float*)d_in[6];
    const float* be1 = (const float*)d_in[7];
    const float* W2  = (const float*)d_in[8];
    const float* b2  = (const float*)d_in[9];
    const float* g2  = (const float*)d_in[10];
    const float* be2 = (const float*)d_in[11];
    const float* cw1 = (const float*)d_in[12];
    const float* cb1 = (const float*)d_in[13];
    const float* cw2 = (const float*)d_in[14];
    const float* cb2 = (const float*)d_in[15];
    float* out = (float*)d_out;
    char*  wsb = (char*)d_ws;

    int nsplit;
    if      (ws_size >= (size_t)25400000) nsplit = 16;
    else if (ws_size >= (size_t)23300000) nsplit = 8;
    else return;
    const int ncand = nsplit * 8;
    const size_t candBytes = (size_t)NROWS * ncand * 4;

    // workspace layout (bytes)
    uint4* xpBhi = (uint4*)(wsb + 0);                    //  8 MB
    uint4* xpBlo = (uint4*)(wsb + 8388608);              //  8 MB
    uint4* xiBhi = (uint4*)(wsb + 16777216);             //  2 MB
    uint4* xiBlo = (uint4*)(wsb + 18874368);             //  2 MB
    float* normP = (float*)(wsb + 20971520);             //  64 KB
    float* normI = (float*)(wsb + 21037056);             //  16 KB
    float* candV = (float*)(wsb + 21053440);             //  candBytes
    int*   candI = (int*)  (wsb + 21053440 + candBytes); //  candBytes
    char*  tail  = wsb + 21053440 + 2 * candBytes;
    float* a2    = (float*)(tail);                       //  64 KB
    float* a1    = (float*)(tail + 65536);               //  16 KB
    float* s1p   = (float*)(tail + 81920);               //  1 KB
    float* s1i   = (float*)(tail + 82944);               //  1 KB
    float* s2p   = (float*)(tail + 83968);               //  512
    float* s2i   = (float*)(tail + 84480);               //  512
    // Aliased AFTER dist kernel completes:
    float* H1Tp  = (float*)(wsb + 0);                    // 8 MB
    float* H2Tp  = (float*)(wsb + 8388608);              // 4 MB
    float* H1Ti  = (float*)(wsb + 16777216);             // 2 MB
    float* H2Ti  = (float*)(wsb + 18874368);             // 1 MB (ends 19922944)
    float* w8    = (float*)(wsb + 19922944);             // 128 KB
    int*   gidx  = (int*)  (wsb + 20054016);             // 128 KB

    copy_kernel<<<1024, 256, 0, stream>>>((const float4*)inp_cont, (float4*)out, 262144);
    norms_kernel<<<320, 256, 0, stream>>>(inp_cont, peers_cont, normI, normP);
    convert_kernel<<<256, 256, 0, stream>>>(inp_cont, xiBhi, xiBlo, 4096);
    convert_kernel<<<1024, 256, 0, stream>>>(peers_cont, xpBhi, xpBlo, 16384);

    dist_topk_mfma<<<32 * nsplit, 256, 0, stream>>>(xpBhi, xpBlo, xiBhi, xiBlo,
                                                    normP, candV, candI, nsplit);

    gemm1_kernel<<<640, 256, 0, stream>>>(peers_cont, inp_cont, W1, b1, H1Tp, H1Ti);
    colstats2x_kernel<<<256, 256, 0, stream>>>(H1Tp, H1Ti, 128, s1p, s1i);
    gemm2_kernel<<<320, 256, 0, stream>>>(H1Tp, H1Ti, W2, b2, s1p, s1i, g1, be1, H2Tp, H2Ti);
    colstats2x_kernel<<<128, 256, 0, stream>>>(H2Tp, H2Ti, 64, s2p, s2i);
    a2x_kernel<<<80, 256, 0, stream>>>(H2Tp, H2Ti, s2p, s2i, g2, be2,
                                       cw2, cb2, cw1, cb1, a2, a1);

    merge_kernel<<<16, 256, 0, stream>>>(candV, candI, a1, a2, w8, gidx, ncand);
    gather_kernel<<<1024, 256, 0, stream>>>(w8, gidx, peers_style, out);
}